// Round 7
// baseline (8713.528 us; speedup 1.0000x reference)
//
#include <hip/hip_runtime.h>
#include <hip/hip_bf16.h>
#include <stdint.h>

typedef unsigned short u16;
typedef unsigned int u32;
typedef unsigned long long u64;
typedef __attribute__((ext_vector_type(8))) short s16x8;
typedef __attribute__((ext_vector_type(4))) float f32x4;

#define AGT __HIP_MEMORY_SCOPE_AGENT

static __device__ __forceinline__ float bf2f(u16 u){
  unsigned v = ((unsigned)u) << 16; return __builtin_bit_cast(float, v);
}
static __device__ __forceinline__ u16 f2bf(float f){
  unsigned u = __builtin_bit_cast(unsigned, f);
  u += 0x7FFFu + ((u >> 16) & 1u);
  return (u16)(u >> 16);
}
static __device__ __forceinline__ float sigm(float x){ return 1.f / (1.f + __expf(-x)); }

typedef __attribute__((address_space(1))) const u32 gu32;
typedef __attribute__((address_space(3))) u32 lu32;
static __device__ __forceinline__ void gload_lds16(const void* g, void* l){
  __builtin_amdgcn_global_load_lds((gu32*)g, (lu32*)l, 16, 0, 0);
}

// coherent 16B load via two 8B agent-scope atomic loads (served at LLC)
static __device__ __forceinline__ s16x8 aload16(const u16* p){
  union { u64 q[2]; s16x8 v; } u;
  u.q[0] = __hip_atomic_load((const u64*)p,     __ATOMIC_RELAXED, AGT);
  u.q[1] = __hip_atomic_load(((const u64*)p)+1, __ATOMIC_RELAXED, AGT);
  return u.v;
}

// SYNC layout (u32 idx; one 128B line per counter)
#define SY_HG        0
#define SY_RDY(b)    (32 + (b)*32)
#define SY_OD(b)     (1056 + (b)*32)
#define SY_BYTES     8448

static __device__ __forceinline__ void drain(){
  asm volatile("s_waitcnt vmcnt(0)" ::: "memory");
}
// single-line poll: concurrent atomic LOADS (no RMW contention)
static __device__ __forceinline__ void await_line(u32* f, u32 target){
  if (threadIdx.x == 0){
    while (__hip_atomic_load(f, __ATOMIC_RELAXED, AGT) < target)
      __builtin_amdgcn_s_sleep(1);
  }
  __syncthreads();
}
// 32-line poll with 32 parallel lanes
static __device__ __forceinline__ void await_all_od(u32* SYNC, u32 target){
  if (threadIdx.x < 32){
    while (__hip_atomic_load(&SYNC[SY_OD(threadIdx.x)], __ATOMIC_RELAXED, AGT) < target)
      __builtin_amdgcn_s_sleep(1);
  }
  __syncthreads();
}
static __device__ __forceinline__ void bump(u32* f){
  drain();
  __syncthreads();
  if (threadIdx.x == 0)
    __hip_atomic_fetch_add(f, 1u, __ATOMIC_RELEASE, AGT);
}

// ---------------- prep kernels ----------------

__global__ __launch_bounds__(256) void k_wfull(const float* __restrict__ wih,
                                               const float* __restrict__ whh,
                                               u16* __restrict__ wf){
  int stride = gridDim.x * blockDim.x;
  for (int i = blockIdx.x * blockDim.x + threadIdx.x; i < 2048 * 1280; i += stride){
    int j = i / 1280, k = i - j * 1280;
    float v = (k < 768) ? wih[j * 768 + k] : whh[j * 512 + (k - 768)];
    wf[i] = f2bf(v);
  }
}

__global__ __launch_bounds__(256) void k_whmt(const float* __restrict__ whm,
                                              u16* __restrict__ wt){
  int stride = gridDim.x * blockDim.x;
  for (int i = blockIdx.x * blockDim.x + threadIdx.x; i < 512 * 512; i += stride){
    int n = i >> 9, k = i & 511;
    wt[i] = f2bf(whm[k * 512 + n]);     // WHMT[a][b] = whm[b][a]
  }
}

__global__ __launch_bounds__(256) void k_cvt(const float* __restrict__ s,
                                             u16* __restrict__ d, int n){
  int stride = gridDim.x * blockDim.x * 4;
  for (int i = (blockIdx.x * blockDim.x + threadIdx.x) * 4; i < n; i += stride){
    float4 v = *(const float4*)&s[i];
    d[i + 0] = f2bf(v.x); d[i + 1] = f2bf(v.y);
    d[i + 2] = f2bf(v.z); d[i + 3] = f2bf(v.w);
  }
}

// xs stored [t][b][e]
__global__ __launch_bounds__(256) void k_xs(const int* __restrict__ seq,
                                            const float* __restrict__ emb,
                                            u16* __restrict__ xs){
  int stride = gridDim.x * blockDim.x;
  for (int i = blockIdx.x * blockDim.x + threadIdx.x; i < 8192 * 256; i += stride){
    int m = i >> 8, e = i & 255;          // m = b*256 + t
    int b = m >> 8, t = m & 255;
    float v = emb[(size_t)seq[m] * 256 + e];
    xs[(size_t)(t * 32 + b) * 256 + e] = f2bf(v > 0.f ? v : 0.f);
  }
}

// ---------------- 128x128 bf16 MFMA GEMM: C = A[M,K] @ B[N,K]^T ----------------

template<int OUTBF, int HASBIAS, int NG>
__global__ __launch_bounds__(256) void k_gemm(const u16* __restrict__ A,
                                              const u16* __restrict__ Bm,
                                              void* __restrict__ Cout,
                                              const float* __restrict__ bias,
                                              int M, int N, int K){
  __shared__ __align__(16) u16 As[128 * 64];
  __shared__ __align__(16) u16 Bs[128 * 64];
  int tid = threadIdx.x; int w = tid >> 6; int l = tid & 63;
  int m0 = blockIdx.x * 128, n0 = blockIdx.y * 128;
  int wr = w >> 1, wc = w & 1;
  f32x4 acc[4][4];
#pragma unroll
  for (int a = 0; a < 4; a++)
#pragma unroll
    for (int b = 0; b < 4; b++){ f32x4 z = {0.f,0.f,0.f,0.f}; acc[a][b] = z; }
  int rA = m0 + (tid >> 3);
  int rB = n0 + (tid >> 3);
  for (int k0 = 0; k0 < K; k0 += 64){
    __syncthreads();
    int ca = k0 + (tid & 7) * 8;
#pragma unroll
    for (int i = 0; i < 4; i++){
      gload_lds16(&A[(size_t)(rA + i * 32) * K + ca], &As[i * 2048 + w * 512]);
      int rb = rB + i * 32;
      if (NG) rb = (rb < N - 1) ? rb : (N - 1);
      gload_lds16(&Bm[(size_t)rb * K + ca], &Bs[i * 2048 + w * 512]);
    }
    asm volatile("s_waitcnt vmcnt(0)" ::: "memory");
    __syncthreads();
#pragma unroll
    for (int ks = 0; ks < 2; ks++){
      s16x8 av[4], bv[4];
      int ko = ks * 32 + (l >> 4) * 8;
#pragma unroll
      for (int i = 0; i < 4; i++) av[i] = *(const s16x8*)&As[(wr * 64 + i * 16 + (l & 15)) * 64 + ko];
#pragma unroll
      for (int i = 0; i < 4; i++) bv[i] = *(const s16x8*)&Bs[(wc * 64 + i * 16 + (l & 15)) * 64 + ko];
#pragma unroll
      for (int mi = 0; mi < 4; mi++)
#pragma unroll
        for (int ni = 0; ni < 4; ni++)
          acc[mi][ni] = __builtin_amdgcn_mfma_f32_16x16x32_bf16(av[mi], bv[ni], acc[mi][ni], 0, 0, 0);
    }
  }
#pragma unroll
  for (int mi = 0; mi < 4; mi++)
#pragma unroll
    for (int ni = 0; ni < 4; ni++){
      int row = m0 + wr * 64 + mi * 16 + (l >> 4) * 4;
      int col = n0 + wc * 64 + ni * 16 + (l & 15);
      if (NG && col >= N) continue;
#pragma unroll
      for (int r = 0; r < 4; r++){
        float v = acc[mi][ni][r];
        if (HASBIAS) v += bias[col];
        if (OUTBF) ((u16*)Cout)[(size_t)(row + r) * N + col] = f2bf(v);
        else       ((float*)Cout)[(size_t)(row + r) * N + col] = v;
      }
    }
}

// ---------------- gates role (gid<32): W pinned in VGPRs ----------------

static __device__ void gates_role(const u16* __restrict__ WF, const u16* __restrict__ XS,
                                  u16* __restrict__ Z, float* __restrict__ CST,
                                  u32* __restrict__ SYNC, float* __restrict__ SM, int g){
  const int tid = threadIdx.x, w = tid >> 6, l = tid & 63;
  const int ns = g << 4;
  float (*red)[32][64] = (float(*)[32][64])SM;

  // pin step-invariant W slices: x(8) + h(16) + out(16) s16x8 = 160 VGPR
  s16x8 bx[2][4], bh[4][4], bo[4][4];
#pragma unroll
  for (int ki = 0; ki < 2; ki++){
    int ko = w * 64 + ki * 32 + (l >> 4) * 8;
#pragma unroll
    for (int gi = 0; gi < 4; gi++)
      bx[ki][gi] = *(const s16x8*)&WF[(size_t)(gi * 512 + ns + (l & 15)) * 1280 + ko];
  }
#pragma unroll
  for (int ki = 0; ki < 4; ki++){
    int koh = 768 + w * 128 + ki * 32 + (l >> 4) * 8;
    int koo = 256 + w * 128 + ki * 32 + (l >> 4) * 8;
#pragma unroll
    for (int gi = 0; gi < 4; gi++){
      bh[ki][gi] = *(const s16x8*)&WF[(size_t)(gi * 512 + ns + (l & 15)) * 1280 + koh];
      bo[ki][gi] = *(const s16x8*)&WF[(size_t)(gi * 512 + ns + (l & 15)) * 1280 + koo];
    }
  }

  for (int t = 0; t < 256; ++t){
    u16* Zn = Z + (t & 1) * 32768;
    const u16* Zp = Z + ((t + 1) & 1) * 32768;
    f32x4 acc[2][4];
#pragma unroll
    for (int a = 0; a < 2; a++)
#pragma unroll
      for (int b = 0; b < 4; b++){ f32x4 z = {0.f,0.f,0.f,0.f}; acc[a][b] = z; }

    // x segment (no dependency)
#pragma unroll
    for (int ki = 0; ki < 2; ki++){
      int ko = w * 64 + ki * 32 + (l >> 4) * 8;
      s16x8 av[2];
#pragma unroll
      for (int mi = 0; mi < 2; mi++)
        av[mi] = *(const s16x8*)&XS[(size_t)(t * 32 + mi * 16 + (l & 15)) * 256 + ko];
#pragma unroll
      for (int mi = 0; mi < 2; mi++)
#pragma unroll
        for (int gi = 0; gi < 4; gi++)
          acc[mi][gi] = __builtin_amdgcn_mfma_f32_16x16x32_bf16(av[mi], bx[ki][gi], acc[mi][gi], 0, 0, 0);
    }
    if (t > 0){
      await_line(&SYNC[SY_HG], 32u * (u32)t);       // h(t-1) complete (all 32 producers)
#pragma unroll
      for (int ki = 0; ki < 4; ki++){
        int ko = 768 + w * 128 + ki * 32 + (l >> 4) * 8;
        s16x8 av[2];
#pragma unroll
        for (int mi = 0; mi < 2; mi++)
          av[mi] = aload16(&Zp[(size_t)(mi * 16 + (l & 15)) * 1024 + (ko - 256)]);
#pragma unroll
        for (int mi = 0; mi < 2; mi++)
#pragma unroll
          for (int gi = 0; gi < 4; gi++)
            acc[mi][gi] = __builtin_amdgcn_mfma_f32_16x16x32_bf16(av[mi], bh[ki][gi], acc[mi][gi], 0, 0, 0);
      }
      await_all_od(SYNC, 7u * (u32)t);              // out(t-1) complete (all batches)
#pragma unroll
      for (int ki = 0; ki < 4; ki++){
        int ko = 256 + w * 128 + ki * 32 + (l >> 4) * 8;
        s16x8 av[2];
#pragma unroll
        for (int mi = 0; mi < 2; mi++)
          av[mi] = aload16(&Zp[(size_t)(mi * 16 + (l & 15)) * 1024 + (ko - 256)]);
#pragma unroll
        for (int mi = 0; mi < 2; mi++)
#pragma unroll
          for (int gi = 0; gi < 4; gi++)
            acc[mi][gi] = __builtin_amdgcn_mfma_f32_16x16x32_bf16(av[mi], bo[ki][gi], acc[mi][gi], 0, 0, 0);
      }
    }
    // cross-wave reduce + LSTM
#pragma unroll
    for (int mi = 0; mi < 2; mi++)
#pragma unroll
      for (int gi = 0; gi < 4; gi++)
#pragma unroll
        for (int r = 0; r < 4; r++)
          red[w][mi * 16 + (l >> 4) * 4 + r][gi * 16 + (l & 15)] = acc[mi][gi][r];
    __syncthreads();
    {
      int bi = tid >> 3, j = (tid & 7) * 2;
      float iv0=0,fv0=0,gv0=0,ov0=0, iv1=0,fv1=0,gv1=0,ov1=0;
#pragma unroll
      for (int qq = 0; qq < 4; qq++){
        iv0 += red[qq][bi][j];      fv0 += red[qq][bi][16 + j];
        gv0 += red[qq][bi][32 + j]; ov0 += red[qq][bi][48 + j];
        iv1 += red[qq][bi][j + 1];      fv1 += red[qq][bi][16 + j + 1];
        gv1 += red[qq][bi][32 + j + 1]; ov1 += red[qq][bi][48 + j + 1];
      }
      int n0 = ns + j;
      float c0 = (t > 0) ? CST[bi * 512 + n0]     : 0.f;
      float c1 = (t > 0) ? CST[bi * 512 + n0 + 1] : 0.f;
      float cn0 = sigm(fv0) * c0 + sigm(iv0) * tanhf(gv0);
      float cn1 = sigm(fv1) * c1 + sigm(iv1) * tanhf(gv1);
      float h0 = sigm(ov0) * tanhf(cn0);
      float h1 = sigm(ov1) * tanhf(cn1);
      CST[bi * 512 + n0] = cn0; CST[bi * 512 + n0 + 1] = cn1;
      u32 pk = (u32)f2bf(h0) | ((u32)f2bf(h1) << 16);
      __hip_atomic_store((u32*)(Zn + bi * 1024 + 512 + n0), pk, __ATOMIC_RELAXED, AGT);
    }
    __syncthreads();
    bump(&SYNC[SY_HG]);
  }
}

// ---------------- attn+out role (gid>=32): V and CNN2 rows pinned in VGPRs ----------------

static __device__ void attn_role(const u16* __restrict__ CNN2, const u16* __restrict__ CNNB,
                                 const u16* __restrict__ WOUT, u16* __restrict__ Z,
                                 float* __restrict__ UPART, float* __restrict__ MS,
                                 u16* __restrict__ OALL, u32* __restrict__ SYNC,
                                 float* __restrict__ SM, int q){
  const int tid = threadIdx.x, w = tid >> 6, ln = tid & 63;
  const int b = q / 7, ch = q - b * 7;
  const int l0 = ch * 112;
  const int nc = (ch == 6) ? 68 : 74, cs = ch * 74;
  float* sc   = SM;          // [112]
  float* sred = SM + 112;    // [4]
  float* msh  = SM + 120;    // [14]
  float* csf  = SM + 144;    // [512]
  float* hsf  = SM + 656;    // [512]
  float* accw = SM + 1184;   // [4*512]
  float* ored = SM + 3232;   // [160]

  // pin V rows and CNN2 rows (step-invariant): 56 s16x8 = 224 VGPR
  s16x8 rowv[28], c2v[28];
  {
    const u16* vb = CNNB + ((size_t)(b * 784 + l0)) * 512 + ln * 8;
    const u16* cb = CNN2 + ((size_t)(b * 784 + l0)) * 512 + ln * 8;
#pragma unroll
    for (int i = 0; i < 28; i++){
      rowv[i] = *(const s16x8*)(vb + (size_t)(w + 4 * i) * 512);
      c2v[i]  = *(const s16x8*)(cb + (size_t)(w + 4 * i) * 512);
    }
  }
  u32* rdy = &SYNC[SY_RDY(b)];
  u32* od  = &SYNC[SY_OD(b)];

  for (int t = 0; t < 256; ++t){
    await_line(&SYNC[SY_HG], 32u * (u32)(t + 1));   // h(t) complete
    u16* Zpar = Z + (t & 1) * 32768;
    float mp[8];
    {
      s16x8 hv = aload16(Zpar + b * 1024 + 512 + ln * 8);
#pragma unroll
      for (int j = 0; j < 8; j++) mp[j] = bf2f((u16)hv[j]);
    }
    // scores from pinned CNN2 rows
    float wmax = -1e30f;
#pragma unroll
    for (int i = 0; i < 28; i++){
      float d = 0.f;
#pragma unroll
      for (int j = 0; j < 8; j++) d = fmaf(mp[j], bf2f((u16)c2v[i][j]), d);
#pragma unroll
      for (int m = 1; m < 64; m <<= 1) d += __shfl_xor(d, m, 64);
      if (ln == 0) sc[w + 4 * i] = d;
      wmax = fmaxf(wmax, d);
    }
    if (ln == 0) sred[w] = wmax;
    __syncthreads();
    float M = fmaxf(fmaxf(sred[0], sred[1]), fmaxf(sred[2], sred[3]));
    __syncthreads();
    float s = 0.f;
    if (tid < 112){ float p = __expf(sc[tid] - M); sc[tid] = p; s = p; }
#pragma unroll
    for (int m = 1; m < 64; m <<= 1) s += __shfl_xor(s, m, 64);
    if (ln == 0) sred[w] = s;
    __syncthreads();
    float S = sred[0] + sred[1] + sred[2] + sred[3];
    // weighted V from pinned registers
    float a8[8] = {0.f,0.f,0.f,0.f,0.f,0.f,0.f,0.f};
#pragma unroll
    for (int i = 0; i < 28; i++){
      float p = sc[w + 4 * i];
#pragma unroll
      for (int j = 0; j < 8; j++) a8[j] = fmaf(p, bf2f((u16)rowv[i][j]), a8[j]);
    }
    {
      f32x4 x0 = {a8[0], a8[1], a8[2], a8[3]};
      f32x4 x1 = {a8[4], a8[5], a8[6], a8[7]};
      *(f32x4*)&accw[w * 512 + ln * 8]     = x0;
      *(f32x4*)&accw[w * 512 + ln * 8 + 4] = x1;
    }
    __syncthreads();
    int e0 = 2 * tid;
    {
      float u0 = accw[e0] + accw[512 + e0] + accw[1024 + e0] + accw[1536 + e0];
      float u1 = accw[e0+1] + accw[512 + e0+1] + accw[1024 + e0+1] + accw[1536 + e0+1];
      union { u64 qv; float f[2]; } uu; uu.f[0] = u0; uu.f[1] = u1;
      __hip_atomic_store((u64*)(UPART + ((size_t)(b * 7 + ch) * 512 + e0)), uu.qv,
                         __ATOMIC_RELAXED, AGT);
      if (tid == 0){
        union { u64 qv; float f[2]; } mm; mm.f[0] = M; mm.f[1] = S;
        __hip_atomic_store((u64*)(MS + (b * 7 + ch) * 2), mm.qv, __ATOMIC_RELAXED, AGT);
      }
    }
    __syncthreads();
    bump(rdy);
    await_line(rdy, 7u * (u32)(t + 1));             // all 7 partials of batch b
    if (tid < 7){
      union { u64 qv; float f[2]; } a;
      a.qv = __hip_atomic_load((const u64*)(MS + (b * 7 + tid) * 2), __ATOMIC_RELAXED, AGT);
      msh[2 * tid] = a.f[0]; msh[2 * tid + 1] = a.f[1];
    }
    __syncthreads();
    float Mg = -1e30f;
#pragma unroll
    for (int c = 0; c < 7; c++) Mg = fmaxf(Mg, msh[2 * c]);
    float bet[7]; float Sg = 0.f;
#pragma unroll
    for (int c = 0; c < 7; c++){
      float e = __expf(msh[2 * c] - Mg);
      bet[c] = e; Sg += e * msh[2 * c + 1];
    }
    float inv = 1.f / Sg;
    {
      float c0 = 0.f, c1 = 0.f;
#pragma unroll
      for (int c = 0; c < 7; c++){
        union { u64 qv; float f[2]; } a;
        a.qv = __hip_atomic_load((const u64*)(UPART + ((size_t)(b * 7 + c) * 512 + e0)),
                                 __ATOMIC_RELAXED, AGT);
        float bc = bet[c] * inv;
        c0 = fmaf(bc, a.f[0], c0); c1 = fmaf(bc, a.f[1], c1);
      }
      csf[e0] = c0; csf[e0 + 1] = c1;
      u32 hv2 = __hip_atomic_load((const u32*)(Zpar + b * 1024 + 512 + e0),
                                  __ATOMIC_RELAXED, AGT);
      hsf[e0] = bf2f((u16)(hv2 & 0xffff)); hsf[e0 + 1] = bf2f((u16)(hv2 >> 16));
    }
    __syncthreads();
    // out slice: cols [cs, cs+nc), (col, K-half) per thread
    if (tid < 2 * nc){
      int col = cs + (tid >> 1), half = tid & 1;
      const s16x8* wr = (const s16x8*)(WOUT + (size_t)col * 1024 + half * 512);
      const float* src = half ? hsf : csf;
      float o = 0.f;
      for (int kk = 0; kk < 64; kk++){
        s16x8 qv = wr[kk];
#pragma unroll
        for (int j = 0; j < 8; j++) o = fmaf(src[kk * 8 + j], bf2f((u16)qv[j]), o);
      }
      ored[tid] = o;
    }
    __syncthreads();
    if (tid < (nc >> 1)){
      int q0 = 2 * tid, q1 = 2 * tid + 1;
      float v0 = tanhf(ored[2 * q0] + ored[2 * q0 + 1]);
      float v1 = tanhf(ored[2 * q1] + ored[2 * q1 + 1]);
      u32 pk = (u32)f2bf(v0) | ((u32)f2bf(v1) << 16);
      __hip_atomic_store((u32*)(Zpar + b * 1024 + cs + q0), pk, __ATOMIC_RELAXED, AGT);
      *(u32*)&OALL[((size_t)(b * 256 + t)) * 512 + cs + q0] = pk;
    }
    __syncthreads();
    bump(od);
  }
}

// ---------------- persistent decoder ----------------

__global__ __launch_bounds__(256, 1) void k_persist(const u16* __restrict__ WF,
                                                    const u16* __restrict__ XS,
                                                    const u16* __restrict__ CNN2,
                                                    const u16* __restrict__ CNNB,
                                                    const u16* __restrict__ WOUT,
                                                    u16* __restrict__ Z,
                                                    float* __restrict__ CST,
                                                    float* __restrict__ UPART,
                                                    float* __restrict__ MS,
                                                    u16* __restrict__ OALL,
                                                    u32* __restrict__ SYNC){
  __shared__ __align__(16) float SM[8192];
  int gid = blockIdx.x;
  if (gid < 32)
    gates_role(WF, XS, Z, CST, SYNC, SM, gid);
  else
    attn_role(CNN2, CNNB, WOUT, Z, UPART, MS, OALL, SYNC, SM, gid - 32);
}

// ---------------- log_softmax ----------------

__global__ __launch_bounds__(256) void k_lsm(float* __restrict__ x){
  size_t base = (size_t)blockIdx.x * 8000;
  int tid = threadIdx.x, w = tid >> 6, ln = tid & 63;
  __shared__ float sred[4];
  float m = -1e30f;
  for (int v = tid; v < 8000; v += 256) m = fmaxf(m, x[base + v]);
#pragma unroll
  for (int mk = 1; mk < 64; mk <<= 1) m = fmaxf(m, __shfl_xor(m, mk, 64));
  if (ln == 0) sred[w] = m;
  __syncthreads();
  float M = fmaxf(fmaxf(sred[0], sred[1]), fmaxf(sred[2], sred[3]));
  __syncthreads();
  float s = 0.f;
  for (int v = tid; v < 8000; v += 256) s += __expf(x[base + v] - M);
#pragma unroll
  for (int mk = 1; mk < 64; mk <<= 1) s += __shfl_xor(s, mk, 64);
  if (ln == 0) sred[w] = s;
  __syncthreads();
  float S = sred[0] + sred[1] + sred[2] + sred[3];
  float lz = M + logf(S);
  for (int v = tid; v < 8000; v += 256) x[base + v] -= lz;
}

// ---------------- launcher ----------------

extern "C" void kernel_launch(void* const* d_in, const int* in_sizes, int n_in,
                              void* d_out, int out_size, void* d_ws, size_t ws_size,
                              hipStream_t stream){
  const float* cnn  = (const float*)d_in[0];
  const int*   seq  = (const int*)d_in[1];
  const float* emb  = (const float*)d_in[2];
  const float* wih  = (const float*)d_in[3];
  const float* whh  = (const float*)d_in[4];
  const float* whm  = (const float*)d_in[5];
  const float* wo   = (const float*)d_in[6];
  const float* wlg  = (const float*)d_in[7];
  const float* blg  = (const float*)d_in[8];

  char* ws = (char*)d_ws;
  u16*   WF     = (u16*)(ws + 0);          // 2048x1280 bf16 = 5,242,880
  u16*   WHMT   = (u16*)(ws + 5242880);    // 512x512 bf16   =   524,288
  u16*   WOUT   = (u16*)(ws + 5767168);    // 512x1024 bf16  = 1,048,576
  u16*   WLOGIT = (u16*)(ws + 6815744);    // 8000x512 bf16  = 8,192,000
  u16*   CNNBF  = (u16*)(ws + 15007744);   // 25088x512 bf16 = 25,690,112
  u16*   CNN2   = (u16*)(ws + 40697856);   // 25088x512 bf16 = 25,690,112
  u16*   XS     = (u16*)(ws + 66387968);   // [256][32][256] bf16 = 4,194,304
  u16*   OALL   = (u16*)(ws + 70582272);   // 8192x512 bf16  = 8,388,608
  u16*   Z      = (u16*)(ws + 78970880);   // [2][32][1024] bf16 = 131,072
  float* CST    = (float*)(ws + 79101952); // 32x512 f32     = 65,536
  float* UPART  = (float*)(ws + 79167488); // [32][7][512] f32 = 458,752
  float* MS     = (float*)(ws + 79626240); // [32][7][2] f32 (pad 2048)
  u32*   SYNC   = (u32*)(ws + 79628288);   // 8,448 B

  float* OUT = (float*)d_out;

  hipMemsetAsync(SYNC, 0, SY_BYTES, stream);
  k_wfull<<<512, 256, 0, stream>>>(wih, whh, WF);
  k_whmt<<<128, 256, 0, stream>>>(whm, WHMT);
  k_cvt<<<512, 256, 0, stream>>>(wo, WOUT, 512 * 1024);
  k_cvt<<<2048, 256, 0, stream>>>(wlg, WLOGIT, 8000 * 512);
  k_cvt<<<2048, 256, 0, stream>>>(cnn, CNNBF, 25088 * 512);
  k_xs<<<2048, 256, 0, stream>>>(seq, emb, XS);

  {
    dim3 g(196, 4);   // CNN2 = CNNB @ WHMT^T : scores key matrix
    k_gemm<1, 0, 0><<<g, 256, 0, stream>>>(CNNBF, WHMT, CNN2, nullptr, 25088, 512, 512);
  }

  k_persist<<<256, 256, 0, stream>>>(WF, XS, CNN2, CNNBF, WOUT, Z, CST, UPART, MS, OALL, SYNC);

  {
    dim3 g(64, 63);
    k_gemm<0, 1, 1><<<g, 256, 0, stream>>>(OALL, WLOGIT, OUT, blg, 8192, 8000, 512);
  }
  k_lsm<<<8192, 256, 0, stream>>>(OUT);
}

// Round 9
// 7146.891 us; speedup vs baseline: 1.2192x; 1.2192x over previous
//
#include <hip/hip_runtime.h>
#include <hip/hip_bf16.h>
#include <stdint.h>

typedef unsigned short u16;
typedef unsigned int u32;
typedef unsigned long long u64;
typedef __attribute__((ext_vector_type(8))) short s16x8;
typedef __attribute__((ext_vector_type(4))) float f32x4;

#define AGT __HIP_MEMORY_SCOPE_AGENT

static __device__ __forceinline__ float bf2f(u16 u){
  unsigned v = ((unsigned)u) << 16; return __builtin_bit_cast(float, v);
}
static __device__ __forceinline__ u16 f2bf(float f){
  unsigned u = __builtin_bit_cast(unsigned, f);
  u += 0x7FFFu + ((u >> 16) & 1u);
  return (u16)(u >> 16);
}
static __device__ __forceinline__ float sigm(float x){ return 1.f / (1.f + __expf(-x)); }

typedef __attribute__((address_space(1))) const u32 gu32;
typedef __attribute__((address_space(3))) u32 lu32;
static __device__ __forceinline__ void gload_lds16(const void* g, void* l){
  __builtin_amdgcn_global_load_lds((gu32*)g, (lu32*)l, 16, 0, 0);
}

// coherent 16B load via two 8B agent-scope atomic loads (served at LLC)
static __device__ __forceinline__ s16x8 aload16(const u16* p){
  union { u64 q[2]; s16x8 v; } u;
  u.q[0] = __hip_atomic_load((const u64*)p,     __ATOMIC_RELAXED, AGT);
  u.q[1] = __hip_atomic_load(((const u64*)p)+1, __ATOMIC_RELAXED, AGT);
  return u.v;
}

// ---- store-only flag lines (one 128B line each, single writer, no RMW) ----
// HGL[g]  (g<32)  : u32 idx g*32          -> holds t+1 when gates wg g wrote h(t)
// RDYL[q] (q<224) : u32 idx (32+q)*32     -> holds t+1 when chunk q wrote partial(t)
// ODL[q]  (q<224) : u32 idx (256+q)*32    -> holds t+1 when chunk q wrote out-slice(t)
#define HGL0   0
#define RDYL0  (32*32)
#define ODL0   (256*32)
#define SY_BYTES (480*128)

static __device__ __forceinline__ void setflag(u32* SYNC, int idx, u32 v){
  asm volatile("s_waitcnt vmcnt(0)" ::: "memory");   // all my stores complete
  __syncthreads();
  if (threadIdx.x == 0)
    __hip_atomic_store(&SYNC[idx], v, __ATOMIC_RELAXED, AGT);
}
// poll nlines lines in parallel (lane i -> line i); store-only lines, load-only polls
template<int SLP>
static __device__ __forceinline__ void await_lines(u32* SYNC, int base, int nlines,
                                                   u32 target){
  if (threadIdx.x < (unsigned)nlines){
    while (__hip_atomic_load(&SYNC[base + threadIdx.x * 32], __ATOMIC_RELAXED, AGT) < target)
      __builtin_amdgcn_s_sleep(SLP);
  }
  __syncthreads();
}

// ---------------- prep kernels ----------------

__global__ __launch_bounds__(256) void k_wfull(const float* __restrict__ wih,
                                               const float* __restrict__ whh,
                                               u16* __restrict__ wf){
  int stride = gridDim.x * blockDim.x;
  for (int i = blockIdx.x * blockDim.x + threadIdx.x; i < 2048 * 1280; i += stride){
    int j = i / 1280, k = i - j * 1280;
    float v = (k < 768) ? wih[j * 768 + k] : whh[j * 512 + (k - 768)];
    wf[i] = f2bf(v);
  }
}

__global__ __launch_bounds__(256) void k_whmt(const float* __restrict__ whm,
                                              u16* __restrict__ wt){
  int stride = gridDim.x * blockDim.x;
  for (int i = blockIdx.x * blockDim.x + threadIdx.x; i < 512 * 512; i += stride){
    int n = i >> 9, k = i & 511;
    wt[i] = f2bf(whm[k * 512 + n]);     // WHMT[a][b] = whm[b][a]
  }
}

__global__ __launch_bounds__(256) void k_cvt(const float* __restrict__ s,
                                             u16* __restrict__ d, int n){
  int stride = gridDim.x * blockDim.x * 4;
  for (int i = (blockIdx.x * blockDim.x + threadIdx.x) * 4; i < n; i += stride){
    float4 v = *(const float4*)&s[i];
    d[i + 0] = f2bf(v.x); d[i + 1] = f2bf(v.y);
    d[i + 2] = f2bf(v.z); d[i + 3] = f2bf(v.w);
  }
}

// xs stored [t][b][e]
__global__ __launch_bounds__(256) void k_xs(const int* __restrict__ seq,
                                            const float* __restrict__ emb,
                                            u16* __restrict__ xs){
  int stride = gridDim.x * blockDim.x;
  for (int i = blockIdx.x * blockDim.x + threadIdx.x; i < 8192 * 256; i += stride){
    int m = i >> 8, e = i & 255;          // m = b*256 + t
    int b = m >> 8, t = m & 255;
    float v = emb[(size_t)seq[m] * 256 + e];
    xs[(size_t)(t * 32 + b) * 256 + e] = f2bf(v > 0.f ? v : 0.f);
  }
}

// ---------------- 128x128 bf16 MFMA GEMM: C = A[M,K] @ B[N,K]^T ----------------

template<int OUTBF, int HASBIAS, int NG>
__global__ __launch_bounds__(256) void k_gemm(const u16* __restrict__ A,
                                              const u16* __restrict__ Bm,
                                              void* __restrict__ Cout,
                                              const float* __restrict__ bias,
                                              int M, int N, int K){
  __shared__ __align__(16) u16 As[128 * 64];
  __shared__ __align__(16) u16 Bs[128 * 64];
  int tid = threadIdx.x; int w = tid >> 6; int l = tid & 63;
  int m0 = blockIdx.x * 128, n0 = blockIdx.y * 128;
  int wr = w >> 1, wc = w & 1;
  f32x4 acc[4][4];
#pragma unroll
  for (int a = 0; a < 4; a++)
#pragma unroll
    for (int b = 0; b < 4; b++){ f32x4 z = {0.f,0.f,0.f,0.f}; acc[a][b] = z; }
  int rA = m0 + (tid >> 3);
  int rB = n0 + (tid >> 3);
  for (int k0 = 0; k0 < K; k0 += 64){
    __syncthreads();
    int ca = k0 + (tid & 7) * 8;
#pragma unroll
    for (int i = 0; i < 4; i++){
      gload_lds16(&A[(size_t)(rA + i * 32) * K + ca], &As[i * 2048 + w * 512]);
      int rb = rB + i * 32;
      if (NG) rb = (rb < N - 1) ? rb : (N - 1);
      gload_lds16(&Bm[(size_t)rb * K + ca], &Bs[i * 2048 + w * 512]);
    }
    asm volatile("s_waitcnt vmcnt(0)" ::: "memory");
    __syncthreads();
#pragma unroll
    for (int ks = 0; ks < 2; ks++){
      s16x8 av[4], bv[4];
      int ko = ks * 32 + (l >> 4) * 8;
#pragma unroll
      for (int i = 0; i < 4; i++) av[i] = *(const s16x8*)&As[(wr * 64 + i * 16 + (l & 15)) * 64 + ko];
#pragma unroll
      for (int i = 0; i < 4; i++) bv[i] = *(const s16x8*)&Bs[(wc * 64 + i * 16 + (l & 15)) * 64 + ko];
#pragma unroll
      for (int mi = 0; mi < 4; mi++)
#pragma unroll
        for (int ni = 0; ni < 4; ni++)
          acc[mi][ni] = __builtin_amdgcn_mfma_f32_16x16x32_bf16(av[mi], bv[ni], acc[mi][ni], 0, 0, 0);
    }
  }
#pragma unroll
  for (int mi = 0; mi < 4; mi++)
#pragma unroll
    for (int ni = 0; ni < 4; ni++){
      int row = m0 + wr * 64 + mi * 16 + (l >> 4) * 4;
      int col = n0 + wc * 64 + ni * 16 + (l & 15);
      if (NG && col >= N) continue;
#pragma unroll
      for (int r = 0; r < 4; r++){
        float v = acc[mi][ni][r];
        if (HASBIAS) v += bias[col];
        if (OUTBF) ((u16*)Cout)[(size_t)(row + r) * N + col] = f2bf(v);
        else       ((float*)Cout)[(size_t)(row + r) * N + col] = v;
      }
    }
}

// ---------------- gates role (gid<32): W pinned in VGPRs ----------------

static __device__ void gates_role(const u16* __restrict__ WF, const u16* __restrict__ XS,
                                  u16* __restrict__ Z, float* __restrict__ CST,
                                  u32* __restrict__ SYNC, float* __restrict__ SM, int g){
  const int tid = threadIdx.x, w = tid >> 6, l = tid & 63;
  const int ns = g << 4;
  float (*red)[32][64] = (float(*)[32][64])SM;

  // pin step-invariant W slices: x(8) + h(16) + out(16) s16x8 = 160 VGPR
  s16x8 bx[2][4], bh[4][4], bo[4][4];
#pragma unroll
  for (int ki = 0; ki < 2; ki++){
    int ko = w * 64 + ki * 32 + (l >> 4) * 8;
#pragma unroll
    for (int gi = 0; gi < 4; gi++)
      bx[ki][gi] = *(const s16x8*)&WF[(size_t)(gi * 512 + ns + (l & 15)) * 1280 + ko];
  }
#pragma unroll
  for (int ki = 0; ki < 4; ki++){
    int koh = 768 + w * 128 + ki * 32 + (l >> 4) * 8;
    int koo = 256 + w * 128 + ki * 32 + (l >> 4) * 8;
#pragma unroll
    for (int gi = 0; gi < 4; gi++){
      bh[ki][gi] = *(const s16x8*)&WF[(size_t)(gi * 512 + ns + (l & 15)) * 1280 + koh];
      bo[ki][gi] = *(const s16x8*)&WF[(size_t)(gi * 512 + ns + (l & 15)) * 1280 + koo];
    }
  }

  for (int t = 0; t < 256; ++t){
    u16* Zn = Z + (t & 1) * 32768;
    const u16* Zp = Z + ((t + 1) & 1) * 32768;
    f32x4 acc[2][4];
#pragma unroll
    for (int a = 0; a < 2; a++)
#pragma unroll
      for (int b = 0; b < 4; b++){ f32x4 z = {0.f,0.f,0.f,0.f}; acc[a][b] = z; }

    // x segment (no dependency)
#pragma unroll
    for (int ki = 0; ki < 2; ki++){
      int ko = w * 64 + ki * 32 + (l >> 4) * 8;
      s16x8 av[2];
#pragma unroll
      for (int mi = 0; mi < 2; mi++)
        av[mi] = *(const s16x8*)&XS[(size_t)(t * 32 + mi * 16 + (l & 15)) * 256 + ko];
#pragma unroll
      for (int mi = 0; mi < 2; mi++)
#pragma unroll
        for (int gi = 0; gi < 4; gi++)
          acc[mi][gi] = __builtin_amdgcn_mfma_f32_16x16x32_bf16(av[mi], bx[ki][gi], acc[mi][gi], 0, 0, 0);
    }
    if (t > 0){
      await_lines<4>(SYNC, HGL0, 32, (u32)t);       // h(t-1) complete (all 32 wgs)
#pragma unroll
      for (int ki = 0; ki < 4; ki++){
        int ko = 768 + w * 128 + ki * 32 + (l >> 4) * 8;
        s16x8 av[2];
#pragma unroll
        for (int mi = 0; mi < 2; mi++)
          av[mi] = aload16(&Zp[(size_t)(mi * 16 + (l & 15)) * 1024 + (ko - 256)]);
#pragma unroll
        for (int mi = 0; mi < 2; mi++)
#pragma unroll
          for (int gi = 0; gi < 4; gi++)
            acc[mi][gi] = __builtin_amdgcn_mfma_f32_16x16x32_bf16(av[mi], bh[ki][gi], acc[mi][gi], 0, 0, 0);
      }
      await_lines<4>(SYNC, ODL0, 224, (u32)t);      // out(t-1) complete (all 224 chunks)
#pragma unroll
      for (int ki = 0; ki < 4; ki++){
        int ko = 256 + w * 128 + ki * 32 + (l >> 4) * 8;
        s16x8 av[2];
#pragma unroll
        for (int mi = 0; mi < 2; mi++)
          av[mi] = aload16(&Zp[(size_t)(mi * 16 + (l & 15)) * 1024 + (ko - 256)]);
#pragma unroll
        for (int mi = 0; mi < 2; mi++)
#pragma unroll
          for (int gi = 0; gi < 4; gi++)
            acc[mi][gi] = __builtin_amdgcn_mfma_f32_16x16x32_bf16(av[mi], bo[ki][gi], acc[mi][gi], 0, 0, 0);
      }
    }
    // cross-wave reduce + LSTM
#pragma unroll
    for (int mi = 0; mi < 2; mi++)
#pragma unroll
      for (int gi = 0; gi < 4; gi++)
#pragma unroll
        for (int r = 0; r < 4; r++)
          red[w][mi * 16 + (l >> 4) * 4 + r][gi * 16 + (l & 15)] = acc[mi][gi][r];
    __syncthreads();
    {
      int bi = tid >> 3, j = (tid & 7) * 2;
      float iv0=0,fv0=0,gv0=0,ov0=0, iv1=0,fv1=0,gv1=0,ov1=0;
#pragma unroll
      for (int qq = 0; qq < 4; qq++){
        iv0 += red[qq][bi][j];      fv0 += red[qq][bi][16 + j];
        gv0 += red[qq][bi][32 + j]; ov0 += red[qq][bi][48 + j];
        iv1 += red[qq][bi][j + 1];      fv1 += red[qq][bi][16 + j + 1];
        gv1 += red[qq][bi][32 + j + 1]; ov1 += red[qq][bi][48 + j + 1];
      }
      int n0 = ns + j;
      float c0 = (t > 0) ? CST[bi * 512 + n0]     : 0.f;
      float c1 = (t > 0) ? CST[bi * 512 + n0 + 1] : 0.f;
      float cn0 = sigm(fv0) * c0 + sigm(iv0) * tanhf(gv0);
      float cn1 = sigm(fv1) * c1 + sigm(iv1) * tanhf(gv1);
      float h0 = sigm(ov0) * tanhf(cn0);
      float h1 = sigm(ov1) * tanhf(cn1);
      CST[bi * 512 + n0] = cn0; CST[bi * 512 + n0 + 1] = cn1;
      u32 pk = (u32)f2bf(h0) | ((u32)f2bf(h1) << 16);
      __hip_atomic_store((u32*)(Zn + bi * 1024 + 512 + n0), pk, __ATOMIC_RELAXED, AGT);
    }
    setflag(SYNC, HGL0 + g * 32, (u32)(t + 1));
  }
}

// ---------------- attn+out role (gid>=32): V and CNN2 rows pinned in VGPRs ----------------

static __device__ void attn_role(const u16* __restrict__ CNN2, const u16* __restrict__ CNNB,
                                 const u16* __restrict__ WOUT, u16* __restrict__ Z,
                                 float* __restrict__ UPART, float* __restrict__ MS,
                                 u16* __restrict__ OALL, u32* __restrict__ SYNC,
                                 float* __restrict__ SM, int q){
  const int tid = threadIdx.x, w = tid >> 6, ln = tid & 63;
  const int b = q / 7, ch = q - b * 7;
  const int l0 = ch * 112;
  const int nc = (ch == 6) ? 68 : 74, cs = ch * 74;
  float* sc   = SM;          // [112]
  float* sred = SM + 112;    // [4]
  float* msh  = SM + 120;    // [14]
  float* csf  = SM + 144;    // [512]
  float* hsf  = SM + 656;    // [512]
  float* accw = SM + 1184;   // [4*512]
  float* ored = SM + 3232;   // [160]

  // pin V rows and CNN2 rows (step-invariant): 56 s16x8 = 224 VGPR
  s16x8 rowv[28], c2v[28];
  {
    const u16* vb = CNNB + ((size_t)(b * 784 + l0)) * 512 + ln * 8;
    const u16* cb = CNN2 + ((size_t)(b * 784 + l0)) * 512 + ln * 8;
#pragma unroll
    for (int i = 0; i < 28; i++){
      rowv[i] = *(const s16x8*)(vb + (size_t)(w + 4 * i) * 512);
      c2v[i]  = *(const s16x8*)(cb + (size_t)(w + 4 * i) * 512);
    }
  }

  for (int t = 0; t < 256; ++t){
    await_lines<8>(SYNC, HGL0, 32, (u32)(t + 1));   // h(t) complete
    u16* Zpar = Z + (t & 1) * 32768;
    float mp[8];
    {
      s16x8 hv = aload16(Zpar + b * 1024 + 512 + ln * 8);
#pragma unroll
      for (int j = 0; j < 8; j++) mp[j] = bf2f((u16)hv[j]);
    }
    // scores from pinned CNN2 rows
    float wmax = -1e30f;
#pragma unroll
    for (int i = 0; i < 28; i++){
      float d = 0.f;
#pragma unroll
      for (int j = 0; j < 8; j++) d = fmaf(mp[j], bf2f((u16)c2v[i][j]), d);
#pragma unroll
      for (int m = 1; m < 64; m <<= 1) d += __shfl_xor(d, m, 64);
      if (ln == 0) sc[w + 4 * i] = d;
      wmax = fmaxf(wmax, d);
    }
    if (ln == 0) sred[w] = wmax;
    __syncthreads();
    float M = fmaxf(fmaxf(sred[0], sred[1]), fmaxf(sred[2], sred[3]));
    __syncthreads();
    float s = 0.f;
    if (tid < 112){ float p = __expf(sc[tid] - M); sc[tid] = p; s = p; }
#pragma unroll
    for (int m = 1; m < 64; m <<= 1) s += __shfl_xor(s, m, 64);
    if (ln == 0) sred[w] = s;
    __syncthreads();
    float S = sred[0] + sred[1] + sred[2] + sred[3];
    // weighted V from pinned registers
    float a8[8] = {0.f,0.f,0.f,0.f,0.f,0.f,0.f,0.f};
#pragma unroll
    for (int i = 0; i < 28; i++){
      float p = sc[w + 4 * i];
#pragma unroll
      for (int j = 0; j < 8; j++) a8[j] = fmaf(p, bf2f((u16)rowv[i][j]), a8[j]);
    }
    {
      f32x4 x0 = {a8[0], a8[1], a8[2], a8[3]};
      f32x4 x1 = {a8[4], a8[5], a8[6], a8[7]};
      *(f32x4*)&accw[w * 512 + ln * 8]     = x0;
      *(f32x4*)&accw[w * 512 + ln * 8 + 4] = x1;
    }
    __syncthreads();
    int e0 = 2 * tid;
    {
      float u0 = accw[e0] + accw[512 + e0] + accw[1024 + e0] + accw[1536 + e0];
      float u1 = accw[e0+1] + accw[512 + e0+1] + accw[1024 + e0+1] + accw[1536 + e0+1];
      union { u64 qv; float f[2]; } uu; uu.f[0] = u0; uu.f[1] = u1;
      __hip_atomic_store((u64*)(UPART + ((size_t)(b * 7 + ch) * 512 + e0)), uu.qv,
                         __ATOMIC_RELAXED, AGT);
      if (tid == 0){
        union { u64 qv; float f[2]; } mm; mm.f[0] = M; mm.f[1] = S;
        __hip_atomic_store((u64*)(MS + (b * 7 + ch) * 2), mm.qv, __ATOMIC_RELAXED, AGT);
      }
    }
    setflag(SYNC, RDYL0 + q * 32, (u32)(t + 1));
    await_lines<2>(SYNC, RDYL0 + b * 7 * 32, 7, (u32)(t + 1));  // all 7 partials
    if (tid < 7){
      union { u64 qv; float f[2]; } a;
      a.qv = __hip_atomic_load((const u64*)(MS + (b * 7 + tid) * 2), __ATOMIC_RELAXED, AGT);
      msh[2 * tid] = a.f[0]; msh[2 * tid + 1] = a.f[1];
    }
    __syncthreads();
    float Mg = -1e30f;
#pragma unroll
    for (int c = 0; c < 7; c++) Mg = fmaxf(Mg, msh[2 * c]);
    float bet[7]; float Sg = 0.f;
#pragma unroll
    for (int c = 0; c < 7; c++){
      float e = __expf(msh[2 * c] - Mg);
      bet[c] = e; Sg += e * msh[2 * c + 1];
    }
    float inv = 1.f / Sg;
    {
      float c0 = 0.f, c1 = 0.f;
#pragma unroll
      for (int c = 0; c < 7; c++){
        union { u64 qv; float f[2]; } a;
        a.qv = __hip_atomic_load((const u64*)(UPART + ((size_t)(b * 7 + c) * 512 + e0)),
                                 __ATOMIC_RELAXED, AGT);
        float bc = bet[c] * inv;
        c0 = fmaf(bc, a.f[0], c0); c1 = fmaf(bc, a.f[1], c1);
      }
      csf[e0] = c0; csf[e0 + 1] = c1;
      u32 hv2 = __hip_atomic_load((const u32*)(Zpar + b * 1024 + 512 + e0),
                                  __ATOMIC_RELAXED, AGT);
      hsf[e0] = bf2f((u16)(hv2 & 0xffff)); hsf[e0 + 1] = bf2f((u16)(hv2 >> 16));
    }
    __syncthreads();
    // out slice: cols [cs, cs+nc), (col, K-half) per thread
    if (tid < 2 * nc){
      int col = cs + (tid >> 1), half = tid & 1;
      const s16x8* wr = (const s16x8*)(WOUT + (size_t)col * 1024 + half * 512);
      const float* src = half ? hsf : csf;
      float o = 0.f;
      for (int kk = 0; kk < 64; kk++){
        s16x8 qv = wr[kk];
#pragma unroll
        for (int j = 0; j < 8; j++) o = fmaf(src[kk * 8 + j], bf2f((u16)qv[j]), o);
      }
      ored[tid] = o;
    }
    __syncthreads();
    if (tid < (nc >> 1)){
      int q0 = 2 * tid, q1 = 2 * tid + 1;
      float v0 = tanhf(ored[2 * q0] + ored[2 * q0 + 1]);
      float v1 = tanhf(ored[2 * q1] + ored[2 * q1 + 1]);
      u32 pk = (u32)f2bf(v0) | ((u32)f2bf(v1) << 16);
      __hip_atomic_store((u32*)(Zpar + b * 1024 + cs + q0), pk, __ATOMIC_RELAXED, AGT);
      *(u32*)&OALL[((size_t)(b * 256 + t)) * 512 + cs + q0] = pk;
    }
    setflag(SYNC, ODL0 + q * 32, (u32)(t + 1));
  }
}

// ---------------- persistent decoder ----------------

__global__ __launch_bounds__(256, 1) void k_persist(const u16* __restrict__ WF,
                                                    const u16* __restrict__ XS,
                                                    const u16* __restrict__ CNN2,
                                                    const u16* __restrict__ CNNB,
                                                    const u16* __restrict__ WOUT,
                                                    u16* __restrict__ Z,
                                                    float* __restrict__ CST,
                                                    float* __restrict__ UPART,
                                                    float* __restrict__ MS,
                                                    u16* __restrict__ OALL,
                                                    u32* __restrict__ SYNC){
  __shared__ __align__(16) float SM[8192];
  int gid = blockIdx.x;
  if (gid < 32)
    gates_role(WF, XS, Z, CST, SYNC, SM, gid);
  else
    attn_role(CNN2, CNNB, WOUT, Z, UPART, MS, OALL, SYNC, SM, gid - 32);
}

// ---------------- log_softmax ----------------

__global__ __launch_bounds__(256) void k_lsm(float* __restrict__ x){
  size_t base = (size_t)blockIdx.x * 8000;
  int tid = threadIdx.x, w = tid >> 6, ln = tid & 63;
  __shared__ float sred[4];
  float m = -1e30f;
  for (int v = tid; v < 8000; v += 256) m = fmaxf(m, x[base + v]);
#pragma unroll
  for (int mk = 1; mk < 64; mk <<= 1) m = fmaxf(m, __shfl_xor(m, mk, 64));
  if (ln == 0) sred[w] = m;
  __syncthreads();
  float M = fmaxf(fmaxf(sred[0], sred[1]), fmaxf(sred[2], sred[3]));
  __syncthreads();
  float s = 0.f;
  for (int v = tid; v < 8000; v += 256) s += __expf(x[base + v] - M);
#pragma unroll
  for (int mk = 1; mk < 64; mk <<= 1) s += __shfl_xor(s, mk, 64);
  if (ln == 0) sred[w] = s;
  __syncthreads();
  float S = sred[0] + sred[1] + sred[2] + sred[3];
  float lz = M + logf(S);
  for (int v = tid; v < 8000; v += 256) x[base + v] -= lz;
}

// ---------------- launcher ----------------

extern "C" void kernel_launch(void* const* d_in, const int* in_sizes, int n_in,
                              void* d_out, int out_size, void* d_ws, size_t ws_size,
                              hipStream_t stream){
  const float* cnn  = (const float*)d_in[0];
  const int*   seq  = (const int*)d_in[1];
  const float* emb  = (const float*)d_in[2];
  const float* wih  = (const float*)d_in[3];
  const float* whh  = (const float*)d_in[4];
  const float* whm  = (const float*)d_in[5];
  const float* wo   = (const float*)d_in[6];
  const float* wlg  = (const float*)d_in[7];
  const float* blg  = (const float*)d_in[8];

  char* ws = (char*)d_ws;
  u16*   WF     = (u16*)(ws + 0);          // 2048x1280 bf16 = 5,242,880
  u16*   WHMT   = (u16*)(ws + 5242880);    // 512x512 bf16   =   524,288
  u16*   WOUT   = (u16*)(ws + 5767168);    // 512x1024 bf16  = 1,048,576
  u16*   WLOGIT = (u16*)(ws + 6815744);    // 8000x512 bf16  = 8,192,000
  u16*   CNNBF  = (u16*)(ws + 15007744);   // 25088x512 bf16 = 25,690,112
  u16*   CNN2   = (u16*)(ws + 40697856);   // 25088x512 bf16 = 25,690,112
  u16*   XS     = (u16*)(ws + 66387968);   // [256][32][256] bf16 = 4,194,304
  u16*   OALL   = (u16*)(ws + 70582272);   // 8192x512 bf16  = 8,388,608
  u16*   Z      = (u16*)(ws + 78970880);   // [2][32][1024] bf16 = 131,072
  float* CST    = (float*)(ws + 79101952); // 32x512 f32     = 65,536
  float* UPART  = (float*)(ws + 79167488); // [32][7][512] f32 = 458,752
  float* MS     = (float*)(ws + 79626240); // [32][7][2] f32 (pad 2048)
  u32*   SYNC   = (u32*)(ws + 79628288);   // 61,440 B -> ends 79,689,728

  float* OUT = (float*)d_out;

  (void)hipMemsetAsync(SYNC, 0, SY_BYTES, stream);
  k_wfull<<<512, 256, 0, stream>>>(wih, whh, WF);
  k_whmt<<<128, 256, 0, stream>>>(whm, WHMT);
  k_cvt<<<512, 256, 0, stream>>>(wo, WOUT, 512 * 1024);
  k_cvt<<<2048, 256, 0, stream>>>(wlg, WLOGIT, 8000 * 512);
  k_cvt<<<2048, 256, 0, stream>>>(cnn, CNNBF, 25088 * 512);
  k_xs<<<2048, 256, 0, stream>>>(seq, emb, XS);

  {
    dim3 g(196, 4);   // CNN2 = CNNB @ WHMT^T : scores key matrix
    k_gemm<1, 0, 0><<<g, 256, 0, stream>>>(CNNBF, WHMT, CNN2, nullptr, 25088, 512, 512);
  }

  k_persist<<<256, 256, 0, stream>>>(WF, XS, CNN2, CNNBF, WOUT, Z, CST, UPART, MS, OALL, SYNC);

  {
    dim3 g(64, 63);
    k_gemm<0, 1, 1><<<g, 256, 0, stream>>>(OALL, WLOGIT, OUT, blg, 8192, 8000, 512);
  }
  k_lsm<<<8192, 256, 0, stream>>>(OUT);
}

// Round 10
// 4656.050 us; speedup vs baseline: 1.8714x; 1.5350x over previous
//
#include <hip/hip_runtime.h>
#include <hip/hip_bf16.h>
#include <stdint.h>

typedef unsigned short u16;
typedef unsigned int u32;
typedef unsigned long long u64;
typedef __attribute__((ext_vector_type(8))) short s16x8;
typedef __attribute__((ext_vector_type(4))) float f32x4;

#define AGT __HIP_MEMORY_SCOPE_AGENT

static __device__ __forceinline__ float bf2f(u16 u){
  unsigned v = ((unsigned)u) << 16; return __builtin_bit_cast(float, v);
}
static __device__ __forceinline__ u16 f2bf(float f){
  unsigned u = __builtin_bit_cast(unsigned, f);
  u += 0x7FFFu + ((u >> 16) & 1u);
  return (u16)(u >> 16);
}
static __device__ __forceinline__ float sigm(float x){ return 1.f / (1.f + __expf(-x)); }

typedef __attribute__((address_space(1))) const u32 gu32;
typedef __attribute__((address_space(3))) u32 lu32;
static __device__ __forceinline__ void gload_lds16(const void* g, void* l){
  __builtin_amdgcn_global_load_lds((gu32*)g, (lu32*)l, 16, 0, 0);
}

// coherent 16B load via two 8B agent-scope atomic loads (served at LLC)
static __device__ __forceinline__ s16x8 aload16(const u16* p){
  union { u64 q[2]; s16x8 v; } u;
  u.q[0] = __hip_atomic_load((const u64*)p,     __ATOMIC_RELAXED, AGT);
  u.q[1] = __hip_atomic_load(((const u64*)p)+1, __ATOMIC_RELAXED, AGT);
  return u.v;
}

// ---- store-only flag lines (one 128B line each, single writer, no RMW) ----
#define HGL0   0
#define RDYL0  (32*32)
#define ODL0   (256*32)
#define SY_BYTES (480*128)

static __device__ __forceinline__ void setflag(u32* SYNC, int idx, u32 v){
  asm volatile("s_waitcnt vmcnt(0)" ::: "memory");
  __syncthreads();
  if (threadIdx.x == 0)
    __hip_atomic_store(&SYNC[idx], v, __ATOMIC_RELAXED, AGT);
}
template<int SLP>
static __device__ __forceinline__ void await_lines(u32* SYNC, int base, int nlines,
                                                   u32 target){
  if (threadIdx.x < (unsigned)nlines){
    while (__hip_atomic_load(&SYNC[base + threadIdx.x * 32], __ATOMIC_RELAXED, AGT) < target)
      __builtin_amdgcn_s_sleep(SLP);
  }
  __syncthreads();
}

// ---------------- prep kernels ----------------

__global__ __launch_bounds__(256) void k_wfull(const float* __restrict__ wih,
                                               const float* __restrict__ whh,
                                               u16* __restrict__ wf){
  int stride = gridDim.x * blockDim.x;
  for (int i = blockIdx.x * blockDim.x + threadIdx.x; i < 2048 * 1280; i += stride){
    int j = i / 1280, k = i - j * 1280;
    float v = (k < 768) ? wih[j * 768 + k] : whh[j * 512 + (k - 768)];
    wf[i] = f2bf(v);
  }
}

__global__ __launch_bounds__(256) void k_whmt(const float* __restrict__ whm,
                                              u16* __restrict__ wt){
  int stride = gridDim.x * blockDim.x;
  for (int i = blockIdx.x * blockDim.x + threadIdx.x; i < 512 * 512; i += stride){
    int n = i >> 9, k = i & 511;
    wt[i] = f2bf(whm[k * 512 + n]);
  }
}

__global__ __launch_bounds__(256) void k_cvt(const float* __restrict__ s,
                                             u16* __restrict__ d, int n){
  int stride = gridDim.x * blockDim.x * 4;
  for (int i = (blockIdx.x * blockDim.x + threadIdx.x) * 4; i < n; i += stride){
    float4 v = *(const float4*)&s[i];
    d[i + 0] = f2bf(v.x); d[i + 1] = f2bf(v.y);
    d[i + 2] = f2bf(v.z); d[i + 3] = f2bf(v.w);
  }
}

__global__ __launch_bounds__(256) void k_xs(const int* __restrict__ seq,
                                            const float* __restrict__ emb,
                                            u16* __restrict__ xs){
  int stride = gridDim.x * blockDim.x;
  for (int i = blockIdx.x * blockDim.x + threadIdx.x; i < 8192 * 256; i += stride){
    int m = i >> 8, e = i & 255;
    int b = m >> 8, t = m & 255;
    float v = emb[(size_t)seq[m] * 256 + e];
    xs[(size_t)(t * 32 + b) * 256 + e] = f2bf(v > 0.f ? v : 0.f);
  }
}

// ---------------- 128x128 bf16 MFMA GEMM: C = A[M,K] @ B[N,K]^T ----------------

template<int OUTBF, int HASBIAS, int NG>
__global__ __launch_bounds__(256) void k_gemm(const u16* __restrict__ A,
                                              const u16* __restrict__ Bm,
                                              void* __restrict__ Cout,
                                              const float* __restrict__ bias,
                                              int M, int N, int K){
  __shared__ __align__(16) u16 As[128 * 64];
  __shared__ __align__(16) u16 Bs[128 * 64];
  int tid = threadIdx.x; int w = tid >> 6; int l = tid & 63;
  int m0 = blockIdx.x * 128, n0 = blockIdx.y * 128;
  int wr = w >> 1, wc = w & 1;
  f32x4 acc[4][4];
#pragma unroll
  for (int a = 0; a < 4; a++)
#pragma unroll
    for (int b = 0; b < 4; b++){ f32x4 z = {0.f,0.f,0.f,0.f}; acc[a][b] = z; }
  int rA = m0 + (tid >> 3);
  int rB = n0 + (tid >> 3);
  for (int k0 = 0; k0 < K; k0 += 64){
    __syncthreads();
    int ca = k0 + (tid & 7) * 8;
#pragma unroll
    for (int i = 0; i < 4; i++){
      gload_lds16(&A[(size_t)(rA + i * 32) * K + ca], &As[i * 2048 + w * 512]);
      int rb = rB + i * 32;
      if (NG) rb = (rb < N - 1) ? rb : (N - 1);
      gload_lds16(&Bm[(size_t)rb * K + ca], &Bs[i * 2048 + w * 512]);
    }
    asm volatile("s_waitcnt vmcnt(0)" ::: "memory");
    __syncthreads();
#pragma unroll
    for (int ks = 0; ks < 2; ks++){
      s16x8 av[4], bv[4];
      int ko = ks * 32 + (l >> 4) * 8;
#pragma unroll
      for (int i = 0; i < 4; i++) av[i] = *(const s16x8*)&As[(wr * 64 + i * 16 + (l & 15)) * 64 + ko];
#pragma unroll
      for (int i = 0; i < 4; i++) bv[i] = *(const s16x8*)&Bs[(wc * 64 + i * 16 + (l & 15)) * 64 + ko];
#pragma unroll
      for (int mi = 0; mi < 4; mi++)
#pragma unroll
        for (int ni = 0; ni < 4; ni++)
          acc[mi][ni] = __builtin_amdgcn_mfma_f32_16x16x32_bf16(av[mi], bv[ni], acc[mi][ni], 0, 0, 0);
    }
  }
#pragma unroll
  for (int mi = 0; mi < 4; mi++)
#pragma unroll
    for (int ni = 0; ni < 4; ni++){
      int row = m0 + wr * 64 + mi * 16 + (l >> 4) * 4;
      int col = n0 + wc * 64 + ni * 16 + (l & 15);
      if (NG && col >= N) continue;
#pragma unroll
      for (int r = 0; r < 4; r++){
        float v = acc[mi][ni][r];
        if (HASBIAS) v += bias[col];
        if (OUTBF) ((u16*)Cout)[(size_t)(row + r) * N + col] = f2bf(v);
        else       ((float*)Cout)[(size_t)(row + r) * N + col] = v;
      }
    }
}

// ---------------- gates role (gid<32): W pinned in VGPRs (unchanged, verified) ----------------

static __device__ void gates_role(const u16* __restrict__ WF, const u16* __restrict__ XS,
                                  u16* __restrict__ Z, float* __restrict__ CST,
                                  u32* __restrict__ SYNC, float* __restrict__ SM, int g){
  const int tid = threadIdx.x, w = tid >> 6, l = tid & 63;
  const int ns = g << 4;
  float (*red)[32][64] = (float(*)[32][64])SM;

  s16x8 bx[2][4], bh[4][4], bo[4][4];
#pragma unroll
  for (int ki = 0; ki < 2; ki++){
    int ko = w * 64 + ki * 32 + (l >> 4) * 8;
#pragma unroll
    for (int gi = 0; gi < 4; gi++)
      bx[ki][gi] = *(const s16x8*)&WF[(size_t)(gi * 512 + ns + (l & 15)) * 1280 + ko];
  }
#pragma unroll
  for (int ki = 0; ki < 4; ki++){
    int koh = 768 + w * 128 + ki * 32 + (l >> 4) * 8;
    int koo = 256 + w * 128 + ki * 32 + (l >> 4) * 8;
#pragma unroll
    for (int gi = 0; gi < 4; gi++){
      bh[ki][gi] = *(const s16x8*)&WF[(size_t)(gi * 512 + ns + (l & 15)) * 1280 + koh];
      bo[ki][gi] = *(const s16x8*)&WF[(size_t)(gi * 512 + ns + (l & 15)) * 1280 + koo];
    }
  }

  for (int t = 0; t < 256; ++t){
    u16* Zn = Z + (t & 1) * 32768;
    const u16* Zp = Z + ((t + 1) & 1) * 32768;
    f32x4 acc[2][4];
#pragma unroll
    for (int a = 0; a < 2; a++)
#pragma unroll
      for (int b = 0; b < 4; b++){ f32x4 z = {0.f,0.f,0.f,0.f}; acc[a][b] = z; }

#pragma unroll
    for (int ki = 0; ki < 2; ki++){
      int ko = w * 64 + ki * 32 + (l >> 4) * 8;
      s16x8 av[2];
#pragma unroll
      for (int mi = 0; mi < 2; mi++)
        av[mi] = *(const s16x8*)&XS[(size_t)(t * 32 + mi * 16 + (l & 15)) * 256 + ko];
#pragma unroll
      for (int mi = 0; mi < 2; mi++)
#pragma unroll
        for (int gi = 0; gi < 4; gi++)
          acc[mi][gi] = __builtin_amdgcn_mfma_f32_16x16x32_bf16(av[mi], bx[ki][gi], acc[mi][gi], 0, 0, 0);
    }
    if (t > 0){
      await_lines<1>(SYNC, HGL0, 32, (u32)t);
#pragma unroll
      for (int ki = 0; ki < 4; ki++){
        int ko = 768 + w * 128 + ki * 32 + (l >> 4) * 8;
        s16x8 av[2];
#pragma unroll
        for (int mi = 0; mi < 2; mi++)
          av[mi] = aload16(&Zp[(size_t)(mi * 16 + (l & 15)) * 1024 + (ko - 256)]);
#pragma unroll
        for (int mi = 0; mi < 2; mi++)
#pragma unroll
          for (int gi = 0; gi < 4; gi++)
            acc[mi][gi] = __builtin_amdgcn_mfma_f32_16x16x32_bf16(av[mi], bh[ki][gi], acc[mi][gi], 0, 0, 0);
      }
      await_lines<1>(SYNC, ODL0, 224, (u32)t);
#pragma unroll
      for (int ki = 0; ki < 4; ki++){
        int ko = 256 + w * 128 + ki * 32 + (l >> 4) * 8;
        s16x8 av[2];
#pragma unroll
        for (int mi = 0; mi < 2; mi++)
          av[mi] = aload16(&Zp[(size_t)(mi * 16 + (l & 15)) * 1024 + (ko - 256)]);
#pragma unroll
        for (int mi = 0; mi < 2; mi++)
#pragma unroll
          for (int gi = 0; gi < 4; gi++)
            acc[mi][gi] = __builtin_amdgcn_mfma_f32_16x16x32_bf16(av[mi], bo[ki][gi], acc[mi][gi], 0, 0, 0);
      }
    }
#pragma unroll
    for (int mi = 0; mi < 2; mi++)
#pragma unroll
      for (int gi = 0; gi < 4; gi++)
#pragma unroll
        for (int r = 0; r < 4; r++)
          red[w][mi * 16 + (l >> 4) * 4 + r][gi * 16 + (l & 15)] = acc[mi][gi][r];
    __syncthreads();
    {
      int bi = tid >> 3, j = (tid & 7) * 2;
      float iv0=0,fv0=0,gv0=0,ov0=0, iv1=0,fv1=0,gv1=0,ov1=0;
#pragma unroll
      for (int qq = 0; qq < 4; qq++){
        iv0 += red[qq][bi][j];      fv0 += red[qq][bi][16 + j];
        gv0 += red[qq][bi][32 + j]; ov0 += red[qq][bi][48 + j];
        iv1 += red[qq][bi][j + 1];      fv1 += red[qq][bi][16 + j + 1];
        gv1 += red[qq][bi][32 + j + 1]; ov1 += red[qq][bi][48 + j + 1];
      }
      int n0 = ns + j;
      float c0 = (t > 0) ? CST[bi * 512 + n0]     : 0.f;
      float c1 = (t > 0) ? CST[bi * 512 + n0 + 1] : 0.f;
      float cn0 = sigm(fv0) * c0 + sigm(iv0) * tanhf(gv0);
      float cn1 = sigm(fv1) * c1 + sigm(iv1) * tanhf(gv1);
      float h0 = sigm(ov0) * tanhf(cn0);
      float h1 = sigm(ov1) * tanhf(cn1);
      CST[bi * 512 + n0] = cn0; CST[bi * 512 + n0 + 1] = cn1;
      u32 pk = (u32)f2bf(h0) | ((u32)f2bf(h1) << 16);
      __hip_atomic_store((u32*)(Zn + bi * 1024 + 512 + n0), pk, __ATOMIC_RELAXED, AGT);
    }
    setflag(SYNC, HGL0 + g * 32, (u32)(t + 1));
  }
}

// ---------------- attn+out role (gid>=32): all GEMVs via broadcast-operand MFMA ----------------
// chunk q = (b, ch): L-rows [ch*112, +112), out-cols [ch*74, +nc)
// LDS word map (within SM[8192] f32):
//  hsh  u16[512]   @ word 0     (h bf16)
//  pbf  u16[128]   @ word 256   (p bf16, zero-padded 112..127)
//  sc   f32[128]   @ word 320   (scores / p f32)
//  scp  f32[4][112]@ word 448   (score K-partials per wave)
//  msh  f32[14]    @ word 896
//  zsh  u32[512]   @ word 912   ([ctx|h] bf16 pairs)
//  opart f32[4][80]@ word 1424

static __device__ void attn_role(const u16* __restrict__ CNN2, const u16* __restrict__ CNNB,
                                 const u16* __restrict__ WOUT, u16* __restrict__ Z,
                                 float* __restrict__ UPART, float* __restrict__ MS,
                                 u16* __restrict__ OALL, u32* __restrict__ SYNC,
                                 float* __restrict__ SM, int q){
  const int tid = threadIdx.x, w = tid >> 6, l = tid & 63;
  const int b = q / 7, ch = q - b * 7;
  const int l0 = ch * 112;
  const int nc = (ch == 6) ? 68 : 74, cs = ch * 74;
  u16*   hsh  = (u16*)SM;
  u16*   pbf  = (u16*)(SM + 256);
  float* sc   = SM + 320;
  float* scp  = SM + 448;
  float* msh  = SM + 896;
  u32*   zsh  = (u32*)(SM + 912);
  float* opart= SM + 1424;

  // pin scores-A (C2 rows, wave K-slice 128) and PV-B (V column slices): 60 s16x8 = 240 VGPR
  s16x8 a2[7][4];    // [tile][kk]  A row = l0 + tile*16 + (l&15), k = w*128 + kk*32 + (l>>4)*8
  s16x8 vb[8][4];    // [nt][kk]    B col = w*128 + nt*16 + (l&15), k(Lrow) = kk*32 + (l>>4)*8 + j
#pragma unroll
  for (int tile = 0; tile < 7; tile++)
#pragma unroll
    for (int kk = 0; kk < 4; kk++)
      a2[tile][kk] = *(const s16x8*)&CNN2[(size_t)(b * 784 + l0 + tile * 16 + (l & 15)) * 512
                                          + w * 128 + kk * 32 + (l >> 4) * 8];
#pragma unroll
  for (int nt = 0; nt < 8; nt++)
#pragma unroll
    for (int kk = 0; kk < 4; kk++){
      int col = w * 128 + nt * 16 + (l & 15);
#pragma unroll
      for (int j = 0; j < 8; j++){
        int krow = kk * 32 + (l >> 4) * 8 + j;
        vb[nt][kk][j] = (krow < 112)
          ? (short)CNNB[(size_t)(b * 784 + l0 + krow) * 512 + col] : (short)0;
      }
    }

  for (int t = 0; t < 256; ++t){
    await_lines<1>(SYNC, HGL0, 32, (u32)(t + 1));     // h(t) complete
    u16* Zpar = Z + (t & 1) * 32768;
    {
      s16x8 hv = aload16(Zpar + b * 1024 + 512 + l * 8);
      if (w == 0) *(s16x8*)&hsh[l * 8] = hv;
    }
    __syncthreads();

    // ---- scores: 7 tiles x 4 kk MFMA (B = h broadcast) ----
    f32x4 sac[7];
#pragma unroll
    for (int tile = 0; tile < 7; tile++){ f32x4 z = {0.f,0.f,0.f,0.f}; sac[tile] = z; }
#pragma unroll
    for (int kk = 0; kk < 4; kk++){
      s16x8 bv = *(const s16x8*)&hsh[w * 128 + kk * 32 + (l >> 4) * 8];
#pragma unroll
      for (int tile = 0; tile < 7; tile++)
        sac[tile] = __builtin_amdgcn_mfma_f32_16x16x32_bf16(a2[tile][kk], bv, sac[tile], 0, 0, 0);
    }
    if ((l & 15) == 0){
#pragma unroll
      for (int tile = 0; tile < 7; tile++)
#pragma unroll
        for (int r = 0; r < 4; r++)
          scp[w * 112 + tile * 16 + (l >> 4) * 4 + r] = sac[tile][r];
    }
    __syncthreads();
    if (tid < 112) sc[tid] = scp[tid] + scp[112 + tid] + scp[224 + tid] + scp[336 + tid];
    else if (tid < 128) sc[tid] = -1e30f;
    __syncthreads();
    // per-wave redundant max over 128
    float m2 = fmaxf(sc[l], sc[l + 64]);
#pragma unroll
    for (int mk = 1; mk < 64; mk <<= 1) m2 = fmaxf(m2, __shfl_xor(m2, mk, 64));
    float M = m2;
    __syncthreads();
    if (tid < 112){ float p = __expf(sc[tid] - M); sc[tid] = p; pbf[tid] = f2bf(p); }
    else if (tid < 128){ sc[tid] = 0.f; pbf[tid] = 0; }
    __syncthreads();
    float s2 = sc[l] + sc[l + 64];
#pragma unroll
    for (int mk = 1; mk < 64; mk <<= 1) s2 += __shfl_xor(s2, mk, 64);
    float S = s2;

    // ---- PV: 8 n-tiles x 4 kk MFMA (A = p broadcast); waves own disjoint cols ----
    f32x4 uac[8];
#pragma unroll
    for (int nt = 0; nt < 8; nt++){ f32x4 z = {0.f,0.f,0.f,0.f}; uac[nt] = z; }
#pragma unroll
    for (int kk = 0; kk < 4; kk++){
      s16x8 av = *(const s16x8*)&pbf[kk * 32 + (l >> 4) * 8];
#pragma unroll
      for (int nt = 0; nt < 8; nt++)
        uac[nt] = __builtin_amdgcn_mfma_f32_16x16x32_bf16(av, vb[nt][kk], uac[nt], 0, 0, 0);
    }
    if (l < 16){
#pragma unroll
      for (int nt = 0; nt < 8; nt++){
        u32 uv = __builtin_bit_cast(u32, uac[nt][0]);
        __hip_atomic_store((u32*)(UPART + ((size_t)(b * 7 + ch) * 512 + w * 128 + nt * 16 + l)),
                           uv, __ATOMIC_RELAXED, AGT);
      }
    }
    if (tid == 0){
      union { u64 qv; float f[2]; } mm; mm.f[0] = M; mm.f[1] = S;
      __hip_atomic_store((u64*)(MS + (b * 7 + ch) * 2), mm.qv, __ATOMIC_RELAXED, AGT);
    }
    setflag(SYNC, RDYL0 + q * 32, (u32)(t + 1));
    await_lines<1>(SYNC, RDYL0 + b * 7 * 32, 7, (u32)(t + 1));

    // ---- combine: ctx -> zsh (bf16), h -> zsh ----
    if (tid < 7){
      union { u64 qv; float f[2]; } a;
      a.qv = __hip_atomic_load((const u64*)(MS + (b * 7 + tid) * 2), __ATOMIC_RELAXED, AGT);
      msh[2 * tid] = a.f[0]; msh[2 * tid + 1] = a.f[1];
    }
    __syncthreads();
    float Mg = -1e30f;
#pragma unroll
    for (int c = 0; c < 7; c++) Mg = fmaxf(Mg, msh[2 * c]);
    float bet[7]; float Sg = 0.f;
#pragma unroll
    for (int c = 0; c < 7; c++){
      float e = __expf(msh[2 * c] - Mg);
      bet[c] = e; Sg += e * msh[2 * c + 1];
    }
    float inv = 1.f / Sg;
    {
      int e0 = 2 * tid;
      float c0 = 0.f, c1 = 0.f;
#pragma unroll
      for (int c = 0; c < 7; c++){
        union { u64 qv; float f[2]; } a;
        a.qv = __hip_atomic_load((const u64*)(UPART + ((size_t)(b * 7 + c) * 512 + e0)),
                                 __ATOMIC_RELAXED, AGT);
        float bc = bet[c] * inv;
        c0 = fmaf(bc, a.f[0], c0); c1 = fmaf(bc, a.f[1], c1);
      }
      zsh[tid] = (u32)f2bf(c0) | ((u32)f2bf(c1) << 16);
      zsh[256 + tid] = ((u32*)hsh)[tid];
    }
    __syncthreads();

    // ---- out: 5 tiles x 8 kk MFMA (A = WOUT rows streamed, B = zsh broadcast) ----
    f32x4 oac[5];
#pragma unroll
    for (int tile = 0; tile < 5; tile++){ f32x4 z = {0.f,0.f,0.f,0.f}; oac[tile] = z; }
#pragma unroll
    for (int kk = 0; kk < 8; kk++){
      int ko = w * 256 + kk * 32 + (l >> 4) * 8;
      s16x8 bv = *(const s16x8*)((const u16*)zsh + ko);
#pragma unroll
      for (int tile = 0; tile < 5; tile++){
        int row = cs + tile * 16 + (l & 15);
        row = (row < 511) ? row : 511;
        s16x8 av = *(const s16x8*)&WOUT[(size_t)row * 1024 + ko];
        oac[tile] = __builtin_amdgcn_mfma_f32_16x16x32_bf16(av, bv, oac[tile], 0, 0, 0);
      }
    }
    if ((l & 15) == 0){
#pragma unroll
      for (int tile = 0; tile < 5; tile++)
#pragma unroll
        for (int r = 0; r < 4; r++)
          opart[w * 80 + tile * 16 + (l >> 4) * 4 + r] = oac[tile][r];
    }
    __syncthreads();
    if (tid < (nc >> 1)){
      int j0 = 2 * tid;
      float v0 = opart[j0]   + opart[80 + j0]   + opart[160 + j0]   + opart[240 + j0];
      float v1 = opart[j0+1] + opart[80 + j0+1] + opart[160 + j0+1] + opart[240 + j0+1];
      u32 pk = (u32)f2bf(tanhf(v0)) | ((u32)f2bf(tanhf(v1)) << 16);
      __hip_atomic_store((u32*)(Zpar + b * 1024 + cs + j0), pk, __ATOMIC_RELAXED, AGT);
      *(u32*)&OALL[((size_t)(b * 256 + t)) * 512 + cs + j0] = pk;
    }
    setflag(SYNC, ODL0 + q * 32, (u32)(t + 1));
  }
}

// ---------------- persistent decoder ----------------

__global__ __launch_bounds__(256, 1) void k_persist(const u16* __restrict__ WF,
                                                    const u16* __restrict__ XS,
                                                    const u16* __restrict__ CNN2,
                                                    const u16* __restrict__ CNNB,
                                                    const u16* __restrict__ WOUT,
                                                    u16* __restrict__ Z,
                                                    float* __restrict__ CST,
                                                    float* __restrict__ UPART,
                                                    float* __restrict__ MS,
                                                    u16* __restrict__ OALL,
                                                    u32* __restrict__ SYNC){
  __shared__ __align__(16) float SM[8192];
  int gid = blockIdx.x;
  if (gid < 32)
    gates_role(WF, XS, Z, CST, SYNC, SM, gid);
  else
    attn_role(CNN2, CNNB, WOUT, Z, UPART, MS, OALL, SYNC, SM, gid - 32);
}

// ---------------- log_softmax ----------------

__global__ __launch_bounds__(256) void k_lsm(float* __restrict__ x){
  size_t base = (size_t)blockIdx.x * 8000;
  int tid = threadIdx.x, w = tid >> 6, ln = tid & 63;
  __shared__ float sred[4];
  float m = -1e30f;
  for (int v = tid; v < 8000; v += 256) m = fmaxf(m, x[base + v]);
#pragma unroll
  for (int mk = 1; mk < 64; mk <<= 1) m = fmaxf(m, __shfl_xor(m, mk, 64));
  if (ln == 0) sred[w] = m;
  __syncthreads();
  float M = fmaxf(fmaxf(sred[0], sred[1]), fmaxf(sred[2], sred[3]));
  __syncthreads();
  float s = 0.f;
  for (int v = tid; v < 8000; v += 256) s += __expf(x[base + v] - M);
#pragma unroll
  for (int mk = 1; mk < 64; mk <<= 1) s += __shfl_xor(s, mk, 64);
  if (ln == 0) sred[w] = s;
  __syncthreads();
  float S = sred[0] + sred[1] + sred[2] + sred[3];
  float lz = M + logf(S);
  for (int v = tid; v < 8000; v += 256) x[base + v] -= lz;
}

// ---------------- launcher ----------------

extern "C" void kernel_launch(void* const* d_in, const int* in_sizes, int n_in,
                              void* d_out, int out_size, void* d_ws, size_t ws_size,
                              hipStream_t stream){
  const float* cnn  = (const float*)d_in[0];
  const int*   seq  = (const int*)d_in[1];
  const float* emb  = (const float*)d_in[2];
  const float* wih  = (const float*)d_in[3];
  const float* whh  = (const float*)d_in[4];
  const float* whm  = (const float*)d_in[5];
  const float* wo   = (const float*)d_in[6];
  const float* wlg  = (const float*)d_in[7];
  const float* blg  = (const float*)d_in[8];

  char* ws = (char*)d_ws;
  u16*   WF     = (u16*)(ws + 0);          // 2048x1280 bf16 = 5,242,880
  u16*   WHMT   = (u16*)(ws + 5242880);    // 512x512 bf16   =   524,288
  u16*   WOUT   = (u16*)(ws + 5767168);    // 512x1024 bf16  = 1,048,576
  u16*   WLOGIT = (u16*)(ws + 6815744);    // 8000x512 bf16  = 8,192,000
  u16*   CNNBF  = (u16*)(ws + 15007744);   // 25088x512 bf16 = 25,690,112
  u16*   CNN2   = (u16*)(ws + 40697856);   // 25088x512 bf16 = 25,690,112
  u16*   XS     = (u16*)(ws + 66387968);   // [256][32][256] bf16 = 4,194,304
  u16*   OALL   = (u16*)(ws + 70582272);   // 8192x512 bf16  = 8,388,608
  u16*   Z      = (u16*)(ws + 78970880);   // [2][32][1024] bf16 = 131,072
  float* CST    = (float*)(ws + 79101952); // 32x512 f32     = 65,536
  float* UPART  = (float*)(ws + 79167488); // [32][7][512] f32 = 458,752
  float* MS     = (float*)(ws + 79626240); // [32][7][2] f32 (pad 2048)
  u32*   SYNC   = (u32*)(ws + 79628288);   // 61,440 B

  float* OUT = (float*)d_out;

  (void)hipMemsetAsync(SYNC, 0, SY_BYTES, stream);
  k_wfull<<<512, 256, 0, stream>>>(wih, whh, WF);
  k_whmt<<<128, 256, 0, stream>>>(whm, WHMT);
  k_cvt<<<512, 256, 0, stream>>>(wo, WOUT, 512 * 1024);
  k_cvt<<<2048, 256, 0, stream>>>(wlg, WLOGIT, 8000 * 512);
  k_cvt<<<2048, 256, 0, stream>>>(cnn, CNNBF, 25088 * 512);
  k_xs<<<2048, 256, 0, stream>>>(seq, emb, XS);

  {
    dim3 g(196, 4);   // CNN2 = CNNB @ WHMT^T : scores key matrix
    k_gemm<1, 0, 0><<<g, 256, 0, stream>>>(CNNBF, WHMT, CNN2, nullptr, 25088, 512, 512);
  }

  k_persist<<<256, 256, 0, stream>>>(WF, XS, CNN2, CNNBF, WOUT, Z, CST, UPART, MS, OALL, SYNC);

  {
    dim3 g(64, 63);
    k_gemm<0, 1, 1><<<g, 256, 0, stream>>>(OALL, WLOGIT, OUT, blg, 8192, 8000, 512);
  }
  k_lsm<<<8192, 256, 0, stream>>>(OUT);
}

// Round 11
// 3497.379 us; speedup vs baseline: 2.4914x; 1.3313x over previous
//
#include <hip/hip_runtime.h>
#include <hip/hip_bf16.h>
#include <stdint.h>

typedef unsigned short u16;
typedef unsigned int u32;
typedef unsigned long long u64;
typedef __attribute__((ext_vector_type(8))) short s16x8;
typedef __attribute__((ext_vector_type(4))) float f32x4;

#define AGT __HIP_MEMORY_SCOPE_AGENT

static __device__ __forceinline__ float bf2f(u16 u){
  unsigned v = ((unsigned)u) << 16; return __builtin_bit_cast(float, v);
}
static __device__ __forceinline__ u16 f2bf(float f){
  unsigned u = __builtin_bit_cast(unsigned, f);
  u += 0x7FFFu + ((u >> 16) & 1u);
  return (u16)(u >> 16);
}
static __device__ __forceinline__ float sigm(float x){ return 1.f / (1.f + __expf(-x)); }

typedef __attribute__((address_space(1))) const u32 gu32;
typedef __attribute__((address_space(3))) u32 lu32;
static __device__ __forceinline__ void gload_lds16(const void* g, void* l){
  __builtin_amdgcn_global_load_lds((gu32*)g, (lu32*)l, 16, 0, 0);
}

// ---- tagged-word sync: u64 = (step_tag << 32) | payload32 ----
static __device__ __forceinline__ u64 tload(const u64* p){
  return __hip_atomic_load(p, __ATOMIC_RELAXED, AGT);
}
static __device__ __forceinline__ void tstore(u64* p, u64 v){
  __hip_atomic_store(p, v, __ATOMIC_RELAXED, AGT);
}
static __device__ __forceinline__ u32 wtag(u64 v){ return (u32)(v >> 32); }
static __device__ __forceinline__ s16x8 pack4(u64 q0, u64 q1, u64 q2, u64 q3){
  u32 a0=(u32)q0, a1=(u32)q1, a2=(u32)q2, a3=(u32)q3;
  s16x8 r = {(short)a0,(short)(a0>>16),(short)a1,(short)(a1>>16),
             (short)a2,(short)(a2>>16),(short)a3,(short)(a3>>16)};
  return r;
}

// ---------------- prep kernels ----------------

__global__ __launch_bounds__(256) void k_wfull(const float* __restrict__ wih,
                                               const float* __restrict__ whh,
                                               u16* __restrict__ wf){
  int stride = gridDim.x * blockDim.x;
  for (int i = blockIdx.x * blockDim.x + threadIdx.x; i < 2048 * 1280; i += stride){
    int j = i / 1280, k = i - j * 1280;
    float v = (k < 768) ? wih[j * 768 + k] : whh[j * 512 + (k - 768)];
    wf[i] = f2bf(v);
  }
}

__global__ __launch_bounds__(256) void k_whmt(const float* __restrict__ whm,
                                              u16* __restrict__ wt){
  int stride = gridDim.x * blockDim.x;
  for (int i = blockIdx.x * blockDim.x + threadIdx.x; i < 512 * 512; i += stride){
    int n = i >> 9, k = i & 511;
    wt[i] = f2bf(whm[k * 512 + n]);
  }
}

__global__ __launch_bounds__(256) void k_cvt(const float* __restrict__ s,
                                             u16* __restrict__ d, int n){
  int stride = gridDim.x * blockDim.x * 4;
  for (int i = (blockIdx.x * blockDim.x + threadIdx.x) * 4; i < n; i += stride){
    float4 v = *(const float4*)&s[i];
    d[i + 0] = f2bf(v.x); d[i + 1] = f2bf(v.y);
    d[i + 2] = f2bf(v.z); d[i + 3] = f2bf(v.w);
  }
}

__global__ __launch_bounds__(256) void k_xs(const int* __restrict__ seq,
                                            const float* __restrict__ emb,
                                            u16* __restrict__ xs){
  int stride = gridDim.x * blockDim.x;
  for (int i = blockIdx.x * blockDim.x + threadIdx.x; i < 8192 * 256; i += stride){
    int m = i >> 8, e = i & 255;
    int b = m >> 8, t = m & 255;
    float v = emb[(size_t)seq[m] * 256 + e];
    xs[(size_t)(t * 32 + b) * 256 + e] = f2bf(v > 0.f ? v : 0.f);
  }
}

// ---------------- 128x128 bf16 MFMA GEMM: C = A[M,K] @ B[N,K]^T ----------------

template<int OUTBF, int HASBIAS, int NG>
__global__ __launch_bounds__(256) void k_gemm(const u16* __restrict__ A,
                                              const u16* __restrict__ Bm,
                                              void* __restrict__ Cout,
                                              const float* __restrict__ bias,
                                              int M, int N, int K){
  __shared__ __align__(16) u16 As[128 * 64];
  __shared__ __align__(16) u16 Bs[128 * 64];
  int tid = threadIdx.x; int w = tid >> 6; int l = tid & 63;
  int m0 = blockIdx.x * 128, n0 = blockIdx.y * 128;
  int wr = w >> 1, wc = w & 1;
  f32x4 acc[4][4];
#pragma unroll
  for (int a = 0; a < 4; a++)
#pragma unroll
    for (int b = 0; b < 4; b++){ f32x4 z = {0.f,0.f,0.f,0.f}; acc[a][b] = z; }
  int rA = m0 + (tid >> 3);
  int rB = n0 + (tid >> 3);
  for (int k0 = 0; k0 < K; k0 += 64){
    __syncthreads();
    int ca = k0 + (tid & 7) * 8;
#pragma unroll
    for (int i = 0; i < 4; i++){
      gload_lds16(&A[(size_t)(rA + i * 32) * K + ca], &As[i * 2048 + w * 512]);
      int rb = rB + i * 32;
      if (NG) rb = (rb < N - 1) ? rb : (N - 1);
      gload_lds16(&Bm[(size_t)rb * K + ca], &Bs[i * 2048 + w * 512]);
    }
    asm volatile("s_waitcnt vmcnt(0)" ::: "memory");
    __syncthreads();
#pragma unroll
    for (int ks = 0; ks < 2; ks++){
      s16x8 av[4], bv[4];
      int ko = ks * 32 + (l >> 4) * 8;
#pragma unroll
      for (int i = 0; i < 4; i++) av[i] = *(const s16x8*)&As[(wr * 64 + i * 16 + (l & 15)) * 64 + ko];
#pragma unroll
      for (int i = 0; i < 4; i++) bv[i] = *(const s16x8*)&Bs[(wc * 64 + i * 16 + (l & 15)) * 64 + ko];
#pragma unroll
      for (int mi = 0; mi < 4; mi++)
#pragma unroll
        for (int ni = 0; ni < 4; ni++)
          acc[mi][ni] = __builtin_amdgcn_mfma_f32_16x16x32_bf16(av[mi], bv[ni], acc[mi][ni], 0, 0, 0);
    }
  }
#pragma unroll
  for (int mi = 0; mi < 4; mi++)
#pragma unroll
    for (int ni = 0; ni < 4; ni++){
      int row = m0 + wr * 64 + mi * 16 + (l >> 4) * 4;
      int col = n0 + wc * 64 + ni * 16 + (l & 15);
      if (NG && col >= N) continue;
#pragma unroll
      for (int r = 0; r < 4; r++){
        float v = acc[mi][ni][r];
        if (HASBIAS) v += bias[col];
        if (OUTBF) ((u16*)Cout)[(size_t)(row + r) * N + col] = f2bf(v);
        else       ((float*)Cout)[(size_t)(row + r) * N + col] = v;
      }
    }
}

// ---------------- gates role (gid<32): W pinned; tagged h/out polls ----------------
// ZH/ZO: [2][32][256] u64, word i of batch b = (tag<<32)|(bf16 pair for elems 2i,2i+1)

static __device__ void gates_role(const u16* __restrict__ WF, const u16* __restrict__ XS,
                                  u64* __restrict__ ZH, u64* __restrict__ ZO,
                                  float* __restrict__ CST, float* __restrict__ SM, int g){
  const int tid = threadIdx.x, w = tid >> 6, l = tid & 63;
  const int ns = g << 4;
  float (*red)[32][64] = (float(*)[32][64])SM;

  s16x8 bx[2][4], bh[4][4], bo[4][4];
#pragma unroll
  for (int ki = 0; ki < 2; ki++){
    int ko = w * 64 + ki * 32 + (l >> 4) * 8;
#pragma unroll
    for (int gi = 0; gi < 4; gi++)
      bx[ki][gi] = *(const s16x8*)&WF[(size_t)(gi * 512 + ns + (l & 15)) * 1280 + ko];
  }
#pragma unroll
  for (int ki = 0; ki < 4; ki++){
    int koh = 768 + w * 128 + ki * 32 + (l >> 4) * 8;
    int koo = 256 + w * 128 + ki * 32 + (l >> 4) * 8;
#pragma unroll
    for (int gi = 0; gi < 4; gi++){
      bh[ki][gi] = *(const s16x8*)&WF[(size_t)(gi * 512 + ns + (l & 15)) * 1280 + koh];
      bo[ki][gi] = *(const s16x8*)&WF[(size_t)(gi * 512 + ns + (l & 15)) * 1280 + koo];
    }
  }

  for (int t = 0; t < 256; ++t){
    const u32 tg = (u32)t;                    // tag of h(t-1)/out(t-1)
    const int rp = (t + 1) & 1;               // read parity: (t-1)&1
    f32x4 acc[2][4];
#pragma unroll
    for (int a = 0; a < 2; a++)
#pragma unroll
      for (int b = 0; b < 4; b++){ f32x4 z = {0.f,0.f,0.f,0.f}; acc[a][b] = z; }

    // x segment (no dependency)
#pragma unroll
    for (int ki = 0; ki < 2; ki++){
      int ko = w * 64 + ki * 32 + (l >> 4) * 8;
      s16x8 av[2];
#pragma unroll
      for (int mi = 0; mi < 2; mi++)
        av[mi] = *(const s16x8*)&XS[(size_t)(t * 32 + mi * 16 + (l & 15)) * 256 + ko];
#pragma unroll
      for (int mi = 0; mi < 2; mi++)
#pragma unroll
        for (int gi = 0; gi < 4; gi++)
          acc[mi][gi] = __builtin_amdgcn_mfma_f32_16x16x32_bf16(av[mi], bx[ki][gi], acc[mi][gi], 0, 0, 0);
    }
    if (t > 0){
      // h segment: poll tagged ZH words directly
#pragma unroll
      for (int kk = 0; kk < 4; kk++){
        int wb = w * 64 + kk * 16 + ((l >> 4) << 2);
        const u64* p0 = &ZH[(size_t)rp * 8192 + (size_t)(l & 15) * 256 + wb];
        const u64* p1 = &ZH[(size_t)rp * 8192 + (size_t)(16 + (l & 15)) * 256 + wb];
        u64 qa0,qa1,qa2,qa3,qb0,qb1,qb2,qb3; bool ok;
        do {
          qa0=tload(p0); qa1=tload(p0+1); qa2=tload(p0+2); qa3=tload(p0+3);
          qb0=tload(p1); qb1=tload(p1+1); qb2=tload(p1+2); qb3=tload(p1+3);
          ok = (wtag(qa0)==tg)&(wtag(qa1)==tg)&(wtag(qa2)==tg)&(wtag(qa3)==tg)
             & (wtag(qb0)==tg)&(wtag(qb1)==tg)&(wtag(qb2)==tg)&(wtag(qb3)==tg);
          if (!ok) __builtin_amdgcn_s_sleep(1);
        } while (!__all(ok));
        s16x8 av0 = pack4(qa0,qa1,qa2,qa3), av1 = pack4(qb0,qb1,qb2,qb3);
#pragma unroll
        for (int gi = 0; gi < 4; gi++){
          acc[0][gi] = __builtin_amdgcn_mfma_f32_16x16x32_bf16(av0, bh[kk][gi], acc[0][gi], 0, 0, 0);
          acc[1][gi] = __builtin_amdgcn_mfma_f32_16x16x32_bf16(av1, bh[kk][gi], acc[1][gi], 0, 0, 0);
        }
      }
      // out segment: poll tagged ZO words directly
#pragma unroll
      for (int kk = 0; kk < 4; kk++){
        int wb = w * 64 + kk * 16 + ((l >> 4) << 2);
        const u64* p0 = &ZO[(size_t)rp * 8192 + (size_t)(l & 15) * 256 + wb];
        const u64* p1 = &ZO[(size_t)rp * 8192 + (size_t)(16 + (l & 15)) * 256 + wb];
        u64 qa0,qa1,qa2,qa3,qb0,qb1,qb2,qb3; bool ok;
        do {
          qa0=tload(p0); qa1=tload(p0+1); qa2=tload(p0+2); qa3=tload(p0+3);
          qb0=tload(p1); qb1=tload(p1+1); qb2=tload(p1+2); qb3=tload(p1+3);
          ok = (wtag(qa0)==tg)&(wtag(qa1)==tg)&(wtag(qa2)==tg)&(wtag(qa3)==tg)
             & (wtag(qb0)==tg)&(wtag(qb1)==tg)&(wtag(qb2)==tg)&(wtag(qb3)==tg);
          if (!ok) __builtin_amdgcn_s_sleep(1);
        } while (!__all(ok));
        s16x8 av0 = pack4(qa0,qa1,qa2,qa3), av1 = pack4(qb0,qb1,qb2,qb3);
#pragma unroll
        for (int gi = 0; gi < 4; gi++){
          acc[0][gi] = __builtin_amdgcn_mfma_f32_16x16x32_bf16(av0, bo[kk][gi], acc[0][gi], 0, 0, 0);
          acc[1][gi] = __builtin_amdgcn_mfma_f32_16x16x32_bf16(av1, bo[kk][gi], acc[1][gi], 0, 0, 0);
        }
      }
    }
    // cross-wave reduce + LSTM
#pragma unroll
    for (int mi = 0; mi < 2; mi++)
#pragma unroll
      for (int gi = 0; gi < 4; gi++)
#pragma unroll
        for (int r = 0; r < 4; r++)
          red[w][mi * 16 + (l >> 4) * 4 + r][gi * 16 + (l & 15)] = acc[mi][gi][r];
    __syncthreads();
    {
      int bi = tid >> 3, j = (tid & 7) * 2;
      float iv0=0,fv0=0,gv0=0,ov0=0, iv1=0,fv1=0,gv1=0,ov1=0;
#pragma unroll
      for (int qq = 0; qq < 4; qq++){
        iv0 += red[qq][bi][j];      fv0 += red[qq][bi][16 + j];
        gv0 += red[qq][bi][32 + j]; ov0 += red[qq][bi][48 + j];
        iv1 += red[qq][bi][j + 1];      fv1 += red[qq][bi][16 + j + 1];
        gv1 += red[qq][bi][32 + j + 1]; ov1 += red[qq][bi][48 + j + 1];
      }
      int n0 = ns + j;
      float c0 = (t > 0) ? CST[bi * 512 + n0]     : 0.f;
      float c1 = (t > 0) ? CST[bi * 512 + n0 + 1] : 0.f;
      float cn0 = sigm(fv0) * c0 + sigm(iv0) * tanhf(gv0);
      float cn1 = sigm(fv1) * c1 + sigm(iv1) * tanhf(gv1);
      float h0 = sigm(ov0) * tanhf(cn0);
      float h1 = sigm(ov1) * tanhf(cn1);
      CST[bi * 512 + n0] = cn0; CST[bi * 512 + n0 + 1] = cn1;
      u32 pk = (u32)f2bf(h0) | ((u32)f2bf(h1) << 16);
      tstore(&ZH[(size_t)(t & 1) * 8192 + (size_t)bi * 256 + g * 8 + (tid & 7)],
             ((u64)(u32)(t + 1) << 32) | pk);
    }
    __syncthreads();
  }
}

// ---------------- attn+out role (gid>=32): MFMA everywhere; tagged polls ----------------

static __device__ void attn_role(const u16* __restrict__ CNN2, const u16* __restrict__ CNNB,
                                 const u16* __restrict__ WOUT,
                                 u64* __restrict__ ZH, u64* __restrict__ ZO,
                                 u64* __restrict__ UT, u64* __restrict__ MST,
                                 u16* __restrict__ OALL, float* __restrict__ SM, int q){
  const int tid = threadIdx.x, w = tid >> 6, l = tid & 63;
  const int b = q / 7, ch = q - b * 7;
  const int l0 = ch * 112;
  const int nc = (ch == 6) ? 68 : 74, cs = ch * 74;
  u16*   hsh  = (u16*)SM;
  u16*   pbf  = (u16*)(SM + 256);
  float* sc   = SM + 320;
  float* scp  = SM + 448;
  float* msh  = SM + 896;
  u32*   zsh  = (u32*)(SM + 912);
  float* opart= SM + 1424;

  s16x8 a2[7][4];
  s16x8 vb[8][4];
#pragma unroll
  for (int tile = 0; tile < 7; tile++)
#pragma unroll
    for (int kk = 0; kk < 4; kk++)
      a2[tile][kk] = *(const s16x8*)&CNN2[(size_t)(b * 784 + l0 + tile * 16 + (l & 15)) * 512
                                          + w * 128 + kk * 32 + (l >> 4) * 8];
#pragma unroll
  for (int nt = 0; nt < 8; nt++)
#pragma unroll
    for (int kk = 0; kk < 4; kk++){
      int col = w * 128 + nt * 16 + (l & 15);
#pragma unroll
      for (int j = 0; j < 8; j++){
        int krow = kk * 32 + (l >> 4) * 8 + j;
        vb[nt][kk][j] = (krow < 112)
          ? (short)CNNB[(size_t)(b * 784 + l0 + krow) * 512 + col] : (short)0;
      }
    }

  for (int t = 0; t < 256; ++t){
    const u32 tagp = (u32)(t + 1);
    // ---- h(t) poll (wave 0 only) ----
    if (w == 0){
      const u64* hp = &ZH[(size_t)(t & 1) * 8192 + (size_t)b * 256 + l * 4];
      u64 h0,h1,h2,h3; bool ok;
      do {
        h0=tload(hp); h1=tload(hp+1); h2=tload(hp+2); h3=tload(hp+3);
        ok = (wtag(h0)==tagp)&(wtag(h1)==tagp)&(wtag(h2)==tagp)&(wtag(h3)==tagp);
        if (!ok) __builtin_amdgcn_s_sleep(1);
      } while (!__all(ok));
      *(s16x8*)&hsh[l * 8] = pack4(h0,h1,h2,h3);
    }
    __syncthreads();

    // ---- scores: 7 tiles x 4 kk MFMA (B = h broadcast) ----
    f32x4 sac[7];
#pragma unroll
    for (int tile = 0; tile < 7; tile++){ f32x4 z = {0.f,0.f,0.f,0.f}; sac[tile] = z; }
#pragma unroll
    for (int kk = 0; kk < 4; kk++){
      s16x8 bv = *(const s16x8*)&hsh[w * 128 + kk * 32 + (l >> 4) * 8];
#pragma unroll
      for (int tile = 0; tile < 7; tile++)
        sac[tile] = __builtin_amdgcn_mfma_f32_16x16x32_bf16(a2[tile][kk], bv, sac[tile], 0, 0, 0);
    }
    if ((l & 15) == 0){
#pragma unroll
      for (int tile = 0; tile < 7; tile++)
#pragma unroll
        for (int r = 0; r < 4; r++)
          scp[w * 112 + tile * 16 + (l >> 4) * 4 + r] = sac[tile][r];
    }
    __syncthreads();
    if (tid < 112) sc[tid] = scp[tid] + scp[112 + tid] + scp[224 + tid] + scp[336 + tid];
    else if (tid < 128) sc[tid] = -1e30f;
    __syncthreads();
    float m2 = fmaxf(sc[l], sc[l + 64]);
#pragma unroll
    for (int mk = 1; mk < 64; mk <<= 1) m2 = fmaxf(m2, __shfl_xor(m2, mk, 64));
    float M = m2;
    __syncthreads();
    if (tid < 112){ float p = __expf(sc[tid] - M); sc[tid] = p; pbf[tid] = f2bf(p); }
    else if (tid < 128){ sc[tid] = 0.f; pbf[tid] = 0; }
    __syncthreads();
    float s2 = sc[l] + sc[l + 64];
#pragma unroll
    for (int mk = 1; mk < 64; mk <<= 1) s2 += __shfl_xor(s2, mk, 64);
    float S = s2;

    // ---- PV: 8 n-tiles x 4 kk MFMA (A = p broadcast) ----
    f32x4 uac[8];
#pragma unroll
    for (int nt = 0; nt < 8; nt++){ f32x4 z = {0.f,0.f,0.f,0.f}; uac[nt] = z; }
#pragma unroll
    for (int kk = 0; kk < 4; kk++){
      s16x8 av = *(const s16x8*)&pbf[kk * 32 + (l >> 4) * 8];
#pragma unroll
      for (int nt = 0; nt < 8; nt++)
        uac[nt] = __builtin_amdgcn_mfma_f32_16x16x32_bf16(av, vb[nt][kk], uac[nt], 0, 0, 0);
    }
    // tagged u-partial write (bf16 pairs)
#pragma unroll
    for (int nt = 0; nt < 8; nt++){
      float o0 = uac[nt][0];
      float o1 = __shfl_xor(o0, 1, 64);
      if (l < 16 && (l & 1) == 0){
        u64 wv = ((u64)tagp << 32) | (u32)f2bf(o0) | ((u32)f2bf(o1) << 16);
        tstore(&UT[((size_t)(b * 7 + ch)) * 256 + w * 64 + nt * 8 + (l >> 1)], wv);
      }
    }
    if (tid == 0){
      tstore(&MST[(b * 7 + ch) * 2 + 0], ((u64)tagp << 32) | __builtin_bit_cast(u32, M));
      tstore(&MST[(b * 7 + ch) * 2 + 1], ((u64)tagp << 32) | __builtin_bit_cast(u32, S));
    }

    // ---- sibling stats poll (wave 0, 14 words) ----
    if (w == 0){
      const u64* mp_ = &MST[(b * 7) * 2 + ((l < 14) ? l : 0)];
      u64 v; bool ok;
      do {
        v = tload(mp_);
        ok = (wtag(v) == tagp);
        if (!ok) __builtin_amdgcn_s_sleep(1);
      } while (!__all(ok));
      if (l < 14) msh[l] = __builtin_bit_cast(float, (u32)v);
    }
    __syncthreads();
    float Mg = -1e30f;
#pragma unroll
    for (int c = 0; c < 7; c++) Mg = fmaxf(Mg, msh[2 * c]);
    float bet[7]; float Sg = 0.f;
#pragma unroll
    for (int c = 0; c < 7; c++){
      float e = __expf(msh[2 * c] - Mg);
      bet[c] = e; Sg += e * msh[2 * c + 1];
    }
    float inv = 1.f / Sg;
    // ---- u-partial gather (tagged, 7 words per thread) + combine ----
    {
      u64 uw[7]; bool ok;
      do {
#pragma unroll
        for (int c = 0; c < 7; c++) uw[c] = tload(&UT[((size_t)(b * 7 + c)) * 256 + tid]);
        ok = true;
#pragma unroll
        for (int c = 0; c < 7; c++) ok &= (wtag(uw[c]) == tagp);
        if (!ok) __builtin_amdgcn_s_sleep(1);
      } while (!__all(ok));
      float c0 = 0.f, c1 = 0.f;
#pragma unroll
      for (int c = 0; c < 7; c++){
        float bc = bet[c] * inv;
        c0 = fmaf(bc, bf2f((u16)uw[c]), c0);
        c1 = fmaf(bc, bf2f((u16)(uw[c] >> 16)), c1);
      }
      zsh[tid] = (u32)f2bf(c0) | ((u32)f2bf(c1) << 16);
      zsh[256 + tid] = ((u32*)hsh)[tid];
    }
    __syncthreads();

    // ---- out: 5 tiles x 8 kk MFMA (A = WOUT streamed, B = zsh broadcast) ----
    f32x4 oac[5];
#pragma unroll
    for (int tile = 0; tile < 5; tile++){ f32x4 z = {0.f,0.f,0.f,0.f}; oac[tile] = z; }
#pragma unroll
    for (int kk = 0; kk < 8; kk++){
      int ko = w * 256 + kk * 32 + (l >> 4) * 8;
      s16x8 bv = *(const s16x8*)((const u16*)zsh + ko);
#pragma unroll
      for (int tile = 0; tile < 5; tile++){
        int row = cs + tile * 16 + (l & 15);
        row = (row < 511) ? row : 511;
        s16x8 av = *(const s16x8*)&WOUT[(size_t)row * 1024 + ko];
        oac[tile] = __builtin_amdgcn_mfma_f32_16x16x32_bf16(av, bv, oac[tile], 0, 0, 0);
      }
    }
    if ((l & 15) == 0){
#pragma unroll
      for (int tile = 0; tile < 5; tile++)
#pragma unroll
        for (int r = 0; r < 4; r++)
          opart[w * 80 + tile * 16 + (l >> 4) * 4 + r] = oac[tile][r];
    }
    __syncthreads();
    if (tid < (nc >> 1)){
      int j0 = 2 * tid;
      float v0 = opart[j0]   + opart[80 + j0]   + opart[160 + j0]   + opart[240 + j0];
      float v1 = opart[j0+1] + opart[80 + j0+1] + opart[160 + j0+1] + opart[240 + j0+1];
      u32 pk = (u32)f2bf(tanhf(v0)) | ((u32)f2bf(tanhf(v1)) << 16);
      tstore(&ZO[(size_t)(t & 1) * 8192 + (size_t)b * 256 + (cs >> 1) + tid],
             ((u64)tagp << 32) | pk);
      *(u32*)&OALL[((size_t)(b * 256 + t)) * 512 + cs + j0] = pk;
    }
    __syncthreads();
  }
}

// ---------------- persistent decoder ----------------

__global__ __launch_bounds__(256, 1) void k_persist(const u16* __restrict__ WF,
                                                    const u16* __restrict__ XS,
                                                    const u16* __restrict__ CNN2,
                                                    const u16* __restrict__ CNNB,
                                                    const u16* __restrict__ WOUT,
                                                    u64* __restrict__ ZH,
                                                    u64* __restrict__ ZO,
                                                    u64* __restrict__ UT,
                                                    u64* __restrict__ MST,
                                                    float* __restrict__ CST,
                                                    u16* __restrict__ OALL){
  __shared__ __align__(16) float SM[8192];
  int gid = blockIdx.x;
  if (gid < 32)
    gates_role(WF, XS, ZH, ZO, CST, SM, gid);
  else
    attn_role(CNN2, CNNB, WOUT, ZH, ZO, UT, MST, OALL, SM, gid - 32);
}

// ---------------- log_softmax ----------------

__global__ __launch_bounds__(256) void k_lsm(float* __restrict__ x){
  size_t base = (size_t)blockIdx.x * 8000;
  int tid = threadIdx.x, w = tid >> 6, ln = tid & 63;
  __shared__ float sred[4];
  float m = -1e30f;
  for (int v = tid; v < 8000; v += 256) m = fmaxf(m, x[base + v]);
#pragma unroll
  for (int mk = 1; mk < 64; mk <<= 1) m = fmaxf(m, __shfl_xor(m, mk, 64));
  if (ln == 0) sred[w] = m;
  __syncthreads();
  float M = fmaxf(fmaxf(sred[0], sred[1]), fmaxf(sred[2], sred[3]));
  __syncthreads();
  float s = 0.f;
  for (int v = tid; v < 8000; v += 256) s += __expf(x[base + v] - M);
#pragma unroll
  for (int mk = 1; mk < 64; mk <<= 1) s += __shfl_xor(s, mk, 64);
  if (ln == 0) sred[w] = s;
  __syncthreads();
  float S = sred[0] + sred[1] + sred[2] + sred[3];
  float lz = M + logf(S);
  for (int v = tid; v < 8000; v += 256) x[base + v] -= lz;
}

// ---------------- launcher ----------------

extern "C" void kernel_launch(void* const* d_in, const int* in_sizes, int n_in,
                              void* d_out, int out_size, void* d_ws, size_t ws_size,
                              hipStream_t stream){
  const float* cnn  = (const float*)d_in[0];
  const int*   seq  = (const int*)d_in[1];
  const float* emb  = (const float*)d_in[2];
  const float* wih  = (const float*)d_in[3];
  const float* whh  = (const float*)d_in[4];
  const float* whm  = (const float*)d_in[5];
  const float* wo   = (const float*)d_in[6];
  const float* wlg  = (const float*)d_in[7];
  const float* blg  = (const float*)d_in[8];

  char* ws = (char*)d_ws;
  u16*   WF     = (u16*)(ws + 0);          // 2048x1280 bf16 = 5,242,880
  u16*   WHMT   = (u16*)(ws + 5242880);    // 512x512 bf16   =   524,288
  u16*   WOUT   = (u16*)(ws + 5767168);    // 512x1024 bf16  = 1,048,576
  u16*   WLOGIT = (u16*)(ws + 6815744);    // 8000x512 bf16  = 8,192,000
  u16*   CNNBF  = (u16*)(ws + 15007744);   // 25088x512 bf16 = 25,690,112
  u16*   CNN2   = (u16*)(ws + 40697856);   // 25088x512 bf16 = 25,690,112
  u16*   XS     = (u16*)(ws + 66387968);   // [256][32][256] bf16 = 4,194,304
  u16*   OALL   = (u16*)(ws + 70582272);   // 8192x512 bf16  = 8,388,608
  u64*   ZH     = (u64*)(ws + 78970880);   // [2][32][256] u64 = 131,072
  u64*   ZO     = (u64*)(ws + 79101952);   // [2][32][256] u64 = 131,072
  u64*   UT     = (u64*)(ws + 79233024);   // [32][7][256] u64 = 458,752
  u64*   MST    = (u64*)(ws + 79691776);   // [32][7][2] u64 = 3,584
  float* CST    = (float*)(ws + 79695360); // 32x512 f32 = 65,536 -> ends 79,760,896

  float* OUT = (float*)d_out;

  (void)hipMemsetAsync(ws + 78970880, 0, 724480, stream);   // ZH..MST tags -> 0
  k_wfull<<<512, 256, 0, stream>>>(wih, whh, WF);
  k_whmt<<<128, 256, 0, stream>>>(whm, WHMT);
  k_cvt<<<512, 256, 0, stream>>>(wo, WOUT, 512 * 1024);
  k_cvt<<<2048, 256, 0, stream>>>(wlg, WLOGIT, 8000 * 512);
  k_cvt<<<2048, 256, 0, stream>>>(cnn, CNNBF, 25088 * 512);
  k_xs<<<2048, 256, 0, stream>>>(seq, emb, XS);

  {
    dim3 g(196, 4);   // CNN2 = CNNB @ WHMT^T
    k_gemm<1, 0, 0><<<g, 256, 0, stream>>>(CNNBF, WHMT, CNN2, nullptr, 25088, 512, 512);
  }

  k_persist<<<256, 256, 0, stream>>>(WF, XS, CNN2, CNNBF, WOUT, ZH, ZO, UT, MST, CST, OALL);

  {
    dim3 g(64, 63);
    k_gemm<0, 1, 1><<<g, 256, 0, stream>>>(OALL, WLOGIT, OUT, blg, 8192, 8000, 512);
  }
  k_lsm<<<8192, 256, 0, stream>>>(OUT);
}

// Round 12
// 3346.325 us; speedup vs baseline: 2.6039x; 1.0451x over previous
//
#include <hip/hip_runtime.h>
#include <hip/hip_bf16.h>
#include <stdint.h>

typedef unsigned short u16;
typedef unsigned int u32;
typedef unsigned long long u64;
typedef __attribute__((ext_vector_type(8))) short s16x8;
typedef __attribute__((ext_vector_type(4))) float f32x4;

#define AGT __HIP_MEMORY_SCOPE_AGENT

static __device__ __forceinline__ float bf2f(u16 u){
  unsigned v = ((unsigned)u) << 16; return __builtin_bit_cast(float, v);
}
static __device__ __forceinline__ u16 f2bf(float f){
  unsigned u = __builtin_bit_cast(unsigned, f);
  u += 0x7FFFu + ((u >> 16) & 1u);
  return (u16)(u >> 16);
}
static __device__ __forceinline__ float sigm(float x){ return 1.f / (1.f + __expf(-x)); }

typedef __attribute__((address_space(1))) const u32 gu32;
typedef __attribute__((address_space(3))) u32 lu32;
static __device__ __forceinline__ void gload_lds16(const void* g, void* l){
  __builtin_amdgcn_global_load_lds((gu32*)g, (lu32*)l, 16, 0, 0);
}

// ---- tagged-word sync: u64 = (step_tag << 32) | payload32 ----
static __device__ __forceinline__ u64 tload(const u64* p){
  return __hip_atomic_load(p, __ATOMIC_RELAXED, AGT);
}
static __device__ __forceinline__ void tstore(u64* p, u64 v){
  __hip_atomic_store(p, v, __ATOMIC_RELAXED, AGT);
}
static __device__ __forceinline__ u32 wtag(u64 v){ return (u32)(v >> 32); }
static __device__ __forceinline__ s16x8 pack4(u64 q0, u64 q1, u64 q2, u64 q3){
  u32 a0=(u32)q0, a1=(u32)q1, a2=(u32)q2, a3=(u32)q3;
  s16x8 r = {(short)a0,(short)(a0>>16),(short)a1,(short)(a1>>16),
             (short)a2,(short)(a2>>16),(short)a3,(short)(a3>>16)};
  return r;
}

// ---------------- prep kernels ----------------

__global__ __launch_bounds__(256) void k_wfull(const float* __restrict__ wih,
                                               const float* __restrict__ whh,
                                               u16* __restrict__ wf){
  int stride = gridDim.x * blockDim.x;
  for (int i = blockIdx.x * blockDim.x + threadIdx.x; i < 2048 * 1280; i += stride){
    int j = i / 1280, k = i - j * 1280;
    float v = (k < 768) ? wih[j * 768 + k] : whh[j * 512 + (k - 768)];
    wf[i] = f2bf(v);
  }
}

__global__ __launch_bounds__(256) void k_whmt(const float* __restrict__ whm,
                                              u16* __restrict__ wt){
  int stride = gridDim.x * blockDim.x;
  for (int i = blockIdx.x * blockDim.x + threadIdx.x; i < 512 * 512; i += stride){
    int n = i >> 9, k = i & 511;
    wt[i] = f2bf(whm[k * 512 + n]);
  }
}

__global__ __launch_bounds__(256) void k_cvt(const float* __restrict__ s,
                                             u16* __restrict__ d, int n){
  int stride = gridDim.x * blockDim.x * 4;
  for (int i = (blockIdx.x * blockDim.x + threadIdx.x) * 4; i < n; i += stride){
    float4 v = *(const float4*)&s[i];
    d[i + 0] = f2bf(v.x); d[i + 1] = f2bf(v.y);
    d[i + 2] = f2bf(v.z); d[i + 3] = f2bf(v.w);
  }
}

__global__ __launch_bounds__(256) void k_xs(const int* __restrict__ seq,
                                            const float* __restrict__ emb,
                                            u16* __restrict__ xs){
  int stride = gridDim.x * blockDim.x;
  for (int i = blockIdx.x * blockDim.x + threadIdx.x; i < 8192 * 256; i += stride){
    int m = i >> 8, e = i & 255;
    int b = m >> 8, t = m & 255;
    float v = emb[(size_t)seq[m] * 256 + e];
    xs[(size_t)(t * 32 + b) * 256 + e] = f2bf(v > 0.f ? v : 0.f);
  }
}

// ---------------- 128x128 bf16 MFMA GEMM: C = A[M,K] @ B[N,K]^T ----------------

template<int OUTBF, int HASBIAS, int NG>
__global__ __launch_bounds__(256) void k_gemm(const u16* __restrict__ A,
                                              const u16* __restrict__ Bm,
                                              void* __restrict__ Cout,
                                              const float* __restrict__ bias,
                                              int M, int N, int K){
  __shared__ __align__(16) u16 As[128 * 64];
  __shared__ __align__(16) u16 Bs[128 * 64];
  int tid = threadIdx.x; int w = tid >> 6; int l = tid & 63;
  int m0 = blockIdx.x * 128, n0 = blockIdx.y * 128;
  int wr = w >> 1, wc = w & 1;
  f32x4 acc[4][4];
#pragma unroll
  for (int a = 0; a < 4; a++)
#pragma unroll
    for (int b = 0; b < 4; b++){ f32x4 z = {0.f,0.f,0.f,0.f}; acc[a][b] = z; }
  int rA = m0 + (tid >> 3);
  int rB = n0 + (tid >> 3);
  for (int k0 = 0; k0 < K; k0 += 64){
    __syncthreads();
    int ca = k0 + (tid & 7) * 8;
#pragma unroll
    for (int i = 0; i < 4; i++){
      gload_lds16(&A[(size_t)(rA + i * 32) * K + ca], &As[i * 2048 + w * 512]);
      int rb = rB + i * 32;
      if (NG) rb = (rb < N - 1) ? rb : (N - 1);
      gload_lds16(&Bm[(size_t)rb * K + ca], &Bs[i * 2048 + w * 512]);
    }
    asm volatile("s_waitcnt vmcnt(0)" ::: "memory");
    __syncthreads();
#pragma unroll
    for (int ks = 0; ks < 2; ks++){
      s16x8 av[4], bv[4];
      int ko = ks * 32 + (l >> 4) * 8;
#pragma unroll
      for (int i = 0; i < 4; i++) av[i] = *(const s16x8*)&As[(wr * 64 + i * 16 + (l & 15)) * 64 + ko];
#pragma unroll
      for (int i = 0; i < 4; i++) bv[i] = *(const s16x8*)&Bs[(wc * 64 + i * 16 + (l & 15)) * 64 + ko];
#pragma unroll
      for (int mi = 0; mi < 4; mi++)
#pragma unroll
        for (int ni = 0; ni < 4; ni++)
          acc[mi][ni] = __builtin_amdgcn_mfma_f32_16x16x32_bf16(av[mi], bv[ni], acc[mi][ni], 0, 0, 0);
    }
  }
#pragma unroll
  for (int mi = 0; mi < 4; mi++)
#pragma unroll
    for (int ni = 0; ni < 4; ni++){
      int row = m0 + wr * 64 + mi * 16 + (l >> 4) * 4;
      int col = n0 + wc * 64 + ni * 16 + (l & 15);
      if (NG && col >= N) continue;
#pragma unroll
      for (int r = 0; r < 4; r++){
        float v = acc[mi][ni][r];
        if (HASBIAS) v += bias[col];
        if (OUTBF) ((u16*)Cout)[(size_t)(row + r) * N + col] = f2bf(v);
        else       ((float*)Cout)[(size_t)(row + r) * N + col] = v;
      }
    }
}

// ---------------- gates role (gid<32): W pinned; tagged h/out polls ----------------

static __device__ void gates_role(const u16* __restrict__ WF, const u16* __restrict__ XS,
                                  u64* __restrict__ ZH, u64* __restrict__ ZO,
                                  float* __restrict__ CST, float* __restrict__ SM, int g){
  const int tid = threadIdx.x, w = tid >> 6, l = tid & 63;
  const int ns = g << 4;
  float (*red)[32][64] = (float(*)[32][64])SM;

  s16x8 bx[2][4], bh[4][4], bo[4][4];
#pragma unroll
  for (int ki = 0; ki < 2; ki++){
    int ko = w * 64 + ki * 32 + (l >> 4) * 8;
#pragma unroll
    for (int gi = 0; gi < 4; gi++)
      bx[ki][gi] = *(const s16x8*)&WF[(size_t)(gi * 512 + ns + (l & 15)) * 1280 + ko];
  }
#pragma unroll
  for (int ki = 0; ki < 4; ki++){
    int koh = 768 + w * 128 + ki * 32 + (l >> 4) * 8;
    int koo = 256 + w * 128 + ki * 32 + (l >> 4) * 8;
#pragma unroll
    for (int gi = 0; gi < 4; gi++){
      bh[ki][gi] = *(const s16x8*)&WF[(size_t)(gi * 512 + ns + (l & 15)) * 1280 + koh];
      bo[ki][gi] = *(const s16x8*)&WF[(size_t)(gi * 512 + ns + (l & 15)) * 1280 + koo];
    }
  }

  for (int t = 0; t < 256; ++t){
    const u32 tg = (u32)t;
    const int rp = (t + 1) & 1;
    f32x4 acc[2][4];
#pragma unroll
    for (int a = 0; a < 2; a++)
#pragma unroll
      for (int b = 0; b < 4; b++){ f32x4 z = {0.f,0.f,0.f,0.f}; acc[a][b] = z; }

#pragma unroll
    for (int ki = 0; ki < 2; ki++){
      int ko = w * 64 + ki * 32 + (l >> 4) * 8;
      s16x8 av[2];
#pragma unroll
      for (int mi = 0; mi < 2; mi++)
        av[mi] = *(const s16x8*)&XS[(size_t)(t * 32 + mi * 16 + (l & 15)) * 256 + ko];
#pragma unroll
      for (int mi = 0; mi < 2; mi++)
#pragma unroll
        for (int gi = 0; gi < 4; gi++)
          acc[mi][gi] = __builtin_amdgcn_mfma_f32_16x16x32_bf16(av[mi], bx[ki][gi], acc[mi][gi], 0, 0, 0);
    }
    if (t > 0){
#pragma unroll
      for (int kk = 0; kk < 4; kk++){
        int wb = w * 64 + kk * 16 + ((l >> 4) << 2);
        const u64* p0 = &ZH[(size_t)rp * 8192 + (size_t)(l & 15) * 256 + wb];
        const u64* p1 = &ZH[(size_t)rp * 8192 + (size_t)(16 + (l & 15)) * 256 + wb];
        u64 qa0,qa1,qa2,qa3,qb0,qb1,qb2,qb3; bool ok;
        do {
          qa0=tload(p0); qa1=tload(p0+1); qa2=tload(p0+2); qa3=tload(p0+3);
          qb0=tload(p1); qb1=tload(p1+1); qb2=tload(p1+2); qb3=tload(p1+3);
          ok = (wtag(qa0)==tg)&(wtag(qa1)==tg)&(wtag(qa2)==tg)&(wtag(qa3)==tg)
             & (wtag(qb0)==tg)&(wtag(qb1)==tg)&(wtag(qb2)==tg)&(wtag(qb3)==tg);
          if (!ok) __builtin_amdgcn_s_sleep(1);
        } while (!__all(ok));
        s16x8 av0 = pack4(qa0,qa1,qa2,qa3), av1 = pack4(qb0,qb1,qb2,qb3);
#pragma unroll
        for (int gi = 0; gi < 4; gi++){
          acc[0][gi] = __builtin_amdgcn_mfma_f32_16x16x32_bf16(av0, bh[kk][gi], acc[0][gi], 0, 0, 0);
          acc[1][gi] = __builtin_amdgcn_mfma_f32_16x16x32_bf16(av1, bh[kk][gi], acc[1][gi], 0, 0, 0);
        }
      }
#pragma unroll
      for (int kk = 0; kk < 4; kk++){
        int wb = w * 64 + kk * 16 + ((l >> 4) << 2);
        const u64* p0 = &ZO[(size_t)rp * 8192 + (size_t)(l & 15) * 256 + wb];
        const u64* p1 = &ZO[(size_t)rp * 8192 + (size_t)(16 + (l & 15)) * 256 + wb];
        u64 qa0,qa1,qa2,qa3,qb0,qb1,qb2,qb3; bool ok;
        do {
          qa0=tload(p0); qa1=tload(p0+1); qa2=tload(p0+2); qa3=tload(p0+3);
          qb0=tload(p1); qb1=tload(p1+1); qb2=tload(p1+2); qb3=tload(p1+3);
          ok = (wtag(qa0)==tg)&(wtag(qa1)==tg)&(wtag(qa2)==tg)&(wtag(qa3)==tg)
             & (wtag(qb0)==tg)&(wtag(qb1)==tg)&(wtag(qb2)==tg)&(wtag(qb3)==tg);
          if (!ok) __builtin_amdgcn_s_sleep(1);
        } while (!__all(ok));
        s16x8 av0 = pack4(qa0,qa1,qa2,qa3), av1 = pack4(qb0,qb1,qb2,qb3);
#pragma unroll
        for (int gi = 0; gi < 4; gi++){
          acc[0][gi] = __builtin_amdgcn_mfma_f32_16x16x32_bf16(av0, bo[kk][gi], acc[0][gi], 0, 0, 0);
          acc[1][gi] = __builtin_amdgcn_mfma_f32_16x16x32_bf16(av1, bo[kk][gi], acc[1][gi], 0, 0, 0);
        }
      }
    }
#pragma unroll
    for (int mi = 0; mi < 2; mi++)
#pragma unroll
      for (int gi = 0; gi < 4; gi++)
#pragma unroll
        for (int r = 0; r < 4; r++)
          red[w][mi * 16 + (l >> 4) * 4 + r][gi * 16 + (l & 15)] = acc[mi][gi][r];
    __syncthreads();
    {
      int bi = tid >> 3, j = (tid & 7) * 2;
      float iv0=0,fv0=0,gv0=0,ov0=0, iv1=0,fv1=0,gv1=0,ov1=0;
#pragma unroll
      for (int qq = 0; qq < 4; qq++){
        iv0 += red[qq][bi][j];      fv0 += red[qq][bi][16 + j];
        gv0 += red[qq][bi][32 + j]; ov0 += red[qq][bi][48 + j];
        iv1 += red[qq][bi][j + 1];      fv1 += red[qq][bi][16 + j + 1];
        gv1 += red[qq][bi][32 + j + 1]; ov1 += red[qq][bi][48 + j + 1];
      }
      int n0 = ns + j;
      float c0 = (t > 0) ? CST[bi * 512 + n0]     : 0.f;
      float c1 = (t > 0) ? CST[bi * 512 + n0 + 1] : 0.f;
      float cn0 = sigm(fv0) * c0 + sigm(iv0) * tanhf(gv0);
      float cn1 = sigm(fv1) * c1 + sigm(iv1) * tanhf(gv1);
      float h0 = sigm(ov0) * tanhf(cn0);
      float h1 = sigm(ov1) * tanhf(cn1);
      CST[bi * 512 + n0] = cn0; CST[bi * 512 + n0 + 1] = cn1;
      u32 pk = (u32)f2bf(h0) | ((u32)f2bf(h1) << 16);
      tstore(&ZH[(size_t)(t & 1) * 8192 + (size_t)bi * 256 + g * 8 + (tid & 7)],
             ((u64)(u32)(t + 1) << 32) | pk);
    }
    __syncthreads();
  }
}

// ---------------- attn+out role (gid>=32): MFMA everywhere; tagged polls ----------------

static __device__ void attn_role(const u16* __restrict__ CNN2, const u16* __restrict__ CNNB,
                                 const u16* __restrict__ WOUT,
                                 u64* __restrict__ ZH, u64* __restrict__ ZO,
                                 u64* __restrict__ UT, u64* __restrict__ MST,
                                 u16* __restrict__ OALL, float* __restrict__ SM, int q){
  const int tid = threadIdx.x, w = tid >> 6, l = tid & 63;
  const int b = q / 7, ch = q - b * 7;
  const int l0 = ch * 112;
  const int nc = (ch == 6) ? 68 : 74, cs = ch * 74;
  u16*   hsh  = (u16*)SM;          // 512 u16 = words [0,256)
  u16*   pbf  = (u16*)(SM + 256);  // 128 u16
  float* sc   = SM + 320;          // [128]
  float* scp  = SM + 448;          // [4][112]
  float* msh  = SM + 896;          // [14]
  u32*   zsh  = (u32*)(SM + 912);  // [512]
  float* opart= SM + 1424;         // [4][80]
  float* pexp = SM + 1744;         // [128]

  s16x8 a2[7][4];
  s16x8 vb[8][4];
#pragma unroll
  for (int tile = 0; tile < 7; tile++)
#pragma unroll
    for (int kk = 0; kk < 4; kk++)
      a2[tile][kk] = *(const s16x8*)&CNN2[(size_t)(b * 784 + l0 + tile * 16 + (l & 15)) * 512
                                          + w * 128 + kk * 32 + (l >> 4) * 8];
#pragma unroll
  for (int nt = 0; nt < 8; nt++)
#pragma unroll
    for (int kk = 0; kk < 4; kk++){
      int col = w * 128 + nt * 16 + (l & 15);
#pragma unroll
      for (int j = 0; j < 8; j++){
        int krow = kk * 32 + (l >> 4) * 8 + j;
        vb[nt][kk][j] = (krow < 112)
          ? (short)CNNB[(size_t)(b * 784 + l0 + krow) * 512 + col] : (short)0;
      }
    }

  for (int t = 0; t < 256; ++t){
    const u32 tagp = (u32)(t + 1);
    // ---- h(t) poll: one tagged word per thread ----
    {
      const u64* hp = &ZH[(size_t)(t & 1) * 8192 + (size_t)b * 256 + tid];
      u64 hw; bool ok;
      do {
        hw = tload(hp);
        ok = (wtag(hw) == tagp);
        if (!ok) __builtin_amdgcn_s_sleep(1);
      } while (!__all(ok));
      ((u32*)hsh)[tid] = (u32)hw;
    }
    __syncthreads();

    // ---- scores: 7 tiles x 4 kk MFMA (B = h broadcast) ----
    f32x4 sac[7];
#pragma unroll
    for (int tile = 0; tile < 7; tile++){ f32x4 z = {0.f,0.f,0.f,0.f}; sac[tile] = z; }
#pragma unroll
    for (int kk = 0; kk < 4; kk++){
      s16x8 bv = *(const s16x8*)&hsh[w * 128 + kk * 32 + (l >> 4) * 8];
#pragma unroll
      for (int tile = 0; tile < 7; tile++)
        sac[tile] = __builtin_amdgcn_mfma_f32_16x16x32_bf16(a2[tile][kk], bv, sac[tile], 0, 0, 0);
    }
    if ((l & 15) == 0){
#pragma unroll
      for (int tile = 0; tile < 7; tile++)
#pragma unroll
        for (int r = 0; r < 4; r++)
          scp[w * 112 + tile * 16 + (l >> 4) * 4 + r] = sac[tile][r];
    }
    __syncthreads();                               // bar1: scp ready
    if (tid < 112) sc[tid] = scp[tid] + scp[112 + tid] + scp[224 + tid] + scp[336 + tid];
    else if (tid < 128) sc[tid] = -1e30f;
    __syncthreads();                               // bar2: sc ready
    float m2 = fmaxf(sc[l], sc[l + 64]);
#pragma unroll
    for (int mk = 1; mk < 64; mk <<= 1) m2 = fmaxf(m2, __shfl_xor(m2, mk, 64));
    float M = m2;
    if (tid < 112){ float p = __expf(sc[tid] - M); pexp[tid] = p; pbf[tid] = f2bf(p); }
    else if (tid < 128){ pexp[tid] = 0.f; pbf[tid] = 0; }
    __syncthreads();                               // bar3: pexp/pbf ready
    float s2 = pexp[l] + pexp[l + 64];
#pragma unroll
    for (int mk = 1; mk < 64; mk <<= 1) s2 += __shfl_xor(s2, mk, 64);
    float S = s2;

    // ---- PV: 8 n-tiles x 4 kk MFMA (A = p broadcast) ----
    f32x4 uac[8];
#pragma unroll
    for (int nt = 0; nt < 8; nt++){ f32x4 z = {0.f,0.f,0.f,0.f}; uac[nt] = z; }
#pragma unroll
    for (int kk = 0; kk < 4; kk++){
      s16x8 av = *(const s16x8*)&pbf[kk * 32 + (l >> 4) * 8];
#pragma unroll
      for (int nt = 0; nt < 8; nt++)
        uac[nt] = __builtin_amdgcn_mfma_f32_16x16x32_bf16(av, vb[nt][kk], uac[nt], 0, 0, 0);
    }
#pragma unroll
    for (int nt = 0; nt < 8; nt++){
      float o0 = uac[nt][0];
      float o1 = __shfl_xor(o0, 1, 64);
      if (l < 16 && (l & 1) == 0){
        u64 wv = ((u64)tagp << 32) | (u32)f2bf(o0) | ((u32)f2bf(o1) << 16);
        tstore(&UT[((size_t)(b * 7 + ch)) * 256 + w * 64 + nt * 8 + (l >> 1)], wv);
      }
    }
    if (tid == 0){
      tstore(&MST[(b * 7 + ch) * 2 + 0], ((u64)tagp << 32) | __builtin_bit_cast(u32, M));
      tstore(&MST[(b * 7 + ch) * 2 + 1], ((u64)tagp << 32) | __builtin_bit_cast(u32, S));
    }

    // ---- merged sibling poll: UT (7 words/thread) + MST (wave0 lanes<14) ----
    u64 uw[7]; u64 msv = 0;
    {
      bool ok;
      do {
#pragma unroll
        for (int c = 0; c < 7; c++) uw[c] = tload(&UT[((size_t)(b * 7 + c)) * 256 + tid]);
        ok = true;
#pragma unroll
        for (int c = 0; c < 7; c++) ok &= (wtag(uw[c]) == tagp);
        if (w == 0){
          msv = tload(&MST[b * 14 + ((l < 14) ? l : 0)]);
          ok &= (wtag(msv) == tagp);
        }
        if (!ok) __builtin_amdgcn_s_sleep(1);
      } while (!__all(ok));
    }
    if (w == 0 && l < 14) msh[l] = __builtin_bit_cast(float, (u32)msv);
    __syncthreads();
    float Mg = -1e30f;
#pragma unroll
    for (int c = 0; c < 7; c++) Mg = fmaxf(Mg, msh[2 * c]);
    float bet[7]; float Sg = 0.f;
#pragma unroll
    for (int c = 0; c < 7; c++){
      float e = __expf(msh[2 * c] - Mg);
      bet[c] = e; Sg += e * msh[2 * c + 1];
    }
    float inv = 1.f / Sg;
    {
      float c0 = 0.f, c1 = 0.f;
#pragma unroll
      for (int c = 0; c < 7; c++){
        float bc = bet[c] * inv;
        c0 = fmaf(bc, bf2f((u16)uw[c]), c0);
        c1 = fmaf(bc, bf2f((u16)(uw[c] >> 16)), c1);
      }
      zsh[tid] = (u32)f2bf(c0) | ((u32)f2bf(c1) << 16);
      zsh[256 + tid] = ((u32*)hsh)[tid];
    }
    __syncthreads();

    // ---- out: 5 tiles x 8 kk MFMA (A = WOUT streamed, B = zsh broadcast) ----
    f32x4 oac[5];
#pragma unroll
    for (int tile = 0; tile < 5; tile++){ f32x4 z = {0.f,0.f,0.f,0.f}; oac[tile] = z; }
#pragma unroll
    for (int kk = 0; kk < 8; kk++){
      int ko = w * 256 + kk * 32 + (l >> 4) * 8;
      s16x8 bv = *(const s16x8*)((const u16*)zsh + ko);
#pragma unroll
      for (int tile = 0; tile < 5; tile++){
        int row = cs + tile * 16 + (l & 15);
        row = (row < 511) ? row : 511;
        s16x8 av = *(const s16x8*)&WOUT[(size_t)row * 1024 + ko];
        oac[tile] = __builtin_amdgcn_mfma_f32_16x16x32_bf16(av, bv, oac[tile], 0, 0, 0);
      }
    }
    if ((l & 15) == 0){
#pragma unroll
      for (int tile = 0; tile < 5; tile++)
#pragma unroll
        for (int r = 0; r < 4; r++)
          opart[w * 80 + tile * 16 + (l >> 4) * 4 + r] = oac[tile][r];
    }
    __syncthreads();
    if (tid < (nc >> 1)){
      int j0 = 2 * tid;
      float v0 = opart[j0]   + opart[80 + j0]   + opart[160 + j0]   + opart[240 + j0];
      float v1 = opart[j0+1] + opart[80 + j0+1] + opart[160 + j0+1] + opart[240 + j0+1];
      u32 pk = (u32)f2bf(tanhf(v0)) | ((u32)f2bf(tanhf(v1)) << 16);
      tstore(&ZO[(size_t)(t & 1) * 8192 + (size_t)b * 256 + (cs >> 1) + tid],
             ((u64)tagp << 32) | pk);
      *(u32*)&OALL[((size_t)(b * 256 + t)) * 512 + cs + j0] = pk;
    }
    __syncthreads();
  }
}

// ---------------- persistent decoder ----------------

__global__ __launch_bounds__(256, 1) void k_persist(const u16* __restrict__ WF,
                                                    const u16* __restrict__ XS,
                                                    const u16* __restrict__ CNN2,
                                                    const u16* __restrict__ CNNB,
                                                    const u16* __restrict__ WOUT,
                                                    u64* __restrict__ ZH,
                                                    u64* __restrict__ ZO,
                                                    u64* __restrict__ UT,
                                                    u64* __restrict__ MST,
                                                    float* __restrict__ CST,
                                                    u16* __restrict__ OALL){
  __shared__ __align__(16) float SM[8192];
  int gid = blockIdx.x;
  if (gid < 32)
    gates_role(WF, XS, ZH, ZO, CST, SM, gid);
  else
    attn_role(CNN2, CNNB, WOUT, ZH, ZO, UT, MST, OALL, SM, gid - 32);
}

// ---------------- log_softmax: 2-pass online, float4 ----------------

__global__ __launch_bounds__(256) void k_lsm(float* __restrict__ x){
  size_t base = (size_t)blockIdx.x * 8000;
  int tid = threadIdx.x, w = tid >> 6, ln = tid & 63;
  __shared__ float sm_[4], ss_[4];
  const float4* xv = (const float4*)(x + base);   // 2000 float4 per row
  float m = -1e30f, s = 0.f;
  for (int v = tid; v < 2000; v += 256){
    float4 f = xv[v];
    float mm = fmaxf(fmaxf(f.x, f.y), fmaxf(f.z, f.w));
    float ss = __expf(f.x-mm)+__expf(f.y-mm)+__expf(f.z-mm)+__expf(f.w-mm);
    float nm = fmaxf(m, mm);
    s = s * __expf(m - nm) + ss * __expf(mm - nm);
    m = nm;
  }
#pragma unroll
  for (int mk = 1; mk < 64; mk <<= 1){
    float mo = __shfl_xor(m, mk, 64), so = __shfl_xor(s, mk, 64);
    float nm = fmaxf(m, mo);
    s = s * __expf(m - nm) + so * __expf(mo - nm);
    m = nm;
  }
  if (ln == 0){ sm_[w] = m; ss_[w] = s; }
  __syncthreads();
  float M = -1e30f, S = 0.f;
#pragma unroll
  for (int q2 = 0; q2 < 4; q2++){
    float mo = sm_[q2], so = ss_[q2];
    float nm = fmaxf(M, mo);
    S = S * __expf(M - nm) + so * __expf(mo - nm);
    M = nm;
  }
  float lz = M + logf(S);
  float4* xw = (float4*)(x + base);
  for (int v = tid; v < 2000; v += 256){
    float4 f = xw[v];
    f.x -= lz; f.y -= lz; f.z -= lz; f.w -= lz;
    xw[v] = f;
  }
}

// ---------------- launcher ----------------

extern "C" void kernel_launch(void* const* d_in, const int* in_sizes, int n_in,
                              void* d_out, int out_size, void* d_ws, size_t ws_size,
                              hipStream_t stream){
  const float* cnn  = (const float*)d_in[0];
  const int*   seq  = (const int*)d_in[1];
  const float* emb  = (const float*)d_in[2];
  const float* wih  = (const float*)d_in[3];
  const float* whh  = (const float*)d_in[4];
  const float* whm  = (const float*)d_in[5];
  const float* wo   = (const float*)d_in[6];
  const float* wlg  = (const float*)d_in[7];
  const float* blg  = (const float*)d_in[8];

  char* ws = (char*)d_ws;
  u16*   WF     = (u16*)(ws + 0);          // 2048x1280 bf16 = 5,242,880
  u16*   WHMT   = (u16*)(ws + 5242880);    // 512x512 bf16   =   524,288
  u16*   WOUT   = (u16*)(ws + 5767168);    // 512x1024 bf16  = 1,048,576
  u16*   WLOGIT = (u16*)(ws + 6815744);    // 8000x512 bf16  = 8,192,000
  u16*   CNNBF  = (u16*)(ws + 15007744);   // 25088x512 bf16 = 25,690,112
  u16*   CNN2   = (u16*)(ws + 40697856);   // 25088x512 bf16 = 25,690,112
  u16*   XS     = (u16*)(ws + 66387968);   // [256][32][256] bf16 = 4,194,304
  u16*   OALL   = (u16*)(ws + 70582272);   // 8192x512 bf16  = 8,388,608
  u64*   ZH     = (u64*)(ws + 78970880);   // [2][32][256] u64 = 131,072
  u64*   ZO     = (u64*)(ws + 79101952);   // [2][32][256] u64 = 131,072
  u64*   UT     = (u64*)(ws + 79233024);   // [32][7][256] u64 = 458,752
  u64*   MST    = (u64*)(ws + 79691776);   // [32][7][2] u64 = 3,584
  float* CST    = (float*)(ws + 79695360); // 32x512 f32 = 65,536 -> ends 79,760,896

  float* OUT = (float*)d_out;

  (void)hipMemsetAsync(ws + 78970880, 0, 724480, stream);   // ZH..MST tags -> 0
  k_wfull<<<512, 256, 0, stream>>>(wih, whh, WF);
  k_whmt<<<128, 256, 0, stream>>>(whm, WHMT);
  k_cvt<<<512, 256, 0, stream>>>(wo, WOUT, 512 * 1024);
  k_cvt<<<2048, 256, 0, stream>>>(wlg, WLOGIT, 8000 * 512);
  k_cvt<<<2048, 256, 0, stream>>>(cnn, CNNBF, 25088 * 512);
  k_xs<<<2048, 256, 0, stream>>>(seq, emb, XS);

  {
    dim3 g(196, 4);   // CNN2 = CNNB @ WHMT^T
    k_gemm<1, 0, 0><<<g, 256, 0, stream>>>(CNNBF, WHMT, CNN2, nullptr, 25088, 512, 512);
  }

  k_persist<<<256, 256, 0, stream>>>(WF, XS, CNN2, CNNBF, WOUT, ZH, ZO, UT, MST, CST, OALL);

  {
    dim3 g(64, 63);
    k_gemm<0, 1, 1><<<g, 256, 0, stream>>>(OALL, WLOGIT, OUT, blg, 8192, 8000, 512);
  }
  k_lsm<<<8192, 256, 0, stream>>>(OUT);
}

// Round 13
// 3243.104 us; speedup vs baseline: 2.6868x; 1.0318x over previous
//
#include <hip/hip_runtime.h>
#include <hip/hip_bf16.h>
#include <stdint.h>

typedef unsigned short u16;
typedef unsigned int u32;
typedef unsigned long long u64;
typedef __attribute__((ext_vector_type(8))) short s16x8;
typedef __attribute__((ext_vector_type(4))) float f32x4;

#define AGT __HIP_MEMORY_SCOPE_AGENT

static __device__ __forceinline__ float bf2f(u16 u){
  unsigned v = ((unsigned)u) << 16; return __builtin_bit_cast(float, v);
}
static __device__ __forceinline__ u16 f2bf(float f){
  unsigned u = __builtin_bit_cast(unsigned, f);
  u += 0x7FFFu + ((u >> 16) & 1u);
  return (u16)(u >> 16);
}
static __device__ __forceinline__ float sigm(float x){ return 1.f / (1.f + __expf(-x)); }

typedef __attribute__((address_space(1))) const u32 gu32;
typedef __attribute__((address_space(3))) u32 lu32;
static __device__ __forceinline__ void gload_lds16(const void* g, void* l){
  __builtin_amdgcn_global_load_lds((gu32*)g, (lu32*)l, 16, 0, 0);
}

// ---- tagged-word sync: u64 = (step_tag << 32) | payload32 ----
static __device__ __forceinline__ u64 tload(const u64* p){
  return __hip_atomic_load(p, __ATOMIC_RELAXED, AGT);
}
static __device__ __forceinline__ void tstore(u64* p, u64 v){
  __hip_atomic_store(p, v, __ATOMIC_RELAXED, AGT);
}
static __device__ __forceinline__ u32 wtag(u64 v){ return (u32)(v >> 32); }
static __device__ __forceinline__ s16x8 pack4(u64 q0, u64 q1, u64 q2, u64 q3){
  u32 a0=(u32)q0, a1=(u32)q1, a2=(u32)q2, a3=(u32)q3;
  s16x8 r = {(short)a0,(short)(a0>>16),(short)a1,(short)(a1>>16),
             (short)a2,(short)(a2>>16),(short)a3,(short)(a3>>16)};
  return r;
}

// ---------------- prep kernels ----------------

__global__ __launch_bounds__(256) void k_wfull(const float* __restrict__ wih,
                                               const float* __restrict__ whh,
                                               u16* __restrict__ wf){
  int stride = gridDim.x * blockDim.x;
  for (int i = blockIdx.x * blockDim.x + threadIdx.x; i < 2048 * 1280; i += stride){
    int j = i / 1280, k = i - j * 1280;
    float v = (k < 768) ? wih[j * 768 + k] : whh[j * 512 + (k - 768)];
    wf[i] = f2bf(v);
  }
}

__global__ __launch_bounds__(256) void k_whmt(const float* __restrict__ whm,
                                              u16* __restrict__ wt){
  int stride = gridDim.x * blockDim.x;
  for (int i = blockIdx.x * blockDim.x + threadIdx.x; i < 512 * 512; i += stride){
    int n = i >> 9, k = i & 511;
    wt[i] = f2bf(whm[k * 512 + n]);
  }
}

__global__ __launch_bounds__(256) void k_cvt(const float* __restrict__ s,
                                             u16* __restrict__ d, int n){
  int stride = gridDim.x * blockDim.x * 4;
  for (int i = (blockIdx.x * blockDim.x + threadIdx.x) * 4; i < n; i += stride){
    float4 v = *(const float4*)&s[i];
    d[i + 0] = f2bf(v.x); d[i + 1] = f2bf(v.y);
    d[i + 2] = f2bf(v.z); d[i + 3] = f2bf(v.w);
  }
}

__global__ __launch_bounds__(256) void k_xs(const int* __restrict__ seq,
                                            const float* __restrict__ emb,
                                            u16* __restrict__ xs){
  int stride = gridDim.x * blockDim.x;
  for (int i = blockIdx.x * blockDim.x + threadIdx.x; i < 8192 * 256; i += stride){
    int m = i >> 8, e = i & 255;
    int b = m >> 8, t = m & 255;
    float v = emb[(size_t)seq[m] * 256 + e];
    xs[(size_t)(t * 32 + b) * 256 + e] = f2bf(v > 0.f ? v : 0.f);
  }
}

// ---------------- 128x128 bf16 MFMA GEMM: C = A[M,K] @ B[N,K]^T ----------------

template<int OUTBF, int HASBIAS, int NG>
__global__ __launch_bounds__(256) void k_gemm(const u16* __restrict__ A,
                                              const u16* __restrict__ Bm,
                                              void* __restrict__ Cout,
                                              const float* __restrict__ bias,
                                              int M, int N, int K){
  __shared__ __align__(16) u16 As[128 * 64];
  __shared__ __align__(16) u16 Bs[128 * 64];
  int tid = threadIdx.x; int w = tid >> 6; int l = tid & 63;
  int m0 = blockIdx.x * 128, n0 = blockIdx.y * 128;
  int wr = w >> 1, wc = w & 1;
  f32x4 acc[4][4];
#pragma unroll
  for (int a = 0; a < 4; a++)
#pragma unroll
    for (int b = 0; b < 4; b++){ f32x4 z = {0.f,0.f,0.f,0.f}; acc[a][b] = z; }
  int rA = m0 + (tid >> 3);
  int rB = n0 + (tid >> 3);
  for (int k0 = 0; k0 < K; k0 += 64){
    __syncthreads();
    int ca = k0 + (tid & 7) * 8;
#pragma unroll
    for (int i = 0; i < 4; i++){
      gload_lds16(&A[(size_t)(rA + i * 32) * K + ca], &As[i * 2048 + w * 512]);
      int rb = rB + i * 32;
      if (NG) rb = (rb < N - 1) ? rb : (N - 1);
      gload_lds16(&Bm[(size_t)rb * K + ca], &Bs[i * 2048 + w * 512]);
    }
    asm volatile("s_waitcnt vmcnt(0)" ::: "memory");
    __syncthreads();
#pragma unroll
    for (int ks = 0; ks < 2; ks++){
      s16x8 av[4], bv[4];
      int ko = ks * 32 + (l >> 4) * 8;
#pragma unroll
      for (int i = 0; i < 4; i++) av[i] = *(const s16x8*)&As[(wr * 64 + i * 16 + (l & 15)) * 64 + ko];
#pragma unroll
      for (int i = 0; i < 4; i++) bv[i] = *(const s16x8*)&Bs[(wc * 64 + i * 16 + (l & 15)) * 64 + ko];
#pragma unroll
      for (int mi = 0; mi < 4; mi++)
#pragma unroll
        for (int ni = 0; ni < 4; ni++)
          acc[mi][ni] = __builtin_amdgcn_mfma_f32_16x16x32_bf16(av[mi], bv[ni], acc[mi][ni], 0, 0, 0);
    }
  }
#pragma unroll
  for (int mi = 0; mi < 4; mi++)
#pragma unroll
    for (int ni = 0; ni < 4; ni++){
      int row = m0 + wr * 64 + mi * 16 + (l >> 4) * 4;
      int col = n0 + wc * 64 + ni * 16 + (l & 15);
      if (NG && col >= N) continue;
#pragma unroll
      for (int r = 0; r < 4; r++){
        float v = acc[mi][ni][r];
        if (HASBIAS) v += bias[col];
        if (OUTBF) ((u16*)Cout)[(size_t)(row + r) * N + col] = f2bf(v);
        else       ((float*)Cout)[(size_t)(row + r) * N + col] = v;
      }
    }
}

// ---------------- gates role (gid<32): W pinned; tagged h/out polls ----------------

static __device__ void gates_role(const u16* __restrict__ WF, const u16* __restrict__ XS,
                                  u64* __restrict__ ZH, u64* __restrict__ ZO,
                                  float* __restrict__ CST, float* __restrict__ SM, int g){
  const int tid = threadIdx.x, w = tid >> 6, l = tid & 63;
  const int ns = g << 4;
  float (*red)[32][64] = (float(*)[32][64])SM;

  s16x8 bx[2][4], bh[4][4], bo[4][4];
#pragma unroll
  for (int ki = 0; ki < 2; ki++){
    int ko = w * 64 + ki * 32 + (l >> 4) * 8;
#pragma unroll
    for (int gi = 0; gi < 4; gi++)
      bx[ki][gi] = *(const s16x8*)&WF[(size_t)(gi * 512 + ns + (l & 15)) * 1280 + ko];
  }
#pragma unroll
  for (int ki = 0; ki < 4; ki++){
    int koh = 768 + w * 128 + ki * 32 + (l >> 4) * 8;
    int koo = 256 + w * 128 + ki * 32 + (l >> 4) * 8;
#pragma unroll
    for (int gi = 0; gi < 4; gi++){
      bh[ki][gi] = *(const s16x8*)&WF[(size_t)(gi * 512 + ns + (l & 15)) * 1280 + koh];
      bo[ki][gi] = *(const s16x8*)&WF[(size_t)(gi * 512 + ns + (l & 15)) * 1280 + koo];
    }
  }

  for (int t = 0; t < 256; ++t){
    const u32 tg = (u32)t;
    const int rp = (t + 1) & 1;
    f32x4 acc[2][4];
#pragma unroll
    for (int a = 0; a < 2; a++)
#pragma unroll
      for (int b = 0; b < 4; b++){ f32x4 z = {0.f,0.f,0.f,0.f}; acc[a][b] = z; }

#pragma unroll
    for (int ki = 0; ki < 2; ki++){
      int ko = w * 64 + ki * 32 + (l >> 4) * 8;
      s16x8 av[2];
#pragma unroll
      for (int mi = 0; mi < 2; mi++)
        av[mi] = *(const s16x8*)&XS[(size_t)(t * 32 + mi * 16 + (l & 15)) * 256 + ko];
#pragma unroll
      for (int mi = 0; mi < 2; mi++)
#pragma unroll
        for (int gi = 0; gi < 4; gi++)
          acc[mi][gi] = __builtin_amdgcn_mfma_f32_16x16x32_bf16(av[mi], bx[ki][gi], acc[mi][gi], 0, 0, 0);
    }
    if (t > 0){
#pragma unroll
      for (int kk = 0; kk < 4; kk++){
        int wb = w * 64 + kk * 16 + ((l >> 4) << 2);
        const u64* p0 = &ZH[(size_t)rp * 8192 + (size_t)(l & 15) * 256 + wb];
        const u64* p1 = &ZH[(size_t)rp * 8192 + (size_t)(16 + (l & 15)) * 256 + wb];
        u64 qa0,qa1,qa2,qa3,qb0,qb1,qb2,qb3; bool ok;
        do {
          qa0=tload(p0); qa1=tload(p0+1); qa2=tload(p0+2); qa3=tload(p0+3);
          qb0=tload(p1); qb1=tload(p1+1); qb2=tload(p1+2); qb3=tload(p1+3);
          ok = (wtag(qa0)==tg)&(wtag(qa1)==tg)&(wtag(qa2)==tg)&(wtag(qa3)==tg)
             & (wtag(qb0)==tg)&(wtag(qb1)==tg)&(wtag(qb2)==tg)&(wtag(qb3)==tg);
          if (!ok) __builtin_amdgcn_s_sleep(1);
        } while (!__all(ok));
        s16x8 av0 = pack4(qa0,qa1,qa2,qa3), av1 = pack4(qb0,qb1,qb2,qb3);
#pragma unroll
        for (int gi = 0; gi < 4; gi++){
          acc[0][gi] = __builtin_amdgcn_mfma_f32_16x16x32_bf16(av0, bh[kk][gi], acc[0][gi], 0, 0, 0);
          acc[1][gi] = __builtin_amdgcn_mfma_f32_16x16x32_bf16(av1, bh[kk][gi], acc[1][gi], 0, 0, 0);
        }
      }
#pragma unroll
      for (int kk = 0; kk < 4; kk++){
        int wb = w * 64 + kk * 16 + ((l >> 4) << 2);
        const u64* p0 = &ZO[(size_t)rp * 8192 + (size_t)(l & 15) * 256 + wb];
        const u64* p1 = &ZO[(size_t)rp * 8192 + (size_t)(16 + (l & 15)) * 256 + wb];
        u64 qa0,qa1,qa2,qa3,qb0,qb1,qb2,qb3; bool ok;
        do {
          qa0=tload(p0); qa1=tload(p0+1); qa2=tload(p0+2); qa3=tload(p0+3);
          qb0=tload(p1); qb1=tload(p1+1); qb2=tload(p1+2); qb3=tload(p1+3);
          ok = (wtag(qa0)==tg)&(wtag(qa1)==tg)&(wtag(qa2)==tg)&(wtag(qa3)==tg)
             & (wtag(qb0)==tg)&(wtag(qb1)==tg)&(wtag(qb2)==tg)&(wtag(qb3)==tg);
          if (!ok) __builtin_amdgcn_s_sleep(1);
        } while (!__all(ok));
        s16x8 av0 = pack4(qa0,qa1,qa2,qa3), av1 = pack4(qb0,qb1,qb2,qb3);
#pragma unroll
        for (int gi = 0; gi < 4; gi++){
          acc[0][gi] = __builtin_amdgcn_mfma_f32_16x16x32_bf16(av0, bo[kk][gi], acc[0][gi], 0, 0, 0);
          acc[1][gi] = __builtin_amdgcn_mfma_f32_16x16x32_bf16(av1, bo[kk][gi], acc[1][gi], 0, 0, 0);
        }
      }
    }
#pragma unroll
    for (int mi = 0; mi < 2; mi++)
#pragma unroll
      for (int gi = 0; gi < 4; gi++)
#pragma unroll
        for (int r = 0; r < 4; r++)
          red[w][mi * 16 + (l >> 4) * 4 + r][gi * 16 + (l & 15)] = acc[mi][gi][r];
    __syncthreads();
    {
      int bi = tid >> 3, j = (tid & 7) * 2;
      float iv0=0,fv0=0,gv0=0,ov0=0, iv1=0,fv1=0,gv1=0,ov1=0;
#pragma unroll
      for (int qq = 0; qq < 4; qq++){
        iv0 += red[qq][bi][j];      fv0 += red[qq][bi][16 + j];
        gv0 += red[qq][bi][32 + j]; ov0 += red[qq][bi][48 + j];
        iv1 += red[qq][bi][j + 1];      fv1 += red[qq][bi][16 + j + 1];
        gv1 += red[qq][bi][32 + j + 1]; ov1 += red[qq][bi][48 + j + 1];
      }
      int n0 = ns + j;
      float c0 = (t > 0) ? CST[bi * 512 + n0]     : 0.f;
      float c1 = (t > 0) ? CST[bi * 512 + n0 + 1] : 0.f;
      float cn0 = sigm(fv0) * c0 + sigm(iv0) * tanhf(gv0);
      float cn1 = sigm(fv1) * c1 + sigm(iv1) * tanhf(gv1);
      float h0 = sigm(ov0) * tanhf(cn0);
      float h1 = sigm(ov1) * tanhf(cn1);
      CST[bi * 512 + n0] = cn0; CST[bi * 512 + n0 + 1] = cn1;
      u32 pk = (u32)f2bf(h0) | ((u32)f2bf(h1) << 16);
      tstore(&ZH[(size_t)(t & 1) * 8192 + (size_t)bi * 256 + g * 8 + (tid & 7)],
             ((u64)(u32)(t + 1) << 32) | pk);
    }
    __syncthreads();
  }
}

// ---------------- attn+out role (gid>=32): MFMA everywhere; tagged polls ----------------
// LDS word map: hsh u16[512] @0; pbf u16[128] @256; scp f32[448] @320;
//               msh f32[14] @768; zsh u32[256] @784; opart f32[320] @1040

static __device__ void attn_role(const u16* __restrict__ CNN2, const u16* __restrict__ CNNB,
                                 const u16* __restrict__ WOUT,
                                 u64* __restrict__ ZH, u64* __restrict__ ZO,
                                 u64* __restrict__ UT, u64* __restrict__ MST,
                                 u16* __restrict__ OALL, float* __restrict__ SM, int q){
  const int tid = threadIdx.x, w = tid >> 6, l = tid & 63;
  const int b = q / 7, ch = q - b * 7;
  const int l0 = ch * 112;
  const int nc = (ch == 6) ? 68 : 74, cs = ch * 74;
  u16*   hsh  = (u16*)SM;
  u16*   pbf  = (u16*)(SM + 256);
  float* scp  = SM + 320;
  float* msh  = SM + 768;
  u32*   zsh  = (u32*)(SM + 784);
  float* opart= SM + 1040;

  s16x8 a2[7][4];
  s16x8 vb[8][4];
#pragma unroll
  for (int tile = 0; tile < 7; tile++)
#pragma unroll
    for (int kk = 0; kk < 4; kk++)
      a2[tile][kk] = *(const s16x8*)&CNN2[(size_t)(b * 784 + l0 + tile * 16 + (l & 15)) * 512
                                          + w * 128 + kk * 32 + (l >> 4) * 8];
#pragma unroll
  for (int nt = 0; nt < 8; nt++)
#pragma unroll
    for (int kk = 0; kk < 4; kk++){
      int col = w * 128 + nt * 16 + (l & 15);
#pragma unroll
      for (int j = 0; j < 8; j++){
        int krow = kk * 32 + (l >> 4) * 8 + j;
        vb[nt][kk][j] = (krow < 112)
          ? (short)CNNB[(size_t)(b * 784 + l0 + krow) * 512 + col] : (short)0;
      }
    }

  for (int t = 0; t < 256; ++t){
    const u32 tagp = (u32)(t + 1);
    // ---- h(t) poll: one tagged word per thread ----
    {
      const u64* hp = &ZH[(size_t)(t & 1) * 8192 + (size_t)b * 256 + tid];
      u64 hw; bool ok;
      do {
        hw = tload(hp);
        ok = (wtag(hw) == tagp);
        if (!ok) __builtin_amdgcn_s_sleep(1);
      } while (!__all(ok));
      ((u32*)hsh)[tid] = (u32)hw;
    }
    __syncthreads();

    // ---- scores: 7 tiles x 4 kk MFMA (B = h broadcast) ----
    f32x4 sac[7];
#pragma unroll
    for (int tile = 0; tile < 7; tile++){ f32x4 z = {0.f,0.f,0.f,0.f}; sac[tile] = z; }
#pragma unroll
    for (int kk = 0; kk < 4; kk++){
      s16x8 bv = *(const s16x8*)&hsh[w * 128 + kk * 32 + (l >> 4) * 8];
#pragma unroll
      for (int tile = 0; tile < 7; tile++)
        sac[tile] = __builtin_amdgcn_mfma_f32_16x16x32_bf16(a2[tile][kk], bv, sac[tile], 0, 0, 0);
    }
    if ((l & 15) == 0){
#pragma unroll
      for (int tile = 0; tile < 7; tile++)
#pragma unroll
        for (int r = 0; r < 4; r++)
          scp[w * 112 + tile * 16 + (l >> 4) * 4 + r] = sac[tile][r];
    }
    __syncthreads();                // bar: scp ready

    // ---- softmax: per-wave redundant, 0 extra barriers before pbf ----
    float v0 = scp[l] + scp[112 + l] + scp[224 + l] + scp[336 + l];
    float v64 = (l < 48) ? (scp[64 + l] + scp[176 + l] + scp[288 + l] + scp[400 + l]) : -1e30f;
    float m2 = fmaxf(v0, v64);
#pragma unroll
    for (int mk = 1; mk < 64; mk <<= 1) m2 = fmaxf(m2, __shfl_xor(m2, mk, 64));
    float M = m2;
    float p0 = __expf(v0 - M);
    float p64 = (l < 48) ? __expf(v64 - M) : 0.f;
    if (w == 0){ pbf[l] = f2bf(p0); pbf[64 + l] = f2bf(p64); }
    float s2 = p0 + p64;
#pragma unroll
    for (int mk = 1; mk < 64; mk <<= 1) s2 += __shfl_xor(s2, mk, 64);
    float S = s2;
    __syncthreads();                // bar: pbf ready

    // ---- PV: 8 n-tiles x 4 kk MFMA (A = p broadcast) ----
    f32x4 uac[8];
#pragma unroll
    for (int nt = 0; nt < 8; nt++){ f32x4 z = {0.f,0.f,0.f,0.f}; uac[nt] = z; }
#pragma unroll
    for (int kk = 0; kk < 4; kk++){
      s16x8 av = *(const s16x8*)&pbf[kk * 32 + (l >> 4) * 8];
#pragma unroll
      for (int nt = 0; nt < 8; nt++)
        uac[nt] = __builtin_amdgcn_mfma_f32_16x16x32_bf16(av, vb[nt][kk], uac[nt], 0, 0, 0);
    }
#pragma unroll
    for (int nt = 0; nt < 8; nt++){
      float o0 = uac[nt][0];
      float o1 = __shfl_xor(o0, 1, 64);
      if (l < 16 && (l & 1) == 0){
        u64 wv = ((u64)tagp << 32) | (u32)f2bf(o0) | ((u32)f2bf(o1) << 16);
        tstore(&UT[((size_t)(b * 7 + ch)) * 256 + w * 64 + nt * 8 + (l >> 1)], wv);
      }
    }
    if (tid == 0){
      tstore(&MST[(b * 7 + ch) * 2 + 0], ((u64)tagp << 32) | __builtin_bit_cast(u32, M));
      tstore(&MST[(b * 7 + ch) * 2 + 1], ((u64)tagp << 32) | __builtin_bit_cast(u32, S));
    }

    // ---- h-half of out projection (independent of ctx) — overlaps the D wait ----
    f32x4 oac[5];
#pragma unroll
    for (int tile = 0; tile < 5; tile++){ f32x4 z = {0.f,0.f,0.f,0.f}; oac[tile] = z; }
#pragma unroll
    for (int kk = 0; kk < 4; kk++){
      int ko = w * 128 + kk * 32 + (l >> 4) * 8;
      s16x8 bv = *(const s16x8*)&hsh[ko];
#pragma unroll
      for (int tile = 0; tile < 5; tile++){
        int row = cs + tile * 16 + (l & 15);
        row = (row < 511) ? row : 511;
        s16x8 av = *(const s16x8*)&WOUT[(size_t)row * 1024 + 512 + ko];
        oac[tile] = __builtin_amdgcn_mfma_f32_16x16x32_bf16(av, bv, oac[tile], 0, 0, 0);
      }
    }

    // ---- merged sibling poll: UT (7 words/thread) + MST (wave0 lanes<14) ----
    u64 uw[7]; u64 msv = 0;
    {
      bool ok;
      do {
#pragma unroll
        for (int c = 0; c < 7; c++) uw[c] = tload(&UT[((size_t)(b * 7 + c)) * 256 + tid]);
        ok = true;
#pragma unroll
        for (int c = 0; c < 7; c++) ok &= (wtag(uw[c]) == tagp);
        if (w == 0){
          msv = tload(&MST[b * 14 + ((l < 14) ? l : 0)]);
          ok &= (wtag(msv) == tagp);
        }
        if (!ok) __builtin_amdgcn_s_sleep(1);
      } while (!__all(ok));
    }
    if (w == 0 && l < 14) msh[l] = __builtin_bit_cast(float, (u32)msv);
    __syncthreads();
    float Mg = -1e30f;
#pragma unroll
    for (int c = 0; c < 7; c++) Mg = fmaxf(Mg, msh[2 * c]);
    float bet[7]; float Sg = 0.f;
#pragma unroll
    for (int c = 0; c < 7; c++){
      float e = __expf(msh[2 * c] - Mg);
      bet[c] = e; Sg += e * msh[2 * c + 1];
    }
    float inv = 1.f / Sg;
    {
      float c0 = 0.f, c1 = 0.f;
#pragma unroll
      for (int c = 0; c < 7; c++){
        float bc = bet[c] * inv;
        c0 = fmaf(bc, bf2f((u16)uw[c]), c0);
        c1 = fmaf(bc, bf2f((u16)(uw[c] >> 16)), c1);
      }
      zsh[tid] = (u32)f2bf(c0) | ((u32)f2bf(c1) << 16);
    }
    __syncthreads();

    // ---- ctx-half of out projection: 5 tiles x 4 kk MFMA into same oac ----
#pragma unroll
    for (int kk = 0; kk < 4; kk++){
      int ko = w * 128 + kk * 32 + (l >> 4) * 8;
      s16x8 bv = *(const s16x8*)((const u16*)zsh + ko);
#pragma unroll
      for (int tile = 0; tile < 5; tile++){
        int row = cs + tile * 16 + (l & 15);
        row = (row < 511) ? row : 511;
        s16x8 av = *(const s16x8*)&WOUT[(size_t)row * 1024 + ko];
        oac[tile] = __builtin_amdgcn_mfma_f32_16x16x32_bf16(av, bv, oac[tile], 0, 0, 0);
      }
    }
    if ((l & 15) == 0){
#pragma unroll
      for (int tile = 0; tile < 5; tile++)
#pragma unroll
        for (int r = 0; r < 4; r++)
          opart[w * 80 + tile * 16 + (l >> 4) * 4 + r] = oac[tile][r];
    }
    __syncthreads();
    if (tid < (nc >> 1)){
      int j0 = 2 * tid;
      float v0o = opart[j0]   + opart[80 + j0]   + opart[160 + j0]   + opart[240 + j0];
      float v1o = opart[j0+1] + opart[80 + j0+1] + opart[160 + j0+1] + opart[240 + j0+1];
      u32 pk = (u32)f2bf(tanhf(v0o)) | ((u32)f2bf(tanhf(v1o)) << 16);
      tstore(&ZO[(size_t)(t & 1) * 8192 + (size_t)b * 256 + (cs >> 1) + tid],
             ((u64)tagp << 32) | pk);
      *(u32*)&OALL[((size_t)(b * 256 + t)) * 512 + cs + j0] = pk;
    }
    __syncthreads();
  }
}

// ---------------- persistent decoder ----------------

__global__ __launch_bounds__(256, 1) void k_persist(const u16* __restrict__ WF,
                                                    const u16* __restrict__ XS,
                                                    const u16* __restrict__ CNN2,
                                                    const u16* __restrict__ CNNB,
                                                    const u16* __restrict__ WOUT,
                                                    u64* __restrict__ ZH,
                                                    u64* __restrict__ ZO,
                                                    u64* __restrict__ UT,
                                                    u64* __restrict__ MST,
                                                    float* __restrict__ CST,
                                                    u16* __restrict__ OALL){
  __shared__ __align__(16) float SM[8192];
  int gid = blockIdx.x;
  if (gid < 32)
    gates_role(WF, XS, ZH, ZO, CST, SM, gid);
  else
    attn_role(CNN2, CNNB, WOUT, ZH, ZO, UT, MST, OALL, SM, gid - 32);
}

// ---------------- log_softmax: 2-pass online, float4 ----------------

__global__ __launch_bounds__(256) void k_lsm(float* __restrict__ x){
  size_t base = (size_t)blockIdx.x * 8000;
  int tid = threadIdx.x, w = tid >> 6, ln = tid & 63;
  __shared__ float sm_[4], ss_[4];
  const float4* xv = (const float4*)(x + base);
  float m = -1e30f, s = 0.f;
  for (int v = tid; v < 2000; v += 256){
    float4 f = xv[v];
    float mm = fmaxf(fmaxf(f.x, f.y), fmaxf(f.z, f.w));
    float ss = __expf(f.x-mm)+__expf(f.y-mm)+__expf(f.z-mm)+__expf(f.w-mm);
    float nm = fmaxf(m, mm);
    s = s * __expf(m - nm) + ss * __expf(mm - nm);
    m = nm;
  }
#pragma unroll
  for (int mk = 1; mk < 64; mk <<= 1){
    float mo = __shfl_xor(m, mk, 64), so = __shfl_xor(s, mk, 64);
    float nm = fmaxf(m, mo);
    s = s * __expf(m - nm) + so * __expf(mo - nm);
    m = nm;
  }
  if (ln == 0){ sm_[w] = m; ss_[w] = s; }
  __syncthreads();
  float M = -1e30f, S = 0.f;
#pragma unroll
  for (int q2 = 0; q2 < 4; q2++){
    float mo = sm_[q2], so = ss_[q2];
    float nm = fmaxf(M, mo);
    S = S * __expf(M - nm) + so * __expf(mo - nm);
    M = nm;
  }
  float lz = M + logf(S);
  float4* xw = (float4*)(x + base);
  for (int v = tid; v < 2000; v += 256){
    float4 f = xw[v];
    f.x -= lz; f.y -= lz; f.z -= lz; f.w -= lz;
    xw[v] = f;
  }
}

// ---------------- launcher ----------------

extern "C" void kernel_launch(void* const* d_in, const int* in_sizes, int n_in,
                              void* d_out, int out_size, void* d_ws, size_t ws_size,
                              hipStream_t stream){
  const float* cnn  = (const float*)d_in[0];
  const int*   seq  = (const int*)d_in[1];
  const float* emb  = (const float*)d_in[2];
  const float* wih  = (const float*)d_in[3];
  const float* whh  = (const float*)d_in[4];
  const float* whm  = (const float*)d_in[5];
  const float* wo   = (const float*)d_in[6];
  const float* wlg  = (const float*)d_in[7];
  const float* blg  = (const float*)d_in[8];

  char* ws = (char*)d_ws;
  u16*   WF     = (u16*)(ws + 0);          // 2048x1280 bf16 = 5,242,880
  u16*   WHMT   = (u16*)(ws + 5242880);    // 512x512 bf16   =   524,288
  u16*   WOUT   = (u16*)(ws + 5767168);    // 512x1024 bf16  = 1,048,576
  u16*   WLOGIT = (u16*)(ws + 6815744);    // 8000x512 bf16  = 8,192,000
  u16*   CNNBF  = (u16*)(ws + 15007744);   // 25088x512 bf16 = 25,690,112
  u16*   CNN2   = (u16*)(ws + 40697856);   // 25088x512 bf16 = 25,690,112
  u16*   XS     = (u16*)(ws + 66387968);   // [256][32][256] bf16 = 4,194,304
  u16*   OALL   = (u16*)(ws + 70582272);   // 8192x512 bf16  = 8,388,608
  u64*   ZH     = (u64*)(ws + 78970880);   // [2][32][256] u64 = 131,072
  u64*   ZO     = (u64*)(ws + 79101952);   // [2][32][256] u64 = 131,072
  u64*   UT     = (u64*)(ws + 79233024);   // [32][7][256] u64 = 458,752
  u64*   MST    = (u64*)(ws + 79691776);   // [32][7][2] u64 = 3,584
  float* CST    = (float*)(ws + 79695360); // 32x512 f32 = 65,536 -> ends 79,760,896

  float* OUT = (float*)d_out;

  (void)hipMemsetAsync(ws + 78970880, 0, 724480, stream);   // ZH..MST tags -> 0
  k_wfull<<<512, 256, 0, stream>>>(wih, whh, WF);
  k_whmt<<<128, 256, 0, stream>>>(whm, WHMT);
  k_cvt<<<512, 256, 0, stream>>>(wo, WOUT, 512 * 1024);
  k_cvt<<<2048, 256, 0, stream>>>(wlg, WLOGIT, 8000 * 512);
  k_cvt<<<2048, 256, 0, stream>>>(cnn, CNNBF, 25088 * 512);
  k_xs<<<2048, 256, 0, stream>>>(seq, emb, XS);

  {
    dim3 g(196, 4);   // CNN2 = CNNB @ WHMT^T
    k_gemm<1, 0, 0><<<g, 256, 0, stream>>>(CNNBF, WHMT, CNN2, nullptr, 25088, 512, 512);
  }

  k_persist<<<256, 256, 0, stream>>>(WF, XS, CNN2, CNNBF, WOUT, ZH, ZO, UT, MST, CST, OALL);

  {
    dim3 g(64, 63);
    k_gemm<0, 1, 1><<<g, 256, 0, stream>>>(OALL, WLOGIT, OUT, blg, 8192, 8000, 512);
  }
  k_lsm<<<8192, 256, 0, stream>>>(OUT);
}

// Round 14
// 3232.787 us; speedup vs baseline: 2.6954x; 1.0032x over previous
//
#include <hip/hip_runtime.h>
#include <hip/hip_bf16.h>
#include <stdint.h>

typedef unsigned short u16;
typedef unsigned int u32;
typedef unsigned long long u64;
typedef __attribute__((ext_vector_type(8))) short s16x8;
typedef __attribute__((ext_vector_type(4))) float f32x4;

#define AGT __HIP_MEMORY_SCOPE_AGENT

static __device__ __forceinline__ float bf2f(u16 u){
  unsigned v = ((unsigned)u) << 16; return __builtin_bit_cast(float, v);
}
static __device__ __forceinline__ u16 f2bf(float f){
  unsigned u = __builtin_bit_cast(unsigned, f);
  u += 0x7FFFu + ((u >> 16) & 1u);
  return (u16)(u >> 16);
}
static __device__ __forceinline__ float sigm(float x){ return 1.f / (1.f + __expf(-x)); }

typedef __attribute__((address_space(1))) const u32 gu32;
typedef __attribute__((address_space(3))) u32 lu32;
static __device__ __forceinline__ void gload_lds16(const void* g, void* l){
  __builtin_amdgcn_global_load_lds((gu32*)g, (lu32*)l, 16, 0, 0);
}

// ---- tagged-word sync: u64 = (step_tag << 32) | payload32 ----
static __device__ __forceinline__ u64 tload(const u64* p){
  return __hip_atomic_load(p, __ATOMIC_RELAXED, AGT);
}
static __device__ __forceinline__ void tstore(u64* p, u64 v){
  __hip_atomic_store(p, v, __ATOMIC_RELAXED, AGT);
}
static __device__ __forceinline__ u32 wtag(u64 v){ return (u32)(v >> 32); }
static __device__ __forceinline__ s16x8 pack4(u64 q0, u64 q1, u64 q2, u64 q3){
  u32 a0=(u32)q0, a1=(u32)q1, a2=(u32)q2, a3=(u32)q3;
  s16x8 r = {(short)a0,(short)(a0>>16),(short)a1,(short)(a1>>16),
             (short)a2,(short)(a2>>16),(short)a3,(short)(a3>>16)};
  return r;
}

// ---------------- merged prep kernel ----------------
// blocks [0,512): WF; [512,640): WHMT; [640,1152): WOUT; [1152,2176): WLOGIT;
// [2176,4224): CNNBF; [4224,6272): XS

__global__ __launch_bounds__(256) void k_prep(const float* __restrict__ wih,
                                              const float* __restrict__ whh,
                                              u16* __restrict__ wf,
                                              const float* __restrict__ whm,
                                              u16* __restrict__ whmt,
                                              const float* __restrict__ wo,
                                              u16* __restrict__ wout,
                                              const float* __restrict__ wlg,
                                              u16* __restrict__ wlogit,
                                              const float* __restrict__ cnn,
                                              u16* __restrict__ cnnbf,
                                              const int* __restrict__ seq,
                                              const float* __restrict__ emb,
                                              u16* __restrict__ xs){
  int bid = blockIdx.x, tid = threadIdx.x;
  if (bid < 512){
    for (int i = bid * 256 + tid; i < 2048 * 1280; i += 512 * 256){
      int j = i / 1280, k = i - j * 1280;
      float v = (k < 768) ? wih[j * 768 + k] : whh[j * 512 + (k - 768)];
      wf[i] = f2bf(v);
    }
  } else if (bid < 640){
    for (int i = (bid - 512) * 256 + tid; i < 512 * 512; i += 128 * 256){
      int n = i >> 9, k = i & 511;
      whmt[i] = f2bf(whm[k * 512 + n]);
    }
  } else if (bid < 1152){
    for (int i = ((bid - 640) * 256 + tid) * 4; i < 512 * 1024; i += 512 * 256 * 4){
      float4 v = *(const float4*)&wo[i];
      wout[i+0]=f2bf(v.x); wout[i+1]=f2bf(v.y); wout[i+2]=f2bf(v.z); wout[i+3]=f2bf(v.w);
    }
  } else if (bid < 2176){
    for (int i = ((bid - 1152) * 256 + tid) * 4; i < 8000 * 512; i += 1024 * 256 * 4){
      float4 v = *(const float4*)&wlg[i];
      wlogit[i+0]=f2bf(v.x); wlogit[i+1]=f2bf(v.y); wlogit[i+2]=f2bf(v.z); wlogit[i+3]=f2bf(v.w);
    }
  } else if (bid < 4224){
    for (int i = ((bid - 2176) * 256 + tid) * 4; i < 25088 * 512; i += 2048 * 256 * 4){
      float4 v = *(const float4*)&cnn[i];
      cnnbf[i+0]=f2bf(v.x); cnnbf[i+1]=f2bf(v.y); cnnbf[i+2]=f2bf(v.z); cnnbf[i+3]=f2bf(v.w);
    }
  } else {
    for (int i = (bid - 4224) * 256 + tid; i < 8192 * 256; i += 2048 * 256){
      int m = i >> 8, e = i & 255;
      int b = m >> 8, t = m & 255;
      float v = emb[(size_t)seq[m] * 256 + e];
      xs[(size_t)(t * 32 + b) * 256 + e] = f2bf(v > 0.f ? v : 0.f);
    }
  }
}

// ---------------- 128x128 bf16 MFMA GEMM: C = A[M,K] @ B[N,K]^T ----------------
// STATS: also emit per-(row, col-tile) online-softmax stats (max, sumexp) incl. bias.

template<int OUTBF, int HASBIAS, int NG, int STATS>
__global__ __launch_bounds__(256) void k_gemm(const u16* __restrict__ A,
                                              const u16* __restrict__ Bm,
                                              void* __restrict__ Cout,
                                              const float* __restrict__ bias,
                                              float* __restrict__ stats,
                                              int M, int N, int K){
  __shared__ __align__(16) u16 As[128 * 64];
  __shared__ __align__(16) u16 Bs[128 * 64];
  int tid = threadIdx.x; int w = tid >> 6; int l = tid & 63;
  int m0 = blockIdx.x * 128, n0 = blockIdx.y * 128;
  int wr = w >> 1, wc = w & 1;
  f32x4 acc[4][4];
#pragma unroll
  for (int a = 0; a < 4; a++)
#pragma unroll
    for (int b = 0; b < 4; b++){ f32x4 z = {0.f,0.f,0.f,0.f}; acc[a][b] = z; }
  int rA = m0 + (tid >> 3);
  int rB = n0 + (tid >> 3);
  for (int k0 = 0; k0 < K; k0 += 64){
    __syncthreads();
    int ca = k0 + (tid & 7) * 8;
#pragma unroll
    for (int i = 0; i < 4; i++){
      gload_lds16(&A[(size_t)(rA + i * 32) * K + ca], &As[i * 2048 + w * 512]);
      int rb = rB + i * 32;
      if (NG) rb = (rb < N - 1) ? rb : (N - 1);
      gload_lds16(&Bm[(size_t)rb * K + ca], &Bs[i * 2048 + w * 512]);
    }
    asm volatile("s_waitcnt vmcnt(0)" ::: "memory");
    __syncthreads();
#pragma unroll
    for (int ks = 0; ks < 2; ks++){
      s16x8 av[4], bv[4];
      int ko = ks * 32 + (l >> 4) * 8;
#pragma unroll
      for (int i = 0; i < 4; i++) av[i] = *(const s16x8*)&As[(wr * 64 + i * 16 + (l & 15)) * 64 + ko];
#pragma unroll
      for (int i = 0; i < 4; i++) bv[i] = *(const s16x8*)&Bs[(wc * 64 + i * 16 + (l & 15)) * 64 + ko];
#pragma unroll
      for (int mi = 0; mi < 4; mi++)
#pragma unroll
        for (int ni = 0; ni < 4; ni++)
          acc[mi][ni] = __builtin_amdgcn_mfma_f32_16x16x32_bf16(av[mi], bv[ni], acc[mi][ni], 0, 0, 0);
    }
  }
#pragma unroll
  for (int mi = 0; mi < 4; mi++)
#pragma unroll
    for (int ni = 0; ni < 4; ni++){
      int row = m0 + wr * 64 + mi * 16 + (l >> 4) * 4;
      int col = n0 + wc * 64 + ni * 16 + (l & 15);
      if (NG && col >= N) continue;
#pragma unroll
      for (int r = 0; r < 4; r++){
        float v = acc[mi][ni][r];
        if (HASBIAS) v += bias[col];
        if (OUTBF) ((u16*)Cout)[(size_t)(row + r) * N + col] = f2bf(v);
        else       ((float*)Cout)[(size_t)(row + r) * N + col] = v;
      }
    }
  if (STATS){
    __syncthreads();
    float* st = (float*)As;   // [128 rows][2 halves][2]
#pragma unroll
    for (int mi = 0; mi < 4; mi++)
#pragma unroll
      for (int r = 0; r < 4; r++){
        float vv[4]; float mx = -1e30f;
#pragma unroll
        for (int ni = 0; ni < 4; ni++){
          int col = n0 + wc * 64 + ni * 16 + (l & 15);
          int cb = (NG && col >= N) ? (N - 1) : col;
          float v = acc[mi][ni][r] + (HASBIAS ? bias[cb] : 0.f);
          vv[ni] = (NG && col >= N) ? -1e30f : v;
          mx = fmaxf(mx, vv[ni]);
        }
        float sm = 0.f;
#pragma unroll
        for (int ni = 0; ni < 4; ni++) sm += (vv[ni] > -1e29f) ? __expf(vv[ni] - mx) : 0.f;
#pragma unroll
        for (int mk = 1; mk < 16; mk <<= 1){
          float mo = __shfl_xor(mx, mk, 64), so = __shfl_xor(sm, mk, 64);
          float nm = fmaxf(mx, mo);
          sm = sm * __expf(mx - nm) + so * __expf(mo - nm);
          mx = nm;
        }
        if ((l & 15) == 0){
          int rr = wr * 64 + mi * 16 + (l >> 4) * 4 + r;
          st[rr * 4 + wc * 2 + 0] = mx;
          st[rr * 4 + wc * 2 + 1] = sm;
        }
      }
    __syncthreads();
    if (tid < 128){
      float ma = st[tid*4], sa = st[tid*4+1], mb = st[tid*4+2], sb = st[tid*4+3];
      float nm = fmaxf(ma, mb);
      float ss = sa * __expf(ma - nm) + sb * __expf(mb - nm);
      size_t idx = ((size_t)(m0 + tid) * 64 + blockIdx.y) * 2;
      stats[idx] = nm; stats[idx + 1] = ss;
    }
  }
}

// ---------------- gates role (gid<32): W pinned; tagged h/out polls ----------------

static __device__ void gates_role(const u16* __restrict__ WF, const u16* __restrict__ XS,
                                  u64* __restrict__ ZH, u64* __restrict__ ZO,
                                  float* __restrict__ CST, float* __restrict__ SM, int g){
  const int tid = threadIdx.x, w = tid >> 6, l = tid & 63;
  const int ns = g << 4;
  float (*red)[32][64] = (float(*)[32][64])SM;

  s16x8 bx[2][4], bh[4][4], bo[4][4];
#pragma unroll
  for (int ki = 0; ki < 2; ki++){
    int ko = w * 64 + ki * 32 + (l >> 4) * 8;
#pragma unroll
    for (int gi = 0; gi < 4; gi++)
      bx[ki][gi] = *(const s16x8*)&WF[(size_t)(gi * 512 + ns + (l & 15)) * 1280 + ko];
  }
#pragma unroll
  for (int ki = 0; ki < 4; ki++){
    int koh = 768 + w * 128 + ki * 32 + (l >> 4) * 8;
    int koo = 256 + w * 128 + ki * 32 + (l >> 4) * 8;
#pragma unroll
    for (int gi = 0; gi < 4; gi++){
      bh[ki][gi] = *(const s16x8*)&WF[(size_t)(gi * 512 + ns + (l & 15)) * 1280 + koh];
      bo[ki][gi] = *(const s16x8*)&WF[(size_t)(gi * 512 + ns + (l & 15)) * 1280 + koo];
    }
  }

  for (int t = 0; t < 256; ++t){
    const u32 tg = (u32)t;
    const int rp = (t + 1) & 1;
    f32x4 acc[2][4];
#pragma unroll
    for (int a = 0; a < 2; a++)
#pragma unroll
      for (int b = 0; b < 4; b++){ f32x4 z = {0.f,0.f,0.f,0.f}; acc[a][b] = z; }

#pragma unroll
    for (int ki = 0; ki < 2; ki++){
      int ko = w * 64 + ki * 32 + (l >> 4) * 8;
      s16x8 av[2];
#pragma unroll
      for (int mi = 0; mi < 2; mi++)
        av[mi] = *(const s16x8*)&XS[(size_t)(t * 32 + mi * 16 + (l & 15)) * 256 + ko];
#pragma unroll
      for (int mi = 0; mi < 2; mi++)
#pragma unroll
        for (int gi = 0; gi < 4; gi++)
          acc[mi][gi] = __builtin_amdgcn_mfma_f32_16x16x32_bf16(av[mi], bx[ki][gi], acc[mi][gi], 0, 0, 0);
    }
    if (t > 0){
#pragma unroll
      for (int kk = 0; kk < 4; kk++){
        int wb = w * 64 + kk * 16 + ((l >> 4) << 2);
        const u64* p0 = &ZH[(size_t)rp * 8192 + (size_t)(l & 15) * 256 + wb];
        const u64* p1 = &ZH[(size_t)rp * 8192 + (size_t)(16 + (l & 15)) * 256 + wb];
        u64 qa0,qa1,qa2,qa3,qb0,qb1,qb2,qb3; bool ok;
        do {
          qa0=tload(p0); qa1=tload(p0+1); qa2=tload(p0+2); qa3=tload(p0+3);
          qb0=tload(p1); qb1=tload(p1+1); qb2=tload(p1+2); qb3=tload(p1+3);
          ok = (wtag(qa0)==tg)&(wtag(qa1)==tg)&(wtag(qa2)==tg)&(wtag(qa3)==tg)
             & (wtag(qb0)==tg)&(wtag(qb1)==tg)&(wtag(qb2)==tg)&(wtag(qb3)==tg);
          if (!ok) __builtin_amdgcn_s_sleep(1);
        } while (!__all(ok));
        s16x8 av0 = pack4(qa0,qa1,qa2,qa3), av1 = pack4(qb0,qb1,qb2,qb3);
#pragma unroll
        for (int gi = 0; gi < 4; gi++){
          acc[0][gi] = __builtin_amdgcn_mfma_f32_16x16x32_bf16(av0, bh[kk][gi], acc[0][gi], 0, 0, 0);
          acc[1][gi] = __builtin_amdgcn_mfma_f32_16x16x32_bf16(av1, bh[kk][gi], acc[1][gi], 0, 0, 0);
        }
      }
#pragma unroll
      for (int kk = 0; kk < 4; kk++){
        int wb = w * 64 + kk * 16 + ((l >> 4) << 2);
        const u64* p0 = &ZO[(size_t)rp * 8192 + (size_t)(l & 15) * 256 + wb];
        const u64* p1 = &ZO[(size_t)rp * 8192 + (size_t)(16 + (l & 15)) * 256 + wb];
        u64 qa0,qa1,qa2,qa3,qb0,qb1,qb2,qb3; bool ok;
        do {
          qa0=tload(p0); qa1=tload(p0+1); qa2=tload(p0+2); qa3=tload(p0+3);
          qb0=tload(p1); qb1=tload(p1+1); qb2=tload(p1+2); qb3=tload(p1+3);
          ok = (wtag(qa0)==tg)&(wtag(qa1)==tg)&(wtag(qa2)==tg)&(wtag(qa3)==tg)
             & (wtag(qb0)==tg)&(wtag(qb1)==tg)&(wtag(qb2)==tg)&(wtag(qb3)==tg);
          if (!ok) __builtin_amdgcn_s_sleep(1);
        } while (!__all(ok));
        s16x8 av0 = pack4(qa0,qa1,qa2,qa3), av1 = pack4(qb0,qb1,qb2,qb3);
#pragma unroll
        for (int gi = 0; gi < 4; gi++){
          acc[0][gi] = __builtin_amdgcn_mfma_f32_16x16x32_bf16(av0, bo[kk][gi], acc[0][gi], 0, 0, 0);
          acc[1][gi] = __builtin_amdgcn_mfma_f32_16x16x32_bf16(av1, bo[kk][gi], acc[1][gi], 0, 0, 0);
        }
      }
    }
#pragma unroll
    for (int mi = 0; mi < 2; mi++)
#pragma unroll
      for (int gi = 0; gi < 4; gi++)
#pragma unroll
        for (int r = 0; r < 4; r++)
          red[w][mi * 16 + (l >> 4) * 4 + r][gi * 16 + (l & 15)] = acc[mi][gi][r];
    __syncthreads();
    {
      int bi = tid >> 3, j = (tid & 7) * 2;
      float iv0=0,fv0=0,gv0=0,ov0=0, iv1=0,fv1=0,gv1=0,ov1=0;
#pragma unroll
      for (int qq = 0; qq < 4; qq++){
        iv0 += red[qq][bi][j];      fv0 += red[qq][bi][16 + j];
        gv0 += red[qq][bi][32 + j]; ov0 += red[qq][bi][48 + j];
        iv1 += red[qq][bi][j + 1];      fv1 += red[qq][bi][16 + j + 1];
        gv1 += red[qq][bi][32 + j + 1]; ov1 += red[qq][bi][48 + j + 1];
      }
      int n0 = ns + j;
      float c0 = (t > 0) ? CST[bi * 512 + n0]     : 0.f;
      float c1 = (t > 0) ? CST[bi * 512 + n0 + 1] : 0.f;
      float cn0 = sigm(fv0) * c0 + sigm(iv0) * tanhf(gv0);
      float cn1 = sigm(fv1) * c1 + sigm(iv1) * tanhf(gv1);
      float h0 = sigm(ov0) * tanhf(cn0);
      float h1 = sigm(ov1) * tanhf(cn1);
      CST[bi * 512 + n0] = cn0; CST[bi * 512 + n0 + 1] = cn1;
      u32 pk = (u32)f2bf(h0) | ((u32)f2bf(h1) << 16);
      tstore(&ZH[(size_t)(t & 1) * 8192 + (size_t)bi * 256 + g * 8 + (tid & 7)],
             ((u64)(u32)(t + 1) << 32) | pk);
    }
    __syncthreads();
  }
}

// ---------------- attn+out role (gid>=32): MFMA everywhere; tagged polls ----------------

static __device__ void attn_role(const u16* __restrict__ CNN2, const u16* __restrict__ CNNB,
                                 const u16* __restrict__ WOUT,
                                 u64* __restrict__ ZH, u64* __restrict__ ZO,
                                 u64* __restrict__ UT, u64* __restrict__ MST,
                                 u16* __restrict__ OALL, float* __restrict__ SM, int q){
  const int tid = threadIdx.x, w = tid >> 6, l = tid & 63;
  const int b = q / 7, ch = q - b * 7;
  const int l0 = ch * 112;
  const int nc = (ch == 6) ? 68 : 74, cs = ch * 74;
  u16*   hsh  = (u16*)SM;
  u16*   pbf  = (u16*)(SM + 256);
  float* scp  = SM + 320;
  float* msh  = SM + 768;
  u32*   zsh  = (u32*)(SM + 784);
  float* opart= SM + 1040;

  s16x8 a2[7][4];
  s16x8 vb[8][4];
#pragma unroll
  for (int tile = 0; tile < 7; tile++)
#pragma unroll
    for (int kk = 0; kk < 4; kk++)
      a2[tile][kk] = *(const s16x8*)&CNN2[(size_t)(b * 784 + l0 + tile * 16 + (l & 15)) * 512
                                          + w * 128 + kk * 32 + (l >> 4) * 8];
#pragma unroll
  for (int nt = 0; nt < 8; nt++)
#pragma unroll
    for (int kk = 0; kk < 4; kk++){
      int col = w * 128 + nt * 16 + (l & 15);
#pragma unroll
      for (int j = 0; j < 8; j++){
        int krow = kk * 32 + (l >> 4) * 8 + j;
        vb[nt][kk][j] = (krow < 112)
          ? (short)CNNB[(size_t)(b * 784 + l0 + krow) * 512 + col] : (short)0;
      }
    }

  for (int t = 0; t < 256; ++t){
    const u32 tagp = (u32)(t + 1);
    {
      const u64* hp = &ZH[(size_t)(t & 1) * 8192 + (size_t)b * 256 + tid];
      u64 hw; bool ok;
      do {
        hw = tload(hp);
        ok = (wtag(hw) == tagp);
        if (!ok) __builtin_amdgcn_s_sleep(1);
      } while (!__all(ok));
      ((u32*)hsh)[tid] = (u32)hw;
    }
    __syncthreads();

    f32x4 sac[7];
#pragma unroll
    for (int tile = 0; tile < 7; tile++){ f32x4 z = {0.f,0.f,0.f,0.f}; sac[tile] = z; }
#pragma unroll
    for (int kk = 0; kk < 4; kk++){
      s16x8 bv = *(const s16x8*)&hsh[w * 128 + kk * 32 + (l >> 4) * 8];
#pragma unroll
      for (int tile = 0; tile < 7; tile++)
        sac[tile] = __builtin_amdgcn_mfma_f32_16x16x32_bf16(a2[tile][kk], bv, sac[tile], 0, 0, 0);
    }
    if ((l & 15) == 0){
#pragma unroll
      for (int tile = 0; tile < 7; tile++)
#pragma unroll
        for (int r = 0; r < 4; r++)
          scp[w * 112 + tile * 16 + (l >> 4) * 4 + r] = sac[tile][r];
    }
    __syncthreads();

    float v0 = scp[l] + scp[112 + l] + scp[224 + l] + scp[336 + l];
    float v64 = (l < 48) ? (scp[64 + l] + scp[176 + l] + scp[288 + l] + scp[400 + l]) : -1e30f;
    float m2 = fmaxf(v0, v64);
#pragma unroll
    for (int mk = 1; mk < 64; mk <<= 1) m2 = fmaxf(m2, __shfl_xor(m2, mk, 64));
    float M = m2;
    float p0 = __expf(v0 - M);
    float p64 = (l < 48) ? __expf(v64 - M) : 0.f;
    if (w == 0){ pbf[l] = f2bf(p0); pbf[64 + l] = f2bf(p64); }
    float s2 = p0 + p64;
#pragma unroll
    for (int mk = 1; mk < 64; mk <<= 1) s2 += __shfl_xor(s2, mk, 64);
    float S = s2;
    __syncthreads();

    f32x4 uac[8];
#pragma unroll
    for (int nt = 0; nt < 8; nt++){ f32x4 z = {0.f,0.f,0.f,0.f}; uac[nt] = z; }
#pragma unroll
    for (int kk = 0; kk < 4; kk++){
      s16x8 av = *(const s16x8*)&pbf[kk * 32 + (l >> 4) * 8];
#pragma unroll
      for (int nt = 0; nt < 8; nt++)
        uac[nt] = __builtin_amdgcn_mfma_f32_16x16x32_bf16(av, vb[nt][kk], uac[nt], 0, 0, 0);
    }
#pragma unroll
    for (int nt = 0; nt < 8; nt++){
      float o0 = uac[nt][0];
      float o1 = __shfl_xor(o0, 1, 64);
      if (l < 16 && (l & 1) == 0){
        u64 wv = ((u64)tagp << 32) | (u32)f2bf(o0) | ((u32)f2bf(o1) << 16);
        tstore(&UT[((size_t)(b * 7 + ch)) * 256 + w * 64 + nt * 8 + (l >> 1)], wv);
      }
    }
    if (tid == 0){
      tstore(&MST[(b * 7 + ch) * 2 + 0], ((u64)tagp << 32) | __builtin_bit_cast(u32, M));
      tstore(&MST[(b * 7 + ch) * 2 + 1], ((u64)tagp << 32) | __builtin_bit_cast(u32, S));
    }

    f32x4 oac[5];
#pragma unroll
    for (int tile = 0; tile < 5; tile++){ f32x4 z = {0.f,0.f,0.f,0.f}; oac[tile] = z; }
#pragma unroll
    for (int kk = 0; kk < 4; kk++){
      int ko = w * 128 + kk * 32 + (l >> 4) * 8;
      s16x8 bv = *(const s16x8*)&hsh[ko];
#pragma unroll
      for (int tile = 0; tile < 5; tile++){
        int row = cs + tile * 16 + (l & 15);
        row = (row < 511) ? row : 511;
        s16x8 av = *(const s16x8*)&WOUT[(size_t)row * 1024 + 512 + ko];
        oac[tile] = __builtin_amdgcn_mfma_f32_16x16x32_bf16(av, bv, oac[tile], 0, 0, 0);
      }
    }

    u64 uw[7]; u64 msv = 0;
    {
      bool ok;
      do {
#pragma unroll
        for (int c = 0; c < 7; c++) uw[c] = tload(&UT[((size_t)(b * 7 + c)) * 256 + tid]);
        ok = true;
#pragma unroll
        for (int c = 0; c < 7; c++) ok &= (wtag(uw[c]) == tagp);
        if (w == 0){
          msv = tload(&MST[b * 14 + ((l < 14) ? l : 0)]);
          ok &= (wtag(msv) == tagp);
        }
        if (!ok) __builtin_amdgcn_s_sleep(1);
      } while (!__all(ok));
    }
    if (w == 0 && l < 14) msh[l] = __builtin_bit_cast(float, (u32)msv);
    __syncthreads();
    float Mg = -1e30f;
#pragma unroll
    for (int c = 0; c < 7; c++) Mg = fmaxf(Mg, msh[2 * c]);
    float bet[7]; float Sg = 0.f;
#pragma unroll
    for (int c = 0; c < 7; c++){
      float e = __expf(msh[2 * c] - Mg);
      bet[c] = e; Sg += e * msh[2 * c + 1];
    }
    float inv = 1.f / Sg;
    {
      float c0 = 0.f, c1 = 0.f;
#pragma unroll
      for (int c = 0; c < 7; c++){
        float bc = bet[c] * inv;
        c0 = fmaf(bc, bf2f((u16)uw[c]), c0);
        c1 = fmaf(bc, bf2f((u16)(uw[c] >> 16)), c1);
      }
      zsh[tid] = (u32)f2bf(c0) | ((u32)f2bf(c1) << 16);
    }
    __syncthreads();

#pragma unroll
    for (int kk = 0; kk < 4; kk++){
      int ko = w * 128 + kk * 32 + (l >> 4) * 8;
      s16x8 bv = *(const s16x8*)((const u16*)zsh + ko);
#pragma unroll
      for (int tile = 0; tile < 5; tile++){
        int row = cs + tile * 16 + (l & 15);
        row = (row < 511) ? row : 511;
        s16x8 av = *(const s16x8*)&WOUT[(size_t)row * 1024 + ko];
        oac[tile] = __builtin_amdgcn_mfma_f32_16x16x32_bf16(av, bv, oac[tile], 0, 0, 0);
      }
    }
    if ((l & 15) == 0){
#pragma unroll
      for (int tile = 0; tile < 5; tile++)
#pragma unroll
        for (int r = 0; r < 4; r++)
          opart[w * 80 + tile * 16 + (l >> 4) * 4 + r] = oac[tile][r];
    }
    __syncthreads();
    if (tid < (nc >> 1)){
      int j0 = 2 * tid;
      float v0o = opart[j0]   + opart[80 + j0]   + opart[160 + j0]   + opart[240 + j0];
      float v1o = opart[j0+1] + opart[80 + j0+1] + opart[160 + j0+1] + opart[240 + j0+1];
      u32 pk = (u32)f2bf(tanhf(v0o)) | ((u32)f2bf(tanhf(v1o)) << 16);
      tstore(&ZO[(size_t)(t & 1) * 8192 + (size_t)b * 256 + (cs >> 1) + tid],
             ((u64)tagp << 32) | pk);
      *(u32*)&OALL[((size_t)(b * 256 + t)) * 512 + cs + j0] = pk;
    }
    __syncthreads();
  }
}

// ---------------- persistent decoder ----------------

__global__ __launch_bounds__(256, 1) void k_persist(const u16* __restrict__ WF,
                                                    const u16* __restrict__ XS,
                                                    const u16* __restrict__ CNN2,
                                                    const u16* __restrict__ CNNB,
                                                    const u16* __restrict__ WOUT,
                                                    u64* __restrict__ ZH,
                                                    u64* __restrict__ ZO,
                                                    u64* __restrict__ UT,
                                                    u64* __restrict__ MST,
                                                    float* __restrict__ CST,
                                                    u16* __restrict__ OALL){
  __shared__ __align__(16) float SM[8192];
  int gid = blockIdx.x;
  if (gid < 32)
    gates_role(WF, XS, ZH, ZO, CST, SM, gid);
  else
    attn_role(CNN2, CNNB, WOUT, ZH, ZO, UT, MST, OALL, SM, gid - 32);
}

// ---------------- log_softmax from precomputed tile stats ----------------

__global__ __launch_bounds__(256) void k_lsm2(float* __restrict__ x,
                                              const float* __restrict__ stats){
  size_t row = blockIdx.x;
  int tid = threadIdx.x, w = tid >> 6, ln = tid & 63;
  __shared__ float lzsh;
  if (w == 0){
    float m = -1e30f, s = 0.f;
    if (ln < 63){
      m = stats[(row * 64 + ln) * 2];
      s = stats[(row * 64 + ln) * 2 + 1];
    }
#pragma unroll
    for (int mk = 1; mk < 64; mk <<= 1){
      float mo = __shfl_xor(m, mk, 64), so = __shfl_xor(s, mk, 64);
      float nm = fmaxf(m, mo);
      s = s * __expf(m - nm) + so * __expf(mo - nm);
      m = nm;
    }
    if (ln == 0) lzsh = m + logf(s);
  }
  __syncthreads();
  float lz = lzsh;
  float4* xw = (float4*)(x + row * 8000);
  for (int v = tid; v < 2000; v += 256){
    float4 f = xw[v];
    f.x -= lz; f.y -= lz; f.z -= lz; f.w -= lz;
    xw[v] = f;
  }
}

// ---------------- launcher ----------------

extern "C" void kernel_launch(void* const* d_in, const int* in_sizes, int n_in,
                              void* d_out, int out_size, void* d_ws, size_t ws_size,
                              hipStream_t stream){
  const float* cnn  = (const float*)d_in[0];
  const int*   seq  = (const int*)d_in[1];
  const float* emb  = (const float*)d_in[2];
  const float* wih  = (const float*)d_in[3];
  const float* whh  = (const float*)d_in[4];
  const float* whm  = (const float*)d_in[5];
  const float* wo   = (const float*)d_in[6];
  const float* wlg  = (const float*)d_in[7];
  const float* blg  = (const float*)d_in[8];

  char* ws = (char*)d_ws;
  u16*   WF     = (u16*)(ws + 0);          // 2048x1280 bf16 = 5,242,880
  u16*   WHMT   = (u16*)(ws + 5242880);    // 512x512 bf16   =   524,288
  u16*   WOUT   = (u16*)(ws + 5767168);    // 512x1024 bf16  = 1,048,576
  u16*   WLOGIT = (u16*)(ws + 6815744);    // 8000x512 bf16  = 8,192,000
  u16*   CNNBF  = (u16*)(ws + 15007744);   // 25088x512 bf16 = 25,690,112
  u16*   CNN2   = (u16*)(ws + 40697856);   // 25088x512 bf16 = 25,690,112
  u16*   XS     = (u16*)(ws + 66387968);   // [256][32][256] bf16 = 4,194,304
  u16*   OALL   = (u16*)(ws + 70582272);   // 8192x512 bf16  = 8,388,608
  u64*   ZH     = (u64*)(ws + 78970880);   // [2][32][256] u64 = 131,072
  u64*   ZO     = (u64*)(ws + 79101952);   // [2][32][256] u64 = 131,072
  u64*   UT     = (u64*)(ws + 79233024);   // [32][7][256] u64 = 458,752
  u64*   MST    = (u64*)(ws + 79691776);   // [32][7][2] u64 = 3,584
  float* CST    = (float*)(ws + 79695360); // 32x512 f32 = 65,536
  float* STATS  = (float*)(ws + 79760896); // [8192][64][2] f32 = 4,194,304 -> ends 83,955,200

  float* OUT = (float*)d_out;

  (void)hipMemsetAsync(ws + 78970880, 0, 724480, stream);   // ZH..MST tags -> 0
  k_prep<<<6272, 256, 0, stream>>>(wih, whh, WF, whm, WHMT, wo, WOUT,
                                   wlg, WLOGIT, cnn, CNNBF, seq, emb, XS);

  {
    dim3 g(196, 4);   // CNN2 = CNNB @ WHMT^T
    k_gemm<1, 0, 0, 0><<<g, 256, 0, stream>>>(CNNBF, WHMT, CNN2, nullptr, nullptr, 25088, 512, 512);
  }

  k_persist<<<256, 256, 0, stream>>>(WF, XS, CNN2, CNNBF, WOUT, ZH, ZO, UT, MST, CST, OALL);

  {
    dim3 g(64, 63);
    k_gemm<0, 1, 1, 1><<<g, 256, 0, stream>>>(OALL, WLOGIT, OUT, blg, STATS, 8192, 8000, 512);
  }
  k_lsm2<<<8192, 256, 0, stream>>>(OUT, STATS);
}